// Round 1
// baseline (3967.054 us; speedup 1.0000x reference)
//
#include <hip/hip_runtime.h>

// ---------------- problem constants ----------------
#define ETOT  500000
#define EHALF 250000
#define NENT  50000
#define DD    200
#define BB    1024
#define NF    96
#define FLAT  38400   // 96*400

// ---------------- workspace layout (float32 offsets) ----------------
// zeroed region: [0, ZERO_END)
#define OFF_AGG_IN   0LL          // 10,000,000  (later overwritten in-place by all_ent)
#define OFF_AGG_OUT  10000000LL   // 10,000,000
#define OFF_DEG      20000000LL   //     50,000
#define OFF_ACC0     20050000LL   //          2  (bn0 sum, sumsq)
#define OFF_ACC1     20050002LL   //        192  (bn1 sum[96], sumsq[96])
#define OFF_X1       20050194LL   //    204,800  (fc output, atomic-accumulated)
#define ZERO_END     20254994LL
// non-zeroed:
#define OFF_DINV     20255000LL   //     50,000
#define OFF_RMAT     20305000LL   //     80,000
#define OFF_CHEQ     20385000LL   //    409,600
#define OFF_BN1S     20795000LL   //        192  (scale[96], shift[96])
#define OFF_X2       20795200LL   //    204,800
// total ws need = 21,000,000 f32 = 84 MB

// ================= encoder =================

__global__ void k_deg(const int* __restrict__ ei, float* __restrict__ deg) {
    int e = blockIdx.x * 256 + threadIdx.x;
    if (e < ETOT) atomicAdd(&deg[ei[ETOT + e]], 1.0f);
}

__global__ void k_dinv(const float* __restrict__ deg, float* __restrict__ dinv) {
    int i = blockIdx.x * 256 + threadIdx.x;
    if (i < NENT) {
        float d = deg[i];
        dinv[i] = d > 0.f ? rsqrtf(fmaxf(d, 1.f)) : 0.f;
    }
}

// scatter raw messages (embed[src]-rel[et])*norm into agg_in/agg_out (pre-GEMM, linearity)
__global__ void k_scatter(const int* __restrict__ ei, const int* __restrict__ et,
                          const float* __restrict__ emb, const float* __restrict__ rel,
                          const float* __restrict__ dinv,
                          float* __restrict__ agg_in, float* __restrict__ agg_out) {
    int flat = blockIdx.x * 256 + threadIdx.x;   // over ETOT*50 (float4 per thread)
    if (flat >= ETOT * 50) return;
    int e = flat / 50;
    int k = (flat % 50) * 4;
    int src = ei[e], dst = ei[ETOT + e], t = et[e];
    float nrm = dinv[src] * dinv[dst];
    if (nrm == 0.f) return;
    float4 a = *(const float4*)&emb[src * DD + k];
    float4 b = *(const float4*)&rel[t * DD + k];
    float* out = (e < EHALF ? agg_in : agg_out) + (long long)dst * DD + k;
    atomicAdd(out + 0, (a.x - b.x) * nrm);
    atomicAdd(out + 1, (a.y - b.y) * nrm);
    atomicAdd(out + 2, (a.z - b.z) * nrm);
    atomicAdd(out + 3, (a.w - b.w) * nrm);
}

// all_ent = tanh((agg_in@w_in + agg_out@w_out + (embed-loop_rel)@w_loop)/3)
// writes in place over agg_in (each block owns its 16 rows; staged to LDS first)
__global__ void k_allent(const float* __restrict__ agg_in, const float* __restrict__ agg_out,
                         const float* __restrict__ emb, const float* __restrict__ loop_rel,
                         const float* __restrict__ w_in, const float* __restrict__ w_out,
                         const float* __restrict__ w_loop, float* __restrict__ all_ent) {
    __shared__ float S[3][16][DD];   // 38.4 KB
    int r0 = blockIdx.x * 16;
    for (int i = threadIdx.x; i < 16 * DD; i += 256) {
        int rr = i / DD, k = i % DD;
        long long g = (long long)(r0 + rr) * DD + k;
        S[0][rr][k] = agg_in[g];
        S[1][rr][k] = agg_out[g];
        S[2][rr][k] = emb[g] - loop_rel[k];
    }
    __syncthreads();
    int j = threadIdx.x;
    if (j < DD) {
        float acc[16];
#pragma unroll
        for (int rr = 0; rr < 16; rr++) acc[rr] = 0.f;
        for (int k = 0; k < DD; k += 4) {
            float w0x = w_in[(k + 0) * DD + j], w0y = w_in[(k + 1) * DD + j],
                  w0z = w_in[(k + 2) * DD + j], w0w = w_in[(k + 3) * DD + j];
            float w1x = w_out[(k + 0) * DD + j], w1y = w_out[(k + 1) * DD + j],
                  w1z = w_out[(k + 2) * DD + j], w1w = w_out[(k + 3) * DD + j];
            float w2x = w_loop[(k + 0) * DD + j], w2y = w_loop[(k + 1) * DD + j],
                  w2z = w_loop[(k + 2) * DD + j], w2w = w_loop[(k + 3) * DD + j];
#pragma unroll
            for (int rr = 0; rr < 16; rr++) {
                float4 a = *(const float4*)&S[0][rr][k];
                float4 b = *(const float4*)&S[1][rr][k];
                float4 c = *(const float4*)&S[2][rr][k];
                acc[rr] += a.x * w0x + a.y * w0y + a.z * w0z + a.w * w0w
                         + b.x * w1x + b.y * w1y + b.z * w1z + b.w * w1w
                         + c.x * w2x + c.y * w2y + c.z * w2z + c.w * w2w;
            }
        }
#pragma unroll
        for (int rr = 0; rr < 16; rr++)
            all_ent[(long long)(r0 + rr) * DD + j] = tanhf(acc[rr] * (1.f / 3.f));
    }
}

// r = init_rel @ w_rel   [400,200]@[200,200]
__global__ void k_rmat(const float* __restrict__ init_rel, const float* __restrict__ w_rel,
                       float* __restrict__ rmat) {
    __shared__ float S[16][DD];
    int r0 = blockIdx.x * 16;
    for (int i = threadIdx.x; i < 16 * DD; i += 256)
        S[i / DD][i % DD] = init_rel[(r0 + i / DD) * DD + i % DD];
    __syncthreads();
    int j = threadIdx.x;
    if (j < DD) {
        float acc[16];
#pragma unroll
        for (int rr = 0; rr < 16; rr++) acc[rr] = 0.f;
        for (int k = 0; k < DD; k += 4) {
            float wx = w_rel[(k + 0) * DD + j], wy = w_rel[(k + 1) * DD + j],
                  wz = w_rel[(k + 2) * DD + j], ww = w_rel[(k + 3) * DD + j];
#pragma unroll
            for (int rr = 0; rr < 16; rr++) {
                float4 a = *(const float4*)&S[rr][k];
                acc[rr] += a.x * wx + a.y * wy + a.z * wz + a.w * ww;
            }
        }
#pragma unroll
        for (int rr = 0; rr < 16; rr++) rmat[(r0 + rr) * DD + j] = acc[rr];
    }
}

// ================= decoder =================

// chequer gather + bn0 statistics
__global__ void k_cheq(const int* __restrict__ sub, const int* __restrict__ rel,
                       const int* __restrict__ perm, const float* __restrict__ all_ent,
                       const float* __restrict__ rmat, float* __restrict__ cheq,
                       float* __restrict__ acc0) {
    int i = blockIdx.x * 256 + threadIdx.x;   // over B*400 = 409600 exactly
    int b = i / 400, p = i % 400;
    int c = perm[p];
    float v = (c < DD) ? all_ent[(long long)sub[b] * DD + c]
                       : rmat[rel[b] * DD + (c - DD)];
    cheq[i] = v;
    __shared__ float s1[256], s2[256];
    s1[threadIdx.x] = v;
    s2[threadIdx.x] = v * v;
    __syncthreads();
    for (int st = 128; st > 0; st >>= 1) {
        if (threadIdx.x < st) { s1[threadIdx.x] += s1[threadIdx.x + st]; s2[threadIdx.x] += s2[threadIdx.x + st]; }
        __syncthreads();
    }
    if (threadIdx.x == 0) { atomicAdd(&acc0[0], s1[0]); atomicAdd(&acc0[1], s2[0]); }
}

// bn0-normalize + circular pad + 9x9 conv (96 filt) + bn1 stats. conv out -> d_out scratch (f32)
__global__ void k_conv(const float* __restrict__ cheq, const float* __restrict__ acc0,
                       const float* __restrict__ bn0_g, const float* __restrict__ bn0_b,
                       const float* __restrict__ filt, float* __restrict__ conv_out,
                       float* __restrict__ acc1) {
    __shared__ float xp[28 * 28];
    __shared__ float fl[NF * 81];
    __shared__ float csum[NF], csq[NF];
    int b = blockIdx.x;
    const float invN = 1.f / (BB * 400.f);
    float mean = acc0[0] * invN;
    float var = acc0[1] * invN - mean * mean;
    float sc = rsqrtf(var + 1e-5f) * bn0_g[0];
    float sh = bn0_b[0] - mean * sc;
    for (int i = threadIdx.x; i < 28 * 28; i += 256) {
        int r = i / 28, c = i % 28;
        int rr = (r + 16) % 20, cc = (c + 16) % 20;   // (idx-4) mod 20
        xp[i] = cheq[b * 400 + rr * 20 + cc] * sc + sh;
    }
    for (int i = threadIdx.x; i < NF * 81; i += 256) fl[i] = filt[i];
    if (threadIdx.x < NF) { csum[threadIdx.x] = 0.f; csq[threadIdx.x] = 0.f; }
    __syncthreads();
    for (int t = threadIdx.x; t < NF * 20; t += 256) {
        int ch = t / 20, row = t % 20;
        float acc[20];
#pragma unroll
        for (int c2 = 0; c2 < 20; c2++) acc[c2] = 0.f;
        for (int di = 0; di < 9; di++) {
            const float* xrow = &xp[(row + di) * 28];
#pragma unroll
            for (int dj = 0; dj < 9; dj++) {
                float f = fl[ch * 81 + di * 9 + dj];
#pragma unroll
                for (int c2 = 0; c2 < 20; c2++) acc[c2] = fmaf(xrow[c2 + dj], f, acc[c2]);
            }
        }
        float s = 0.f, q = 0.f;
        long long base = (long long)b * FLAT + ch * 400 + row * 20;
#pragma unroll
        for (int c2 = 0; c2 < 20; c2++) {
            float v = acc[c2];
            s += v; q += v * v;
            conv_out[base + c2] = v;
        }
        atomicAdd(&csum[ch], s);
        atomicAdd(&csq[ch], q);
    }
    __syncthreads();
    if (threadIdx.x < NF) {
        atomicAdd(&acc1[threadIdx.x], csum[threadIdx.x]);
        atomicAdd(&acc1[NF + threadIdx.x], csq[threadIdx.x]);
    }
}

__global__ void k_bn1fin(const float* __restrict__ acc1, const float* __restrict__ g1,
                         const float* __restrict__ b1, float* __restrict__ bn1s) {
    int c = threadIdx.x;
    if (c >= NF) return;
    const float invN = 1.f / (BB * 400.f);
    float m = acc1[c] * invN;
    float v = acc1[NF + c] * invN - m * m;
    float sc = rsqrtf(v + 1e-5f) * g1[c];
    bn1s[c] = sc;
    bn1s[NF + c] = b1[c] - m * sc;
}

// fc: x1[b][j] = sum_k relu(bn1(conv)) * fc_w[j][k]; grid = (64 b-tiles, 10 k-slices); atomic acc
__global__ void k_fc(const float* __restrict__ conv_out, const float* __restrict__ bn1s,
                     const float* __restrict__ fc_w, float* __restrict__ x1) {
    __shared__ float As[16][256];   // 16 KB
    int b0 = blockIdx.x * 16;
    int kslice = blockIdx.y;        // 10 slices of 3840 = 15 chunks of 256
    int j = threadIdx.x;
    float acc[16];
#pragma unroll
    for (int bi = 0; bi < 16; bi++) acc[bi] = 0.f;
    for (int chunk = 0; chunk < 15; chunk++) {
        int kb = kslice * 3840 + chunk * 256;
        __syncthreads();
        int k = kb + threadIdx.x;
        int ch = k / 400;
        float scl = bn1s[ch], shf = bn1s[NF + ch];
        for (int bi = 0; bi < 16; bi++) {
            float v = conv_out[(long long)(b0 + bi) * FLAT + k] * scl + shf;
            As[bi][threadIdx.x] = fmaxf(v, 0.f);
        }
        __syncthreads();
        if (j < DD) {
            for (int kk = 0; kk < 256; kk += 4) {
                float4 w = *(const float4*)&fc_w[(long long)j * FLAT + kb + kk];
#pragma unroll
                for (int bi = 0; bi < 16; bi++) {
                    float4 a = *(const float4*)&As[bi][kk];
                    acc[bi] += a.x * w.x + a.y * w.y + a.z * w.z + a.w * w.w;
                }
            }
        }
    }
    if (j < DD) {
#pragma unroll
        for (int bi = 0; bi < 16; bi++) atomicAdd(&x1[(b0 + bi) * DD + j], acc[bi]);
    }
}

// bn2 (per-feature over batch) + relu -> x2. one block per feature j.
__global__ void k_bn2(const float* __restrict__ x1, const float* __restrict__ fc_b,
                      const float* __restrict__ g2, const float* __restrict__ b2,
                      float* __restrict__ x2) {
    int j = blockIdx.x;
    float vals[4];
    float s = 0.f, q = 0.f;
#pragma unroll
    for (int i = 0; i < 4; i++) {
        int b = threadIdx.x + i * 256;
        float v = x1[b * DD + j] + fc_b[j];
        vals[i] = v;
        s += v; q += v * v;
    }
    __shared__ float r1[256], r2[256];
    __shared__ float bc[2];
    r1[threadIdx.x] = s; r2[threadIdx.x] = q;
    __syncthreads();
    for (int st = 128; st > 0; st >>= 1) {
        if (threadIdx.x < st) { r1[threadIdx.x] += r1[threadIdx.x + st]; r2[threadIdx.x] += r2[threadIdx.x + st]; }
        __syncthreads();
    }
    if (threadIdx.x == 0) {
        float m = r1[0] * (1.f / BB);
        float v = r2[0] * (1.f / BB) - m * m;
        float sc = rsqrtf(v + 1e-5f) * g2[j];
        bc[0] = sc; bc[1] = b2[j] - m * sc;
    }
    __syncthreads();
    float sc = bc[0], sh = bc[1];
#pragma unroll
    for (int i = 0; i < 4; i++) {
        int b = threadIdx.x + i * 256;
        x2[b * DD + j] = fmaxf(vals[i] * sc + sh, 0.f);
    }
}

// logits = sigmoid(x2 @ all_ent^T + bias)
__global__ void k_logits(const float* __restrict__ x2, const float* __restrict__ all_ent,
                         const float* __restrict__ bias, float* __restrict__ out) {
    __shared__ float X[16][DD];   // 12.8 KB
    int e0 = blockIdx.x * 256;
    int b0 = blockIdx.y * 16;
    for (int i = threadIdx.x; i < 16 * DD; i += 256)
        X[i / DD][i % DD] = x2[(b0 + i / DD) * DD + i % DD];
    __syncthreads();
    int e = e0 + threadIdx.x;
    if (e >= NENT) return;
    float acc[16];
#pragma unroll
    for (int bi = 0; bi < 16; bi++) acc[bi] = 0.f;
    for (int k = 0; k < DD; k += 4) {
        float4 a = *(const float4*)&all_ent[(long long)e * DD + k];
#pragma unroll
        for (int bi = 0; bi < 16; bi++) {
            float4 x = *(const float4*)&X[bi][k];
            acc[bi] += a.x * x.x + a.y * x.y + a.z * x.z + a.w * x.w;
        }
    }
    float bv = bias[e];
#pragma unroll
    for (int bi = 0; bi < 16; bi++) {
        float t = acc[bi] + bv;
        out[(long long)(b0 + bi) * NENT + e] = 1.f / (1.f + expf(-t));
    }
}

// ================= host =================

extern "C" void kernel_launch(void* const* d_in, const int* in_sizes, int n_in,
                              void* d_out, int out_size, void* d_ws, size_t ws_size,
                              hipStream_t stream) {
    const int*   sub      = (const int*)d_in[0];
    const int*   rel      = (const int*)d_in[1];
    // d_in[2] = neg_ents (unused in forward)
    const int*   ei       = (const int*)d_in[3];
    const int*   et       = (const int*)d_in[4];
    const int*   perm     = (const int*)d_in[5];
    const float* emb      = (const float*)d_in[6];
    const float* init_rel = (const float*)d_in[7];
    const float* w_in     = (const float*)d_in[8];
    const float* w_out    = (const float*)d_in[9];
    const float* w_loop   = (const float*)d_in[10];
    const float* w_rel    = (const float*)d_in[11];
    const float* loop_rel = (const float*)d_in[12];
    const float* bn0_g    = (const float*)d_in[13];
    const float* bn0_b    = (const float*)d_in[14];
    const float* bn1_g    = (const float*)d_in[15];
    const float* bn1_b    = (const float*)d_in[16];
    const float* bn2_g    = (const float*)d_in[17];
    const float* bn2_b    = (const float*)d_in[18];
    const float* filt     = (const float*)d_in[19];
    const float* fc_w     = (const float*)d_in[20];
    const float* fc_b     = (const float*)d_in[21];
    const float* bias_ent = (const float*)d_in[22];

    float* ws  = (float*)d_ws;
    float* o   = (float*)d_out;   // also used as conv scratch (157MB < 205MB), fully overwritten by k_logits

    float* agg_in  = ws + OFF_AGG_IN;
    float* agg_out = ws + OFF_AGG_OUT;
    float* deg     = ws + OFF_DEG;
    float* acc0    = ws + OFF_ACC0;
    float* acc1    = ws + OFF_ACC1;
    float* x1      = ws + OFF_X1;
    float* dinv    = ws + OFF_DINV;
    float* rmat    = ws + OFF_RMAT;
    float* cheq    = ws + OFF_CHEQ;
    float* bn1s    = ws + OFF_BN1S;
    float* x2      = ws + OFF_X2;
    float* all_ent = agg_in;      // k_allent writes in place over agg_in

    // zero accumulators (agg_in, agg_out, deg, acc0, acc1, x1)
    hipMemsetAsync(d_ws, 0, (size_t)ZERO_END * 4, stream);

    // ---- encoder ----
    k_deg<<<(ETOT + 255) / 256, 256, 0, stream>>>(ei, deg);
    k_dinv<<<(NENT + 255) / 256, 256, 0, stream>>>(deg, dinv);
    k_scatter<<<(ETOT * 50 + 255) / 256, 256, 0, stream>>>(ei, et, emb, init_rel, dinv,
                                                           agg_in, agg_out);
    k_allent<<<NENT / 16, 256, 0, stream>>>(agg_in, agg_out, emb, loop_rel,
                                            w_in, w_out, w_loop, all_ent);
    k_rmat<<<400 / 16, 256, 0, stream>>>(init_rel, w_rel, rmat);

    // ---- decoder ----
    k_cheq<<<(BB * 400) / 256, 256, 0, stream>>>(sub, rel, perm, all_ent, rmat, cheq, acc0);
    k_conv<<<BB, 256, 0, stream>>>(cheq, acc0, bn0_g, bn0_b, filt, o, acc1);
    k_bn1fin<<<1, 128, 0, stream>>>(acc1, bn1_g, bn1_b, bn1s);
    k_fc<<<dim3(BB / 16, 10), 256, 0, stream>>>(o, bn1s, fc_w, x1);
    k_bn2<<<DD, 256, 0, stream>>>(x1, fc_b, bn2_g, bn2_b, x2);
    k_logits<<<dim3((NENT + 255) / 256, BB / 16), 256, 0, stream>>>(x2, all_ent, bias_ent, o);
}

// Round 2
// 2651.880 us; speedup vs baseline: 1.4959x; 1.4959x over previous
//
#include <hip/hip_runtime.h>

// ---------------- problem constants ----------------
#define ETOT  500000
#define EHALF 250000
#define NENT  50000
#define NSEG  (2 * NENT)   // segments: half*NENT + dst
#define DD    200
#define BB    1024
#define NF    96
#define FLAT  38400   // 96*400

// ---------------- workspace layout (float32 offsets) ----------------
#define OFF_AGG      0LL          // 20,000,000  ([0,10M)=agg_in, [10M,20M)=agg_out; all_ent overwrites agg_in)
// zeroed region: [ZSTART, ZEND)
#define ZSTART       20000000LL
#define OFF_CNT      20000000LL   // 100,004 ints (NSEG+1 used; becomes row_start after scan)
#define OFF_ACC0     20100004LL   //          2  (bn0 sum, sumsq)
#define OFF_ACC1     20100006LL   //        192  (bn1 sum[96], sumsq[96])
#define OFF_X1       20100198LL   //    204,800  (fc output, atomic-accumulated)
#define ZEND         20304998LL
// non-zeroed:
#define OFF_CURSOR   20304998LL   //    100,000 ints (copy of row_start for fill)
#define OFF_BSUM     20404998LL   //        128 ints (scan block sums)
#define OFF_ELIST    20405126LL   //    500,000 ints
#define OFF_DINV     20905126LL   //     50,000
#define OFF_RMAT     20955126LL   //     80,000
#define OFF_CHEQ     21035126LL   //    409,600
#define OFF_BN1S     21444726LL   //        192  (scale[96], shift[96])
#define OFF_X2       21444918LL   //    204,800
// total ws need ~= 21,649,718 f32 = 86.6 MB

// ================= CSR build =================

__global__ void k_hist(const int* __restrict__ ei, int* __restrict__ cnt) {
    int e = blockIdx.x * 256 + threadIdx.x;
    if (e < ETOT) {
        int seg = (e < EHALF ? 0 : NENT) + ei[ETOT + e];
        atomicAdd(&cnt[seg], 1);
    }
}

__global__ void k_dinv(const int* __restrict__ cnt, float* __restrict__ dinv) {
    int i = blockIdx.x * 256 + threadIdx.x;
    if (i < NENT) {
        int d = cnt[i] + cnt[NENT + i];
        dinv[i] = d > 0 ? rsqrtf((float)d) : 0.f;
    }
}

// exclusive scan over cnt[0..NSEG] (100001 elements), chunk=1024/block
__global__ void k_scan1(int* __restrict__ cnt, int* __restrict__ bsum) {
    __shared__ int S[256];
    int base = blockIdx.x * 1024 + threadIdx.x * 4;
    int v[4], s = 0;
#pragma unroll
    for (int i = 0; i < 4; i++) { v[i] = (base + i <= NSEG) ? cnt[base + i] : 0; s += v[i]; }
    S[threadIdx.x] = s;
    __syncthreads();
    for (int off = 1; off < 256; off <<= 1) {
        int t = (threadIdx.x >= off) ? S[threadIdx.x - off] : 0;
        __syncthreads();
        S[threadIdx.x] += t;
        __syncthreads();
    }
    int run = S[threadIdx.x] - s;   // exclusive prefix of this thread within block
#pragma unroll
    for (int i = 0; i < 4; i++) {
        if (base + i <= NSEG) cnt[base + i] = run;
        run += v[i];
    }
    if (threadIdx.x == 255) bsum[blockIdx.x] = S[255];
}

__global__ void k_scan2(int* __restrict__ bsum) {
    __shared__ int S[128];
    int v = (threadIdx.x < 98) ? bsum[threadIdx.x] : 0;
    S[threadIdx.x] = v;
    __syncthreads();
    for (int off = 1; off < 128; off <<= 1) {
        int t = (threadIdx.x >= off) ? S[threadIdx.x - off] : 0;
        __syncthreads();
        S[threadIdx.x] += t;
        __syncthreads();
    }
    if (threadIdx.x < 98) bsum[threadIdx.x] = S[threadIdx.x] - v;   // exclusive
}

__global__ void k_scan3(int* __restrict__ cnt, const int* __restrict__ bsum,
                        int* __restrict__ cursor) {
    int add = bsum[blockIdx.x];
    int base = blockIdx.x * 1024 + threadIdx.x * 4;
#pragma unroll
    for (int i = 0; i < 4; i++) {
        int idx = base + i;
        if (idx <= NSEG) {
            int v = cnt[idx] + add;
            cnt[idx] = v;                 // row_start
            if (idx < NSEG) cursor[idx] = v;
        }
    }
}

__global__ void k_fill(const int* __restrict__ ei, int* __restrict__ cursor,
                       int* __restrict__ elist) {
    int e = blockIdx.x * 256 + threadIdx.x;
    if (e < ETOT) {
        int seg = (e < EHALF ? 0 : NENT) + ei[ETOT + e];
        int pos = atomicAdd(&cursor[seg], 1);
        elist[pos] = e;
    }
}

// gather-aggregate: one wave per segment (4 waves/block), no float atomics
__global__ void k_agg(const int* __restrict__ ei, const int* __restrict__ et,
                      const int* __restrict__ row_start, const int* __restrict__ elist,
                      const float* __restrict__ emb, const float* __restrict__ rel,
                      const float* __restrict__ dinv, float* __restrict__ agg) {
    int seg = blockIdx.x * 4 + (threadIdx.x >> 6);
    int lane = threadIdx.x & 63;
    int dst = seg - (seg >= NENT ? NENT : 0);
    float dd = dinv[dst];
    int s = row_start[seg], e = row_start[seg + 1];
    bool act = lane < 50;
    float4 acc = {0.f, 0.f, 0.f, 0.f};
    for (int i = s; i < e; i++) {
        int ed = elist[i];
        int src = ei[ed];
        int t = et[ed];
        float nrm = dinv[src] * dd;
        if (act) {
            float4 a = *(const float4*)&emb[(long long)src * DD + lane * 4];
            float4 b = *(const float4*)&rel[t * DD + lane * 4];
            acc.x += (a.x - b.x) * nrm;
            acc.y += (a.y - b.y) * nrm;
            acc.z += (a.z - b.z) * nrm;
            acc.w += (a.w - b.w) * nrm;
        }
    }
    if (act) *(float4*)&agg[(long long)seg * DD + lane * 4] = acc;
}

// ================= encoder GEMMs =================

// all_ent = tanh((agg_in@w_in + agg_out@w_out + (embed-loop_rel)@w_loop)/3), in place over agg_in
__global__ void k_allent(const float* __restrict__ agg_in, const float* __restrict__ agg_out,
                         const float* __restrict__ emb, const float* __restrict__ loop_rel,
                         const float* __restrict__ w_in, const float* __restrict__ w_out,
                         const float* __restrict__ w_loop, float* __restrict__ all_ent) {
    __shared__ float S[3][16][DD];   // 38.4 KB
    int r0 = blockIdx.x * 16;
    for (int i = threadIdx.x; i < 16 * DD; i += 256) {
        int rr = i / DD, k = i % DD;
        long long g = (long long)(r0 + rr) * DD + k;
        S[0][rr][k] = agg_in[g];
        S[1][rr][k] = agg_out[g];
        S[2][rr][k] = emb[g] - loop_rel[k];
    }
    __syncthreads();
    int j = threadIdx.x;
    if (j < DD) {
        float acc[16];
#pragma unroll
        for (int rr = 0; rr < 16; rr++) acc[rr] = 0.f;
        for (int k = 0; k < DD; k += 4) {
            float w0x = w_in[(k + 0) * DD + j], w0y = w_in[(k + 1) * DD + j],
                  w0z = w_in[(k + 2) * DD + j], w0w = w_in[(k + 3) * DD + j];
            float w1x = w_out[(k + 0) * DD + j], w1y = w_out[(k + 1) * DD + j],
                  w1z = w_out[(k + 2) * DD + j], w1w = w_out[(k + 3) * DD + j];
            float w2x = w_loop[(k + 0) * DD + j], w2y = w_loop[(k + 1) * DD + j],
                  w2z = w_loop[(k + 2) * DD + j], w2w = w_loop[(k + 3) * DD + j];
#pragma unroll
            for (int rr = 0; rr < 16; rr++) {
                float4 a = *(const float4*)&S[0][rr][k];
                float4 b = *(const float4*)&S[1][rr][k];
                float4 c = *(const float4*)&S[2][rr][k];
                acc[rr] += a.x * w0x + a.y * w0y + a.z * w0z + a.w * w0w
                         + b.x * w1x + b.y * w1y + b.z * w1z + b.w * w1w
                         + c.x * w2x + c.y * w2y + c.z * w2z + c.w * w2w;
            }
        }
#pragma unroll
        for (int rr = 0; rr < 16; rr++)
            all_ent[(long long)(r0 + rr) * DD + j] = tanhf(acc[rr] * (1.f / 3.f));
    }
}

// r = init_rel @ w_rel   [400,200]@[200,200]
__global__ void k_rmat(const float* __restrict__ init_rel, const float* __restrict__ w_rel,
                       float* __restrict__ rmat) {
    __shared__ float S[16][DD];
    int r0 = blockIdx.x * 16;
    for (int i = threadIdx.x; i < 16 * DD; i += 256)
        S[i / DD][i % DD] = init_rel[(r0 + i / DD) * DD + i % DD];
    __syncthreads();
    int j = threadIdx.x;
    if (j < DD) {
        float acc[16];
#pragma unroll
        for (int rr = 0; rr < 16; rr++) acc[rr] = 0.f;
        for (int k = 0; k < DD; k += 4) {
            float wx = w_rel[(k + 0) * DD + j], wy = w_rel[(k + 1) * DD + j],
                  wz = w_rel[(k + 2) * DD + j], ww = w_rel[(k + 3) * DD + j];
#pragma unroll
            for (int rr = 0; rr < 16; rr++) {
                float4 a = *(const float4*)&S[rr][k];
                acc[rr] += a.x * wx + a.y * wy + a.z * wz + a.w * ww;
            }
        }
#pragma unroll
        for (int rr = 0; rr < 16; rr++) rmat[(r0 + rr) * DD + j] = acc[rr];
    }
}

// ================= decoder =================

// chequer gather + bn0 statistics
__global__ void k_cheq(const int* __restrict__ sub, const int* __restrict__ rel,
                       const int* __restrict__ perm, const float* __restrict__ all_ent,
                       const float* __restrict__ rmat, float* __restrict__ cheq,
                       float* __restrict__ acc0) {
    int i = blockIdx.x * 256 + threadIdx.x;   // over B*400 = 409600 exactly
    int b = i / 400, p = i % 400;
    int c = perm[p];
    float v = (c < DD) ? all_ent[(long long)sub[b] * DD + c]
                       : rmat[rel[b] * DD + (c - DD)];
    cheq[i] = v;
    __shared__ float s1[256], s2[256];
    s1[threadIdx.x] = v;
    s2[threadIdx.x] = v * v;
    __syncthreads();
    for (int st = 128; st > 0; st >>= 1) {
        if (threadIdx.x < st) { s1[threadIdx.x] += s1[threadIdx.x + st]; s2[threadIdx.x] += s2[threadIdx.x + st]; }
        __syncthreads();
    }
    if (threadIdx.x == 0) { atomicAdd(&acc0[0], s1[0]); atomicAdd(&acc0[1], s2[0]); }
}

// bn0-normalize + circular pad + 9x9 conv (96 filt) + bn1 stats. conv out -> d_out scratch (f32)
__global__ void k_conv(const float* __restrict__ cheq, const float* __restrict__ acc0,
                       const float* __restrict__ bn0_g, const float* __restrict__ bn0_b,
                       const float* __restrict__ filt, float* __restrict__ conv_out,
                       float* __restrict__ acc1) {
    __shared__ float xp[28 * 28];
    __shared__ float fl[NF * 81];
    __shared__ float csum[NF], csq[NF];
    int b = blockIdx.x;
    const float invN = 1.f / (BB * 400.f);
    float mean = acc0[0] * invN;
    float var = acc0[1] * invN - mean * mean;
    float sc = rsqrtf(var + 1e-5f) * bn0_g[0];
    float sh = bn0_b[0] - mean * sc;
    for (int i = threadIdx.x; i < 28 * 28; i += 256) {
        int r = i / 28, c = i % 28;
        int rr = (r + 16) % 20, cc = (c + 16) % 20;   // (idx-4) mod 20
        xp[i] = cheq[b * 400 + rr * 20 + cc] * sc + sh;
    }
    for (int i = threadIdx.x; i < NF * 81; i += 256) fl[i] = filt[i];
    if (threadIdx.x < NF) { csum[threadIdx.x] = 0.f; csq[threadIdx.x] = 0.f; }
    __syncthreads();
    for (int t = threadIdx.x; t < NF * 20; t += 256) {
        int ch = t / 20, row = t % 20;
        float acc[20];
#pragma unroll
        for (int c2 = 0; c2 < 20; c2++) acc[c2] = 0.f;
        for (int di = 0; di < 9; di++) {
            const float* xrow = &xp[(row + di) * 28];
#pragma unroll
            for (int dj = 0; dj < 9; dj++) {
                float f = fl[ch * 81 + di * 9 + dj];
#pragma unroll
                for (int c2 = 0; c2 < 20; c2++) acc[c2] = fmaf(xrow[c2 + dj], f, acc[c2]);
            }
        }
        float s = 0.f, q = 0.f;
        long long base = (long long)b * FLAT + ch * 400 + row * 20;
#pragma unroll
        for (int c2 = 0; c2 < 20; c2++) {
            float v = acc[c2];
            s += v; q += v * v;
            conv_out[base + c2] = v;
        }
        atomicAdd(&csum[ch], s);
        atomicAdd(&csq[ch], q);
    }
    __syncthreads();
    if (threadIdx.x < NF) {
        atomicAdd(&acc1[threadIdx.x], csum[threadIdx.x]);
        atomicAdd(&acc1[NF + threadIdx.x], csq[threadIdx.x]);
    }
}

__global__ void k_bn1fin(const float* __restrict__ acc1, const float* __restrict__ g1,
                         const float* __restrict__ b1, float* __restrict__ bn1s) {
    int c = threadIdx.x;
    if (c >= NF) return;
    const float invN = 1.f / (BB * 400.f);
    float m = acc1[c] * invN;
    float v = acc1[NF + c] * invN - m * m;
    float sc = rsqrtf(v + 1e-5f) * g1[c];
    bn1s[c] = sc;
    bn1s[NF + c] = b1[c] - m * sc;
}

// fc: x1[b][j] = sum_k relu(bn1(conv)) * fc_w[j][k]; grid = (64 b-tiles, 10 k-slices); atomic acc
__global__ void k_fc(const float* __restrict__ conv_out, const float* __restrict__ bn1s,
                     const float* __restrict__ fc_w, float* __restrict__ x1) {
    __shared__ float As[16][256];   // 16 KB
    int b0 = blockIdx.x * 16;
    int kslice = blockIdx.y;        // 10 slices of 3840 = 15 chunks of 256
    int j = threadIdx.x;
    float acc[16];
#pragma unroll
    for (int bi = 0; bi < 16; bi++) acc[bi] = 0.f;
    for (int chunk = 0; chunk < 15; chunk++) {
        int kb = kslice * 3840 + chunk * 256;
        __syncthreads();
        int k = kb + threadIdx.x;
        int ch = k / 400;
        float scl = bn1s[ch], shf = bn1s[NF + ch];
        for (int bi = 0; bi < 16; bi++) {
            float v = conv_out[(long long)(b0 + bi) * FLAT + k] * scl + shf;
            As[bi][threadIdx.x] = fmaxf(v, 0.f);
        }
        __syncthreads();
        if (j < DD) {
            for (int kk = 0; kk < 256; kk += 4) {
                float4 w = *(const float4*)&fc_w[(long long)j * FLAT + kb + kk];
#pragma unroll
                for (int bi = 0; bi < 16; bi++) {
                    float4 a = *(const float4*)&As[bi][kk];
                    acc[bi] += a.x * w.x + a.y * w.y + a.z * w.z + a.w * w.w;
                }
            }
        }
    }
    if (j < DD) {
#pragma unroll
        for (int bi = 0; bi < 16; bi++) atomicAdd(&x1[(b0 + bi) * DD + j], acc[bi]);
    }
}

// bn2 (per-feature over batch) + relu -> x2. one block per feature j.
__global__ void k_bn2(const float* __restrict__ x1, const float* __restrict__ fc_b,
                      const float* __restrict__ g2, const float* __restrict__ b2,
                      float* __restrict__ x2) {
    int j = blockIdx.x;
    float vals[4];
    float s = 0.f, q = 0.f;
#pragma unroll
    for (int i = 0; i < 4; i++) {
        int b = threadIdx.x + i * 256;
        float v = x1[b * DD + j] + fc_b[j];
        vals[i] = v;
        s += v; q += v * v;
    }
    __shared__ float r1[256], r2[256];
    __shared__ float bc[2];
    r1[threadIdx.x] = s; r2[threadIdx.x] = q;
    __syncthreads();
    for (int st = 128; st > 0; st >>= 1) {
        if (threadIdx.x < st) { r1[threadIdx.x] += r1[threadIdx.x + st]; r2[threadIdx.x] += r2[threadIdx.x + st]; }
        __syncthreads();
    }
    if (threadIdx.x == 0) {
        float m = r1[0] * (1.f / BB);
        float v = r2[0] * (1.f / BB) - m * m;
        float sc = rsqrtf(v + 1e-5f) * g2[j];
        bc[0] = sc; bc[1] = b2[j] - m * sc;
    }
    __syncthreads();
    float sc = bc[0], sh = bc[1];
#pragma unroll
    for (int i = 0; i < 4; i++) {
        int b = threadIdx.x + i * 256;
        x2[b * DD + j] = fmaxf(vals[i] * sc + sh, 0.f);
    }
}

// logits = sigmoid(x2 @ all_ent^T + bias)
__global__ void k_logits(const float* __restrict__ x2, const float* __restrict__ all_ent,
                         const float* __restrict__ bias, float* __restrict__ out) {
    __shared__ float X[16][DD];   // 12.8 KB
    int e0 = blockIdx.x * 256;
    int b0 = blockIdx.y * 16;
    for (int i = threadIdx.x; i < 16 * DD; i += 256)
        X[i / DD][i % DD] = x2[(b0 + i / DD) * DD + i % DD];
    __syncthreads();
    int e = e0 + threadIdx.x;
    if (e >= NENT) return;
    float acc[16];
#pragma unroll
    for (int bi = 0; bi < 16; bi++) acc[bi] = 0.f;
    for (int k = 0; k < DD; k += 4) {
        float4 a = *(const float4*)&all_ent[(long long)e * DD + k];
#pragma unroll
        for (int bi = 0; bi < 16; bi++) {
            float4 x = *(const float4*)&X[bi][k];
            acc[bi] += a.x * x.x + a.y * x.y + a.z * x.z + a.w * x.w;
        }
    }
    float bv = bias[e];
#pragma unroll
    for (int bi = 0; bi < 16; bi++) {
        float t = acc[bi] + bv;
        out[(long long)(b0 + bi) * NENT + e] = 1.f / (1.f + expf(-t));
    }
}

// ================= host =================

extern "C" void kernel_launch(void* const* d_in, const int* in_sizes, int n_in,
                              void* d_out, int out_size, void* d_ws, size_t ws_size,
                              hipStream_t stream) {
    const int*   sub      = (const int*)d_in[0];
    const int*   rel      = (const int*)d_in[1];
    // d_in[2] = neg_ents (unused in forward)
    const int*   ei       = (const int*)d_in[3];
    const int*   et       = (const int*)d_in[4];
    const int*   perm     = (const int*)d_in[5];
    const float* emb      = (const float*)d_in[6];
    const float* init_rel = (const float*)d_in[7];
    const float* w_in     = (const float*)d_in[8];
    const float* w_out    = (const float*)d_in[9];
    const float* w_loop   = (const float*)d_in[10];
    const float* w_rel    = (const float*)d_in[11];
    const float* loop_rel = (const float*)d_in[12];
    const float* bn0_g    = (const float*)d_in[13];
    const float* bn0_b    = (const float*)d_in[14];
    const float* bn1_g    = (const float*)d_in[15];
    const float* bn1_b    = (const float*)d_in[16];
    const float* bn2_g    = (const float*)d_in[17];
    const float* bn2_b    = (const float*)d_in[18];
    const float* filt     = (const float*)d_in[19];
    const float* fc_w     = (const float*)d_in[20];
    const float* fc_b     = (const float*)d_in[21];
    const float* bias_ent = (const float*)d_in[22];

    float* ws  = (float*)d_ws;
    float* o   = (float*)d_out;   // also used as conv scratch (157MB < 205MB), fully overwritten by k_logits

    float* agg     = ws + OFF_AGG;            // [NSEG][DD]: in rows [0,NENT), out rows [NENT,NSEG)
    float* agg_in  = agg;
    float* agg_out = agg + (long long)NENT * DD;
    int*   cnt     = (int*)(ws + OFF_CNT);    // row_start after scan
    int*   cursor  = (int*)(ws + OFF_CURSOR);
    int*   bsum    = (int*)(ws + OFF_BSUM);
    int*   elist   = (int*)(ws + OFF_ELIST);
    float* acc0    = ws + OFF_ACC0;
    float* acc1    = ws + OFF_ACC1;
    float* x1      = ws + OFF_X1;
    float* dinv    = ws + OFF_DINV;
    float* rmat    = ws + OFF_RMAT;
    float* cheq    = ws + OFF_CHEQ;
    float* bn1s    = ws + OFF_BN1S;
    float* x2      = ws + OFF_X2;
    float* all_ent = agg_in;      // k_allent writes in place over agg_in (same row indices)

    // zero accumulators (cnt, acc0, acc1, x1) — ~1.2 MB
    hipMemsetAsync(ws + ZSTART, 0, (size_t)(ZEND - ZSTART) * 4, stream);

    // ---- CSR build + gather aggregation (replaces atomic scatter) ----
    k_hist<<<(ETOT + 255) / 256, 256, 0, stream>>>(ei, cnt);
    k_dinv<<<(NENT + 255) / 256, 256, 0, stream>>>(cnt, dinv);
    k_scan1<<<98, 256, 0, stream>>>(cnt, bsum);
    k_scan2<<<1, 128, 0, stream>>>(bsum);
    k_scan3<<<98, 256, 0, stream>>>(cnt, bsum, cursor);
    k_fill<<<(ETOT + 255) / 256, 256, 0, stream>>>(ei, cursor, elist);
    k_agg<<<NSEG / 4, 256, 0, stream>>>(ei, et, cnt, elist, emb, init_rel, dinv, agg);

    // ---- encoder GEMMs ----
    k_allent<<<NENT / 16, 256, 0, stream>>>(agg_in, agg_out, emb, loop_rel,
                                            w_in, w_out, w_loop, all_ent);
    k_rmat<<<400 / 16, 256, 0, stream>>>(init_rel, w_rel, rmat);

    // ---- decoder ----
    k_cheq<<<(BB * 400) / 256, 256, 0, stream>>>(sub, rel, perm, all_ent, rmat, cheq, acc0);
    k_conv<<<BB, 256, 0, stream>>>(cheq, acc0, bn0_g, bn0_b, filt, o, acc1);
    k_bn1fin<<<1, 128, 0, stream>>>(acc1, bn1_g, bn1_b, bn1s);
    k_fc<<<dim3(BB / 16, 10), 256, 0, stream>>>(o, bn1s, fc_w, x1);
    k_bn2<<<DD, 256, 0, stream>>>(x1, fc_b, bn2_g, bn2_b, x2);
    k_logits<<<dim3((NENT + 255) / 256, BB / 16), 256, 0, stream>>>(x2, all_ent, bias_ent, o);
}

// Round 3
// 1669.932 us; speedup vs baseline: 2.3756x; 1.5880x over previous
//
#include <hip/hip_runtime.h>

// ---------------- problem constants ----------------
#define ETOT  500000
#define EHALF 250000
#define NENT  50000
#define NSEG  (2 * NENT)   // segments: half*NENT + dst
#define DD    200
#define BB    1024
#define NF    96
#define FLAT  38400   // 96*400

// ---------------- workspace layout (float32 offsets) ----------------
#define OFF_AGG      0LL          // 20,000,000  ([0,10M)=agg_in->all_ent, [10M,20M)=agg_out->aeh/ael)
// zeroed region: [ZSTART, ZEND)
#define ZSTART       20000000LL
#define OFF_CNT      20000000LL   // 100,004 ints (NSEG+1 used; becomes row_start after scan)
#define OFF_ACC0     20100004LL   //          2  (bn0 sum, sumsq)
#define OFF_ACC1     20100006LL   //        192  (bn1 sum[96], sumsq[96])
#define OFF_X1       20100198LL   //    204,800  (fc output, atomic-accumulated)
#define ZEND         20304998LL
// non-zeroed:
#define OFF_CURSOR   20304998LL   //    100,000 ints (copy of row_start for fill)
#define OFF_BSUM     20404998LL   //        128 ints (scan block sums)
#define OFF_ELIST    20405126LL   //    500,000 ints
#define OFF_DINV     20905126LL   //     50,000
#define OFF_RMAT     20955126LL   //     80,000
#define OFF_CHEQ     21035126LL   //    409,600
#define OFF_BN1S     21444726LL   //        192  (scale[96], shift[96])
#define OFF_X2       21444918LL   //    204,800
#define OFF_X2H      21649720LL   //    102,400 f32 (= 204,800 ushort), 16B-aligned
#define OFF_X2L      21752120LL   //    102,400 f32
// total ws need ~= 21,854,520 f32 = 87.4 MB

typedef __attribute__((ext_vector_type(8))) short bf16x8;
typedef __attribute__((ext_vector_type(4))) float f32x4;

__device__ inline void bf16split(float v, ushort& h, ushort& l) {
    unsigned u = __float_as_uint(v);
    unsigned hu = u & 0xffff0000u;
    h = (ushort)(hu >> 16);
    float lf = v - __uint_as_float(hu);
    l = (ushort)(__float_as_uint(lf) >> 16);
}

// ================= CSR build =================

__global__ void k_hist(const int* __restrict__ ei, int* __restrict__ cnt) {
    int e = blockIdx.x * 256 + threadIdx.x;
    if (e < ETOT) {
        int seg = (e < EHALF ? 0 : NENT) + ei[ETOT + e];
        atomicAdd(&cnt[seg], 1);
    }
}

__global__ void k_dinv(const int* __restrict__ cnt, float* __restrict__ dinv) {
    int i = blockIdx.x * 256 + threadIdx.x;
    if (i < NENT) {
        int d = cnt[i] + cnt[NENT + i];
        dinv[i] = d > 0 ? rsqrtf((float)d) : 0.f;
    }
}

// exclusive scan over cnt[0..NSEG] (100001 elements), chunk=1024/block
__global__ void k_scan1(int* __restrict__ cnt, int* __restrict__ bsum) {
    __shared__ int S[256];
    int base = blockIdx.x * 1024 + threadIdx.x * 4;
    int v[4], s = 0;
#pragma unroll
    for (int i = 0; i < 4; i++) { v[i] = (base + i <= NSEG) ? cnt[base + i] : 0; s += v[i]; }
    S[threadIdx.x] = s;
    __syncthreads();
    for (int off = 1; off < 256; off <<= 1) {
        int t = (threadIdx.x >= off) ? S[threadIdx.x - off] : 0;
        __syncthreads();
        S[threadIdx.x] += t;
        __syncthreads();
    }
    int run = S[threadIdx.x] - s;
#pragma unroll
    for (int i = 0; i < 4; i++) {
        if (base + i <= NSEG) cnt[base + i] = run;
        run += v[i];
    }
    if (threadIdx.x == 255) bsum[blockIdx.x] = S[255];
}

__global__ void k_scan2(int* __restrict__ bsum) {
    __shared__ int S[128];
    int v = (threadIdx.x < 98) ? bsum[threadIdx.x] : 0;
    S[threadIdx.x] = v;
    __syncthreads();
    for (int off = 1; off < 128; off <<= 1) {
        int t = (threadIdx.x >= off) ? S[threadIdx.x - off] : 0;
        __syncthreads();
        S[threadIdx.x] += t;
        __syncthreads();
    }
    if (threadIdx.x < 98) bsum[threadIdx.x] = S[threadIdx.x] - v;
}

__global__ void k_scan3(int* __restrict__ cnt, const int* __restrict__ bsum,
                        int* __restrict__ cursor) {
    int add = bsum[blockIdx.x];
    int base = blockIdx.x * 1024 + threadIdx.x * 4;
#pragma unroll
    for (int i = 0; i < 4; i++) {
        int idx = base + i;
        if (idx <= NSEG) {
            int v = cnt[idx] + add;
            cnt[idx] = v;
            if (idx < NSEG) cursor[idx] = v;
        }
    }
}

__global__ void k_fill(const int* __restrict__ ei, int* __restrict__ cursor,
                       int* __restrict__ elist) {
    int e = blockIdx.x * 256 + threadIdx.x;
    if (e < ETOT) {
        int seg = (e < EHALF ? 0 : NENT) + ei[ETOT + e];
        int pos = atomicAdd(&cursor[seg], 1);
        elist[pos] = e;
    }
}

// gather-aggregate: one wave per segment (4 waves/block), no float atomics
__global__ void k_agg(const int* __restrict__ ei, const int* __restrict__ et,
                      const int* __restrict__ row_start, const int* __restrict__ elist,
                      const float* __restrict__ emb, const float* __restrict__ rel,
                      const float* __restrict__ dinv, float* __restrict__ agg) {
    int seg = blockIdx.x * 4 + (threadIdx.x >> 6);
    int lane = threadIdx.x & 63;
    int dst = seg - (seg >= NENT ? NENT : 0);
    float dd = dinv[dst];
    int s = row_start[seg], e = row_start[seg + 1];
    bool act = lane < 50;
    float4 acc = {0.f, 0.f, 0.f, 0.f};
    for (int i = s; i < e; i++) {
        int ed = elist[i];
        int src = ei[ed];
        int t = et[ed];
        float nrm = dinv[src] * dd;
        if (act) {
            float4 a = *(const float4*)&emb[(long long)src * DD + lane * 4];
            float4 b = *(const float4*)&rel[t * DD + lane * 4];
            acc.x += (a.x - b.x) * nrm;
            acc.y += (a.y - b.y) * nrm;
            acc.z += (a.z - b.z) * nrm;
            acc.w += (a.w - b.w) * nrm;
        }
    }
    if (act) *(float4*)&agg[(long long)seg * DD + lane * 4] = acc;
}

// ================= encoder GEMMs =================

__global__ void k_allent(const float* __restrict__ agg_in, const float* __restrict__ agg_out,
                         const float* __restrict__ emb, const float* __restrict__ loop_rel,
                         const float* __restrict__ w_in, const float* __restrict__ w_out,
                         const float* __restrict__ w_loop, float* __restrict__ all_ent) {
    __shared__ float S[3][16][DD];   // 38.4 KB
    int r0 = blockIdx.x * 16;
    for (int i = threadIdx.x; i < 16 * DD; i += 256) {
        int rr = i / DD, k = i % DD;
        long long g = (long long)(r0 + rr) * DD + k;
        S[0][rr][k] = agg_in[g];
        S[1][rr][k] = agg_out[g];
        S[2][rr][k] = emb[g] - loop_rel[k];
    }
    __syncthreads();
    int j = threadIdx.x;
    if (j < DD) {
        float acc[16];
#pragma unroll
        for (int rr = 0; rr < 16; rr++) acc[rr] = 0.f;
        for (int k = 0; k < DD; k += 4) {
            float w0x = w_in[(k + 0) * DD + j], w0y = w_in[(k + 1) * DD + j],
                  w0z = w_in[(k + 2) * DD + j], w0w = w_in[(k + 3) * DD + j];
            float w1x = w_out[(k + 0) * DD + j], w1y = w_out[(k + 1) * DD + j],
                  w1z = w_out[(k + 2) * DD + j], w1w = w_out[(k + 3) * DD + j];
            float w2x = w_loop[(k + 0) * DD + j], w2y = w_loop[(k + 1) * DD + j],
                  w2z = w_loop[(k + 2) * DD + j], w2w = w_loop[(k + 3) * DD + j];
#pragma unroll
            for (int rr = 0; rr < 16; rr++) {
                float4 a = *(const float4*)&S[0][rr][k];
                float4 b = *(const float4*)&S[1][rr][k];
                float4 c = *(const float4*)&S[2][rr][k];
                acc[rr] += a.x * w0x + a.y * w0y + a.z * w0z + a.w * w0w
                         + b.x * w1x + b.y * w1y + b.z * w1z + b.w * w1w
                         + c.x * w2x + c.y * w2y + c.z * w2z + c.w * w2w;
            }
        }
#pragma unroll
        for (int rr = 0; rr < 16; rr++)
            all_ent[(long long)(r0 + rr) * DD + j] = tanhf(acc[rr] * (1.f / 3.f));
    }
}

// convert all_ent f32 -> bf16 hi/lo (over agg_out region), 4 elems/thread
__global__ void k_cvt(const float* __restrict__ src, ushort* __restrict__ hi,
                      ushort* __restrict__ lo) {
    long long i = (long long)(blockIdx.x * 256 + threadIdx.x) * 4;
    if (i >= (long long)NENT * DD) return;
    float4 v = *(const float4*)&src[i];
    ushort4 h, l;
    bf16split(v.x, h.x, l.x);
    bf16split(v.y, h.y, l.y);
    bf16split(v.z, h.z, l.z);
    bf16split(v.w, h.w, l.w);
    *(ushort4*)&hi[i] = h;
    *(ushort4*)&lo[i] = l;
}

__global__ void k_rmat(const float* __restrict__ init_rel, const float* __restrict__ w_rel,
                       float* __restrict__ rmat) {
    __shared__ float S[16][DD];
    int r0 = blockIdx.x * 16;
    for (int i = threadIdx.x; i < 16 * DD; i += 256)
        S[i / DD][i % DD] = init_rel[(r0 + i / DD) * DD + i % DD];
    __syncthreads();
    int j = threadIdx.x;
    if (j < DD) {
        float acc[16];
#pragma unroll
        for (int rr = 0; rr < 16; rr++) acc[rr] = 0.f;
        for (int k = 0; k < DD; k += 4) {
            float wx = w_rel[(k + 0) * DD + j], wy = w_rel[(k + 1) * DD + j],
                  wz = w_rel[(k + 2) * DD + j], ww = w_rel[(k + 3) * DD + j];
#pragma unroll
            for (int rr = 0; rr < 16; rr++) {
                float4 a = *(const float4*)&S[rr][k];
                acc[rr] += a.x * wx + a.y * wy + a.z * wz + a.w * ww;
            }
        }
#pragma unroll
        for (int rr = 0; rr < 16; rr++) rmat[(r0 + rr) * DD + j] = acc[rr];
    }
}

// ================= decoder =================

__global__ void k_cheq(const int* __restrict__ sub, const int* __restrict__ rel,
                       const int* __restrict__ perm, const float* __restrict__ all_ent,
                       const float* __restrict__ rmat, float* __restrict__ cheq,
                       float* __restrict__ acc0) {
    int i = blockIdx.x * 256 + threadIdx.x;
    int b = i / 400, p = i % 400;
    int c = perm[p];
    float v = (c < DD) ? all_ent[(long long)sub[b] * DD + c]
                       : rmat[rel[b] * DD + (c - DD)];
    cheq[i] = v;
    __shared__ float s1[256], s2[256];
    s1[threadIdx.x] = v;
    s2[threadIdx.x] = v * v;
    __syncthreads();
    for (int st = 128; st > 0; st >>= 1) {
        if (threadIdx.x < st) { s1[threadIdx.x] += s1[threadIdx.x + st]; s2[threadIdx.x] += s2[threadIdx.x + st]; }
        __syncthreads();
    }
    if (threadIdx.x == 0) { atomicAdd(&acc0[0], s1[0]); atomicAdd(&acc0[1], s2[0]); }
}

__global__ void k_conv(const float* __restrict__ cheq, const float* __restrict__ acc0,
                       const float* __restrict__ bn0_g, const float* __restrict__ bn0_b,
                       const float* __restrict__ filt, float* __restrict__ conv_out,
                       float* __restrict__ acc1) {
    __shared__ float xp[28 * 28];
    __shared__ float fl[NF * 81];
    __shared__ float csum[NF], csq[NF];
    int b = blockIdx.x;
    const float invN = 1.f / (BB * 400.f);
    float mean = acc0[0] * invN;
    float var = acc0[1] * invN - mean * mean;
    float sc = rsqrtf(var + 1e-5f) * bn0_g[0];
    float sh = bn0_b[0] - mean * sc;
    for (int i = threadIdx.x; i < 28 * 28; i += 256) {
        int r = i / 28, c = i % 28;
        int rr = (r + 16) % 20, cc = (c + 16) % 20;
        xp[i] = cheq[b * 400 + rr * 20 + cc] * sc + sh;
    }
    for (int i = threadIdx.x; i < NF * 81; i += 256) fl[i] = filt[i];
    if (threadIdx.x < NF) { csum[threadIdx.x] = 0.f; csq[threadIdx.x] = 0.f; }
    __syncthreads();
    for (int t = threadIdx.x; t < NF * 20; t += 256) {
        int ch = t / 20, row = t % 20;
        float acc[20];
#pragma unroll
        for (int c2 = 0; c2 < 20; c2++) acc[c2] = 0.f;
        for (int di = 0; di < 9; di++) {
            const float* xrow = &xp[(row + di) * 28];
#pragma unroll
            for (int dj = 0; dj < 9; dj++) {
                float f = fl[ch * 81 + di * 9 + dj];
#pragma unroll
                for (int c2 = 0; c2 < 20; c2++) acc[c2] = fmaf(xrow[c2 + dj], f, acc[c2]);
            }
        }
        float s = 0.f, q = 0.f;
        long long base = (long long)b * FLAT + ch * 400 + row * 20;
#pragma unroll
        for (int c2 = 0; c2 < 20; c2++) {
            float v = acc[c2];
            s += v; q += v * v;
            conv_out[base + c2] = v;
        }
        atomicAdd(&csum[ch], s);
        atomicAdd(&csq[ch], q);
    }
    __syncthreads();
    if (threadIdx.x < NF) {
        atomicAdd(&acc1[threadIdx.x], csum[threadIdx.x]);
        atomicAdd(&acc1[NF + threadIdx.x], csq[threadIdx.x]);
    }
}

__global__ void k_bn1fin(const float* __restrict__ acc1, const float* __restrict__ g1,
                         const float* __restrict__ b1, float* __restrict__ bn1s) {
    int c = threadIdx.x;
    if (c >= NF) return;
    const float invN = 1.f / (BB * 400.f);
    float m = acc1[c] * invN;
    float v = acc1[NF + c] * invN - m * m;
    float sc = rsqrtf(v + 1e-5f) * g1[c];
    bn1s[c] = sc;
    bn1s[NF + c] = b1[c] - m * sc;
}

__global__ void k_fc(const float* __restrict__ conv_out, const float* __restrict__ bn1s,
                     const float* __restrict__ fc_w, float* __restrict__ x1) {
    __shared__ float As[16][256];
    int b0 = blockIdx.x * 16;
    int kslice = blockIdx.y;
    int j = threadIdx.x;
    float acc[16];
#pragma unroll
    for (int bi = 0; bi < 16; bi++) acc[bi] = 0.f;
    for (int chunk = 0; chunk < 15; chunk++) {
        int kb = kslice * 3840 + chunk * 256;
        __syncthreads();
        int k = kb + threadIdx.x;
        int ch = k / 400;
        float scl = bn1s[ch], shf = bn1s[NF + ch];
        for (int bi = 0; bi < 16; bi++) {
            float v = conv_out[(long long)(b0 + bi) * FLAT + k] * scl + shf;
            As[bi][threadIdx.x] = fmaxf(v, 0.f);
        }
        __syncthreads();
        if (j < DD) {
            for (int kk = 0; kk < 256; kk += 4) {
                float4 w = *(const float4*)&fc_w[(long long)j * FLAT + kb + kk];
#pragma unroll
                for (int bi = 0; bi < 16; bi++) {
                    float4 a = *(const float4*)&As[bi][kk];
                    acc[bi] += a.x * w.x + a.y * w.y + a.z * w.z + a.w * w.w;
                }
            }
        }
    }
    if (j < DD) {
#pragma unroll
        for (int bi = 0; bi < 16; bi++) atomicAdd(&x1[(b0 + bi) * DD + j], acc[bi]);
    }
}

// bn2 + relu -> x2 (f32) and bf16 hi/lo for the MFMA logits kernel
__global__ void k_bn2(const float* __restrict__ x1, const float* __restrict__ fc_b,
                      const float* __restrict__ g2, const float* __restrict__ b2,
                      float* __restrict__ x2, ushort* __restrict__ x2h,
                      ushort* __restrict__ x2l) {
    int j = blockIdx.x;
    float vals[4];
    float s = 0.f, q = 0.f;
#pragma unroll
    for (int i = 0; i < 4; i++) {
        int b = threadIdx.x + i * 256;
        float v = x1[b * DD + j] + fc_b[j];
        vals[i] = v;
        s += v; q += v * v;
    }
    __shared__ float r1[256], r2[256];
    __shared__ float bc[2];
    r1[threadIdx.x] = s; r2[threadIdx.x] = q;
    __syncthreads();
    for (int st = 128; st > 0; st >>= 1) {
        if (threadIdx.x < st) { r1[threadIdx.x] += r1[threadIdx.x + st]; r2[threadIdx.x] += r2[threadIdx.x + st]; }
        __syncthreads();
    }
    if (threadIdx.x == 0) {
        float m = r1[0] * (1.f / BB);
        float v = r2[0] * (1.f / BB) - m * m;
        float sc = rsqrtf(v + 1e-5f) * g2[j];
        bc[0] = sc; bc[1] = b2[j] - m * sc;
    }
    __syncthreads();
    float sc = bc[0], sh = bc[1];
#pragma unroll
    for (int i = 0; i < 4; i++) {
        int b = threadIdx.x + i * 256;
        float v = fmaxf(vals[i] * sc + sh, 0.f);
        x2[b * DD + j] = v;
        ushort h, l;
        bf16split(v, h, l);
        x2h[b * DD + j] = h;
        x2l[b * DD + j] = l;
    }
}

// logits = sigmoid(x2 @ all_ent^T + bias) via bf16-split MFMA (hi*hi + hi*lo + lo*hi)
// block: 512 thr = 8 waves; block tile M64 x N512; wave tile 64x64 (4x4 frags of 16x16x32)
__global__ __launch_bounds__(512) void k_logits_mfma(
        const ushort* __restrict__ x2h, const ushort* __restrict__ x2l,
        const ushort* __restrict__ aeh, const ushort* __restrict__ ael,
        const float* __restrict__ bias, float* __restrict__ out) {
    __shared__ ushort Ah[64 * DD];   // 25.6 KB
    __shared__ ushort Al[64 * DD];   // 25.6 KB
    int m0 = blockIdx.y * 64;
    {   // stage x2 hi/lo tile (contiguous copy, 1600 uint4 each)
        const uint4* g0 = (const uint4*)(x2h + (long long)m0 * DD);
        const uint4* g1 = (const uint4*)(x2l + (long long)m0 * DD);
        uint4* s0 = (uint4*)Ah;
        uint4* s1 = (uint4*)Al;
        for (int i = threadIdx.x; i < 1600; i += 512) { s0[i] = g0[i]; s1[i] = g1[i]; }
    }
    __syncthreads();
    int wid = threadIdx.x >> 6;
    int lane = threadIdx.x & 63;
    int l15 = lane & 15, q = lane >> 4;
    int e0 = blockIdx.x * 512 + wid * 64;

    f32x4 zero4 = {0.f, 0.f, 0.f, 0.f};
    f32x4 acc[4][4];
#pragma unroll
    for (int m = 0; m < 4; m++)
#pragma unroll
        for (int n = 0; n < 4; n++) acc[m][n] = zero4;

    long long brow[4];
#pragma unroll
    for (int n = 0; n < 4; n++) {
        int e = e0 + n * 16 + l15;
        if (e > NENT - 1) e = NENT - 1;
        brow[n] = (long long)e * DD;
    }
    int aoff = q * 8;

#pragma unroll
    for (int kk = 0; kk < 6; kk++) {
        int k0 = kk * 32 + aoff;
        bf16x8 ah[4], al[4], bh[4], bl[4];
#pragma unroll
        for (int m = 0; m < 4; m++) {
            int off = (m * 16 + l15) * DD + k0;
            ah[m] = *(const bf16x8*)&Ah[off];
            al[m] = *(const bf16x8*)&Al[off];
        }
#pragma unroll
        for (int n = 0; n < 4; n++) {
            bh[n] = *(const bf16x8*)&aeh[brow[n] + k0];
            bl[n] = *(const bf16x8*)&ael[brow[n] + k0];
        }
#pragma unroll
        for (int m = 0; m < 4; m++)
#pragma unroll
            for (int n = 0; n < 4; n++) {
                acc[m][n] = __builtin_amdgcn_mfma_f32_16x16x32_bf16(ah[m], bh[n], acc[m][n], 0, 0, 0);
                acc[m][n] = __builtin_amdgcn_mfma_f32_16x16x32_bf16(ah[m], bl[n], acc[m][n], 0, 0, 0);
                acc[m][n] = __builtin_amdgcn_mfma_f32_16x16x32_bf16(al[m], bh[n], acc[m][n], 0, 0, 0);
            }
    }
    {   // partial k-step: k = 192..199 live in quarter 0 only; zeroed A-frags mask the tail
        bf16x8 zf = {0, 0, 0, 0, 0, 0, 0, 0};
        bf16x8 ah[4], al[4], bh[4], bl[4];
#pragma unroll
        for (int m = 0; m < 4; m++) { ah[m] = zf; al[m] = zf; }
#pragma unroll
        for (int n = 0; n < 4; n++) { bh[n] = zf; bl[n] = zf; }
        if (q == 0) {
#pragma unroll
            for (int m = 0; m < 4; m++) {
                int off = (m * 16 + l15) * DD + 192;
                ah[m] = *(const bf16x8*)&Ah[off];
                al[m] = *(const bf16x8*)&Al[off];
            }
#pragma unroll
            for (int n = 0; n < 4; n++) {
                bh[n] = *(const bf16x8*)&aeh[brow[n] + 192];
                bl[n] = *(const bf16x8*)&ael[brow[n] + 192];
            }
        }
#pragma unroll
        for (int m = 0; m < 4; m++)
#pragma unroll
            for (int n = 0; n < 4; n++) {
                acc[m][n] = __builtin_amdgcn_mfma_f32_16x16x32_bf16(ah[m], bh[n], acc[m][n], 0, 0, 0);
                acc[m][n] = __builtin_amdgcn_mfma_f32_16x16x32_bf16(ah[m], bl[n], acc[m][n], 0, 0, 0);
                acc[m][n] = __builtin_amdgcn_mfma_f32_16x16x32_bf16(al[m], bh[n], acc[m][n], 0, 0, 0);
            }
    }
    // epilogue: bias + sigmoid; C layout: row=(q*4+r), col=l15 within each 16x16 frag
#pragma unroll
    for (int n = 0; n < 4; n++) {
        int e = e0 + n * 16 + l15;
        if (e < NENT) {
            float bv = bias[e];
#pragma unroll
            for (int m = 0; m < 4; m++) {
                int row = m0 + m * 16 + q * 4;
#pragma unroll
                for (int r = 0; r < 4; r++) {
                    float t = acc[m][n][r] + bv;
                    out[(long long)(row + r) * NENT + e] = 1.f / (1.f + __expf(-t));
                }
            }
        }
    }
}

// ================= host =================

extern "C" void kernel_launch(void* const* d_in, const int* in_sizes, int n_in,
                              void* d_out, int out_size, void* d_ws, size_t ws_size,
                              hipStream_t stream) {
    const int*   sub      = (const int*)d_in[0];
    const int*   rel      = (const int*)d_in[1];
    const int*   ei       = (const int*)d_in[3];
    const int*   et       = (const int*)d_in[4];
    const int*   perm     = (const int*)d_in[5];
    const float* emb      = (const float*)d_in[6];
    const float* init_rel = (const float*)d_in[7];
    const float* w_in     = (const float*)d_in[8];
    const float* w_out    = (const float*)d_in[9];
    const float* w_loop   = (const float*)d_in[10];
    const float* w_rel    = (const float*)d_in[11];
    const float* loop_rel = (const float*)d_in[12];
    const float* bn0_g    = (const float*)d_in[13];
    const float* bn0_b    = (const float*)d_in[14];
    const float* bn1_g    = (const float*)d_in[15];
    const float* bn1_b    = (const float*)d_in[16];
    const float* bn2_g    = (const float*)d_in[17];
    const float* bn2_b    = (const float*)d_in[18];
    const float* filt     = (const float*)d_in[19];
    const float* fc_w     = (const float*)d_in[20];
    const float* fc_b     = (const float*)d_in[21];
    const float* bias_ent = (const float*)d_in[22];

    float* ws  = (float*)d_ws;
    float* o   = (float*)d_out;   // conv scratch (157MB < 205MB), fully overwritten by k_logits_mfma

    float* agg     = ws + OFF_AGG;
    float* agg_in  = agg;
    float* agg_out = agg + (long long)NENT * DD;
    int*   cnt     = (int*)(ws + OFF_CNT);
    int*   cursor  = (int*)(ws + OFF_CURSOR);
    int*   bsum    = (int*)(ws + OFF_BSUM);
    int*   elist   = (int*)(ws + OFF_ELIST);
    float* acc0    = ws + OFF_ACC0;
    float* acc1    = ws + OFF_ACC1;
    float* x1      = ws + OFF_X1;
    float* dinv    = ws + OFF_DINV;
    float* rmat    = ws + OFF_RMAT;
    float* cheq    = ws + OFF_CHEQ;
    float* bn1s    = ws + OFF_BN1S;
    float* x2      = ws + OFF_X2;
    ushort* x2h    = (ushort*)(ws + OFF_X2H);
    ushort* x2l    = (ushort*)(ws + OFF_X2L);
    float* all_ent = agg_in;                      // k_allent writes in place over agg_in
    ushort* aeh    = (ushort*)agg_out;            // bf16 hi/lo reuse dead agg_out (10M f32 exactly)
    ushort* ael    = aeh + (long long)NENT * DD;

    hipMemsetAsync(ws + ZSTART, 0, (size_t)(ZEND - ZSTART) * 4, stream);

    // ---- CSR build + gather aggregation ----
    k_hist<<<(ETOT + 255) / 256, 256, 0, stream>>>(ei, cnt);
    k_dinv<<<(NENT + 255) / 256, 256, 0, stream>>>(cnt, dinv);
    k_scan1<<<98, 256, 0, stream>>>(cnt, bsum);
    k_scan2<<<1, 128, 0, stream>>>(bsum);
    k_scan3<<<98, 256, 0, stream>>>(cnt, bsum, cursor);
    k_fill<<<(ETOT + 255) / 256, 256, 0, stream>>>(ei, cursor, elist);
    k_agg<<<NSEG / 4, 256, 0, stream>>>(ei, et, cnt, elist, emb, init_rel, dinv, agg);

    // ---- encoder GEMMs ----
    k_allent<<<NENT / 16, 256, 0, stream>>>(agg_in, agg_out, emb, loop_rel,
                                            w_in, w_out, w_loop, all_ent);
    k_cvt<<<((NENT * DD / 4) + 255) / 256, 256, 0, stream>>>(all_ent, aeh, ael);
    k_rmat<<<400 / 16, 256, 0, stream>>>(init_rel, w_rel, rmat);

    // ---- decoder ----
    k_cheq<<<(BB * 400) / 256, 256, 0, stream>>>(sub, rel, perm, all_ent, rmat, cheq, acc0);
    k_conv<<<BB, 256, 0, stream>>>(cheq, acc0, bn0_g, bn0_b, filt, o, acc1);
    k_bn1fin<<<1, 128, 0, stream>>>(acc1, bn1_g, bn1_b, bn1s);
    k_fc<<<dim3(BB / 16, 10), 256, 0, stream>>>(o, bn1s, fc_w, x1);
    k_bn2<<<DD, 256, 0, stream>>>(x1, fc_b, bn2_g, bn2_b, x2, x2h, x2l);
    k_logits_mfma<<<dim3((NENT + 511) / 512, BB / 64), 512, 0, stream>>>(
        x2h, x2l, aeh, ael, bias_ent, o);
}

// Round 4
// 1393.661 us; speedup vs baseline: 2.8465x; 1.1982x over previous
//
#include <hip/hip_runtime.h>

// ---------------- problem constants ----------------
#define ETOT  500000
#define EHALF 250000
#define NENT  50000
#define NSEG  (2 * NENT)   // segments: half*NENT + dst
#define DD    200
#define BB    1024
#define NF    96
#define FLAT  38400   // 96*400

// fc split-K config
#define FC_KS     20
#define FC_KSLICE 1920    // 38400/20
#define FC_CHUNKS 30      // 1920/64

// ---------------- workspace layout (float32 offsets) ----------------
#define OFF_AGG      0LL          // 20,000,000  ([0,10M)=agg_in->all_ent, [10M,20M)=agg_out->aeh/ael)
// zeroed region: [ZSTART, ZEND)
#define ZSTART       20000000LL
#define OFF_CNT      20000000LL   // 100,004 ints (NSEG+1 used; becomes row_start after scan)
#define OFF_ACC0     20100004LL   //          2  (bn0 sum, sumsq)
#define OFF_ACC1     20100006LL   //        192  (bn1 sum[96], sumsq[96])
#define ZEND         20100198LL
// non-zeroed:
#define OFF_CURSOR   20304998LL   //    100,000 ints
#define OFF_BSUM     20404998LL   //        128 ints
#define OFF_ELIST    20405126LL   //    500,000 ints
#define OFF_DINV     20905126LL   //     50,000
#define OFF_RMAT     20955126LL   //     80,000
#define OFF_CHEQ     21035126LL   //    409,600
#define OFF_BN1S     21444726LL   //        192  (scale[96], shift[96])
#define OFF_X2H      21649720LL   //    102,400 f32 (= 204,800 ushort), 16B-aligned
#define OFF_X2L      21752120LL   //    102,400 f32
// total ws need ~= 21,854,520 f32 = 87.4 MB

// ---------------- d_out scratch layout (f32 offsets; out_size = 51,200,000) ----
#define OD_CONV 0LL          // 39,321,600 (1024 x 38400 conv output, f32)
#define OD_FWH  39321600LL   //  3,840,000 f32 = 7,680,000 ushort (fc_w hi plane)
#define OD_FWL  43161600LL   //  3,840,000 f32 (fc_w lo plane)
#define OD_PART 47001600LL   //  4,096,000 f32 (FC_KS x 1024 x 200 partials) -> ends 51,097,600

typedef __attribute__((ext_vector_type(8))) short bf16x8;
typedef __attribute__((ext_vector_type(4))) float f32x4;

__device__ inline void bf16split(float v, ushort& h, ushort& l) {
    unsigned u = __float_as_uint(v);
    unsigned hu = u & 0xffff0000u;
    h = (ushort)(hu >> 16);
    float lf = v - __uint_as_float(hu);
    l = (ushort)(__float_as_uint(lf) >> 16);
}

// ================= CSR build =================

__global__ void k_hist(const int* __restrict__ ei, int* __restrict__ cnt) {
    int e = blockIdx.x * 256 + threadIdx.x;
    if (e < ETOT) {
        int seg = (e < EHALF ? 0 : NENT) + ei[ETOT + e];
        atomicAdd(&cnt[seg], 1);
    }
}

__global__ void k_dinv(const int* __restrict__ cnt, float* __restrict__ dinv) {
    int i = blockIdx.x * 256 + threadIdx.x;
    if (i < NENT) {
        int d = cnt[i] + cnt[NENT + i];
        dinv[i] = d > 0 ? rsqrtf((float)d) : 0.f;
    }
}

__global__ void k_scan1(int* __restrict__ cnt, int* __restrict__ bsum) {
    __shared__ int S[256];
    int base = blockIdx.x * 1024 + threadIdx.x * 4;
    int v[4], s = 0;
#pragma unroll
    for (int i = 0; i < 4; i++) { v[i] = (base + i <= NSEG) ? cnt[base + i] : 0; s += v[i]; }
    S[threadIdx.x] = s;
    __syncthreads();
    for (int off = 1; off < 256; off <<= 1) {
        int t = (threadIdx.x >= off) ? S[threadIdx.x - off] : 0;
        __syncthreads();
        S[threadIdx.x] += t;
        __syncthreads();
    }
    int run = S[threadIdx.x] - s;
#pragma unroll
    for (int i = 0; i < 4; i++) {
        if (base + i <= NSEG) cnt[base + i] = run;
        run += v[i];
    }
    if (threadIdx.x == 255) bsum[blockIdx.x] = S[255];
}

__global__ void k_scan2(int* __restrict__ bsum) {
    __shared__ int S[128];
    int v = (threadIdx.x < 98) ? bsum[threadIdx.x] : 0;
    S[threadIdx.x] = v;
    __syncthreads();
    for (int off = 1; off < 128; off <<= 1) {
        int t = (threadIdx.x >= off) ? S[threadIdx.x - off] : 0;
        __syncthreads();
        S[threadIdx.x] += t;
        __syncthreads();
    }
    if (threadIdx.x < 98) bsum[threadIdx.x] = S[threadIdx.x] - v;
}

__global__ void k_scan3(int* __restrict__ cnt, const int* __restrict__ bsum,
                        int* __restrict__ cursor) {
    int add = bsum[blockIdx.x];
    int base = blockIdx.x * 1024 + threadIdx.x * 4;
#pragma unroll
    for (int i = 0; i < 4; i++) {
        int idx = base + i;
        if (idx <= NSEG) {
            int v = cnt[idx] + add;
            cnt[idx] = v;
            if (idx < NSEG) cursor[idx] = v;
        }
    }
}

__global__ void k_fill(const int* __restrict__ ei, int* __restrict__ cursor,
                       int* __restrict__ elist) {
    int e = blockIdx.x * 256 + threadIdx.x;
    if (e < ETOT) {
        int seg = (e < EHALF ? 0 : NENT) + ei[ETOT + e];
        int pos = atomicAdd(&cursor[seg], 1);
        elist[pos] = e;
    }
}

// gather-aggregate: one wave per segment (4 waves/block), no float atomics
__global__ void k_agg(const int* __restrict__ ei, const int* __restrict__ et,
                      const int* __restrict__ row_start, const int* __restrict__ elist,
                      const float* __restrict__ emb, const float* __restrict__ rel,
                      const float* __restrict__ dinv, float* __restrict__ agg) {
    int seg = blockIdx.x * 4 + (threadIdx.x >> 6);
    int lane = threadIdx.x & 63;
    int dst = seg - (seg >= NENT ? NENT : 0);
    float dd = dinv[dst];
    int s = row_start[seg], e = row_start[seg + 1];
    bool act = lane < 50;
    float4 acc = {0.f, 0.f, 0.f, 0.f};
    for (int i = s; i < e; i++) {
        int ed = elist[i];
        int src = ei[ed];
        int t = et[ed];
        float nrm = dinv[src] * dd;
        if (act) {
            float4 a = *(const float4*)&emb[(long long)src * DD + lane * 4];
            float4 b = *(const float4*)&rel[t * DD + lane * 4];
            acc.x += (a.x - b.x) * nrm;
            acc.y += (a.y - b.y) * nrm;
            acc.z += (a.z - b.z) * nrm;
            acc.w += (a.w - b.w) * nrm;
        }
    }
    if (act) *(float4*)&agg[(long long)seg * DD + lane * 4] = acc;
}

// ================= encoder GEMMs =================

__global__ void k_allent(const float* __restrict__ agg_in, const float* __restrict__ agg_out,
                         const float* __restrict__ emb, const float* __restrict__ loop_rel,
                         const float* __restrict__ w_in, const float* __restrict__ w_out,
                         const float* __restrict__ w_loop, float* __restrict__ all_ent) {
    __shared__ float S[3][16][DD];   // 38.4 KB
    int r0 = blockIdx.x * 16;
    for (int i = threadIdx.x; i < 16 * DD; i += 256) {
        int rr = i / DD, k = i % DD;
        long long g = (long long)(r0 + rr) * DD + k;
        S[0][rr][k] = agg_in[g];
        S[1][rr][k] = agg_out[g];
        S[2][rr][k] = emb[g] - loop_rel[k];
    }
    __syncthreads();
    int j = threadIdx.x;
    if (j < DD) {
        float acc[16];
#pragma unroll
        for (int rr = 0; rr < 16; rr++) acc[rr] = 0.f;
        for (int k = 0; k < DD; k += 4) {
            float w0x = w_in[(k + 0) * DD + j], w0y = w_in[(k + 1) * DD + j],
                  w0z = w_in[(k + 2) * DD + j], w0w = w_in[(k + 3) * DD + j];
            float w1x = w_out[(k + 0) * DD + j], w1y = w_out[(k + 1) * DD + j],
                  w1z = w_out[(k + 2) * DD + j], w1w = w_out[(k + 3) * DD + j];
            float w2x = w_loop[(k + 0) * DD + j], w2y = w_loop[(k + 1) * DD + j],
                  w2z = w_loop[(k + 2) * DD + j], w2w = w_loop[(k + 3) * DD + j];
#pragma unroll
            for (int rr = 0; rr < 16; rr++) {
                float4 a = *(const float4*)&S[0][rr][k];
                float4 b = *(const float4*)&S[1][rr][k];
                float4 c = *(const float4*)&S[2][rr][k];
                acc[rr] += a.x * w0x + a.y * w0y + a.z * w0z + a.w * w0w
                         + b.x * w1x + b.y * w1y + b.z * w1z + b.w * w1w
                         + c.x * w2x + c.y * w2y + c.z * w2z + c.w * w2w;
            }
        }
#pragma unroll
        for (int rr = 0; rr < 16; rr++)
            all_ent[(long long)(r0 + rr) * DD + j] = tanhf(acc[rr] * (1.f / 3.f));
    }
}

// convert all_ent f32 -> bf16 hi/lo (over agg_out region), 4 elems/thread
__global__ void k_cvt(const float* __restrict__ src, ushort* __restrict__ hi,
                      ushort* __restrict__ lo) {
    long long i = (long long)(blockIdx.x * 256 + threadIdx.x) * 4;
    if (i >= (long long)NENT * DD) return;
    float4 v = *(const float4*)&src[i];
    ushort4 h, l;
    bf16split(v.x, h.x, l.x);
    bf16split(v.y, h.y, l.y);
    bf16split(v.z, h.z, l.z);
    bf16split(v.w, h.w, l.w);
    *(ushort4*)&hi[i] = h;
    *(ushort4*)&lo[i] = l;
}

// convert fc_w f32 -> bf16 hi/lo planes (into d_out tail)
__global__ void k_cvtw(const float* __restrict__ src, ushort* __restrict__ hi,
                       ushort* __restrict__ lo) {
    long long i = (long long)(blockIdx.x * 256 + threadIdx.x) * 4;
    if (i >= (long long)DD * FLAT) return;
    float4 v = *(const float4*)&src[i];
    ushort4 h, l;
    bf16split(v.x, h.x, l.x);
    bf16split(v.y, h.y, l.y);
    bf16split(v.z, h.z, l.z);
    bf16split(v.w, h.w, l.w);
    *(ushort4*)&hi[i] = h;
    *(ushort4*)&lo[i] = l;
}

__global__ void k_rmat(const float* __restrict__ init_rel, const float* __restrict__ w_rel,
                       float* __restrict__ rmat) {
    __shared__ float S[16][DD];
    int r0 = blockIdx.x * 16;
    for (int i = threadIdx.x; i < 16 * DD; i += 256)
        S[i / DD][i % DD] = init_rel[(r0 + i / DD) * DD + i % DD];
    __syncthreads();
    int j = threadIdx.x;
    if (j < DD) {
        float acc[16];
#pragma unroll
        for (int rr = 0; rr < 16; rr++) acc[rr] = 0.f;
        for (int k = 0; k < DD; k += 4) {
            float wx = w_rel[(k + 0) * DD + j], wy = w_rel[(k + 1) * DD + j],
                  wz = w_rel[(k + 2) * DD + j], ww = w_rel[(k + 3) * DD + j];
#pragma unroll
            for (int rr = 0; rr < 16; rr++) {
                float4 a = *(const float4*)&S[rr][k];
                acc[rr] += a.x * wx + a.y * wy + a.z * wz + a.w * ww;
            }
        }
#pragma unroll
        for (int rr = 0; rr < 16; rr++) rmat[(r0 + rr) * DD + j] = acc[rr];
    }
}

// ================= decoder =================

__global__ void k_cheq(const int* __restrict__ sub, const int* __restrict__ rel,
                       const int* __restrict__ perm, const float* __restrict__ all_ent,
                       const float* __restrict__ rmat, float* __restrict__ cheq,
                       float* __restrict__ acc0) {
    int i = blockIdx.x * 256 + threadIdx.x;
    int b = i / 400, p = i % 400;
    int c = perm[p];
    float v = (c < DD) ? all_ent[(long long)sub[b] * DD + c]
                       : rmat[rel[b] * DD + (c - DD)];
    cheq[i] = v;
    __shared__ float s1[256], s2[256];
    s1[threadIdx.x] = v;
    s2[threadIdx.x] = v * v;
    __syncthreads();
    for (int st = 128; st > 0; st >>= 1) {
        if (threadIdx.x < st) { s1[threadIdx.x] += s1[threadIdx.x + st]; s2[threadIdx.x] += s2[threadIdx.x + st]; }
        __syncthreads();
    }
    if (threadIdx.x == 0) { atomicAdd(&acc0[0], s1[0]); atomicAdd(&acc0[1], s2[0]); }
}

__global__ void k_conv(const float* __restrict__ cheq, const float* __restrict__ acc0,
                       const float* __restrict__ bn0_g, const float* __restrict__ bn0_b,
                       const float* __restrict__ filt, float* __restrict__ conv_out,
                       float* __restrict__ acc1) {
    __shared__ float xp[28 * 28];
    __shared__ float fl[NF * 81];
    __shared__ float csum[NF], csq[NF];
    int b = blockIdx.x;
    const float invN = 1.f / (BB * 400.f);
    float mean = acc0[0] * invN;
    float var = acc0[1] * invN - mean * mean;
    float sc = rsqrtf(var + 1e-5f) * bn0_g[0];
    float sh = bn0_b[0] - mean * sc;
    for (int i = threadIdx.x; i < 28 * 28; i += 256) {
        int r = i / 28, c = i % 28;
        int rr = (r + 16) % 20, cc = (c + 16) % 20;
        xp[i] = cheq[b * 400 + rr * 20 + cc] * sc + sh;
    }
    for (int i = threadIdx.x; i < NF * 81; i += 256) fl[i] = filt[i];
    if (threadIdx.x < NF) { csum[threadIdx.x] = 0.f; csq[threadIdx.x] = 0.f; }
    __syncthreads();
    for (int t = threadIdx.x; t < NF * 20; t += 256) {
        int ch = t / 20, row = t % 20;
        float acc[20];
#pragma unroll
        for (int c2 = 0; c2 < 20; c2++) acc[c2] = 0.f;
        for (int di = 0; di < 9; di++) {
            const float* xrow = &xp[(row + di) * 28];
#pragma unroll
            for (int dj = 0; dj < 9; dj++) {
                float f = fl[ch * 81 + di * 9 + dj];
#pragma unroll
                for (int c2 = 0; c2 < 20; c2++) acc[c2] = fmaf(xrow[c2 + dj], f, acc[c2]);
            }
        }
        float s = 0.f, q = 0.f;
        long long base = (long long)b * FLAT + ch * 400 + row * 20;
#pragma unroll
        for (int c2 = 0; c2 < 20; c2++) {
            float v = acc[c2];
            s += v; q += v * v;
            conv_out[base + c2] = v;
        }
        atomicAdd(&csum[ch], s);
        atomicAdd(&csq[ch], q);
    }
    __syncthreads();
    if (threadIdx.x < NF) {
        atomicAdd(&acc1[threadIdx.x], csum[threadIdx.x]);
        atomicAdd(&acc1[NF + threadIdx.x], csq[threadIdx.x]);
    }
}

__global__ void k_bn1fin(const float* __restrict__ acc1, const float* __restrict__ g1,
                         const float* __restrict__ b1, float* __restrict__ bn1s) {
    int c = threadIdx.x;
    if (c >= NF) return;
    const float invN = 1.f / (BB * 400.f);
    float m = acc1[c] * invN;
    float v = acc1[NF + c] * invN - m * m;
    float sc = rsqrtf(v + 1e-5f) * g1[c];
    bn1s[c] = sc;
    bn1s[NF + c] = b1[c] - m * sc;
}

// fc GEMM via bf16-split MFMA: part[ks][b][j] = sum_{k in slice} relu(bn1(conv))[b][k] * fc_w[j][k]
// grid (16 M-tiles, FC_KS slices), 128 thr = 2 waves; wave tile 32x208 (2x13 frags 16x16x32)
__global__ __launch_bounds__(128) void k_fc_mfma(
        const float* __restrict__ conv_out, const float* __restrict__ bn1s,
        const ushort* __restrict__ fwh, const ushort* __restrict__ fwl,
        float* __restrict__ part) {
    __shared__ __align__(16) ushort Ah[64][72];   // +8 pad: 2-way banks only
    __shared__ __align__(16) ushort Al[64][72];
    __shared__ __align__(16) ushort Bh[208][72];
    __shared__ __align__(16) ushort Bl[208][72];
    __shared__ float bns[192];
    int tid = threadIdx.x;
    for (int i = tid; i < 192; i += 128) bns[i] = bn1s[i];
    int b0 = blockIdx.x * 64;
    int ksl = blockIdx.y;
    int kbase = ksl * FC_KSLICE;
    int wid = tid >> 6, lane = tid & 63, l15 = lane & 15, q = lane >> 4;

    f32x4 zero4 = {0.f, 0.f, 0.f, 0.f};
    f32x4 acc[2][13];
#pragma unroll
    for (int m = 0; m < 2; m++)
#pragma unroll
        for (int n = 0; n < 13; n++) acc[m][n] = zero4;

    for (int c = 0; c < FC_CHUNKS; c++) {
        int k0 = kbase + c * 64;
        __syncthreads();   // previous compute done before restaging
        // stage A: 64 rows x 64 k, bn1+relu+split on the fly
        for (int i = tid; i < 256; i += 128) {
            int row = i >> 2, seg = i & 3;
            const float* src = &conv_out[(long long)(b0 + row) * FLAT + k0 + seg * 16];
#pragma unroll
            for (int s = 0; s < 4; s++) {
                float4 v = *(const float4*)&src[s * 4];
                int kk = k0 + seg * 16 + s * 4;
                int ch = kk / 400;    // 4 | 400 -> all 4 elems same channel
                float sc = bns[ch], sh = bns[96 + ch];
                ushort4 h, l;
                float e0 = fmaxf(v.x * sc + sh, 0.f);
                float e1 = fmaxf(v.y * sc + sh, 0.f);
                float e2 = fmaxf(v.z * sc + sh, 0.f);
                float e3 = fmaxf(v.w * sc + sh, 0.f);
                bf16split(e0, h.x, l.x);
                bf16split(e1, h.y, l.y);
                bf16split(e2, h.z, l.z);
                bf16split(e3, h.w, l.w);
                *(ushort4*)&Ah[row][seg * 16 + s * 4] = h;
                *(ushort4*)&Al[row][seg * 16 + s * 4] = l;
            }
        }
        // stage B: 208 rows x 64 k (rows >= 200 zeroed)
        for (int i = tid; i < 1664; i += 128) {
            int row = i >> 3, koff = (i & 7) * 8;
            uint4 h = {0u, 0u, 0u, 0u}, l = {0u, 0u, 0u, 0u};
            if (row < DD) {
                h = *(const uint4*)&fwh[(long long)row * FLAT + k0 + koff];
                l = *(const uint4*)&fwl[(long long)row * FLAT + k0 + koff];
            }
            *(uint4*)&Bh[row][koff] = h;
            *(uint4*)&Bl[row][koff] = l;
        }
        __syncthreads();
#pragma unroll
        for (int ks2 = 0; ks2 < 2; ks2++) {
            int ko = ks2 * 32 + q * 8;
            bf16x8 ah[2], al[2];
#pragma unroll
            for (int m = 0; m < 2; m++) {
                ah[m] = *(const bf16x8*)&Ah[wid * 32 + m * 16 + l15][ko];
                al[m] = *(const bf16x8*)&Al[wid * 32 + m * 16 + l15][ko];
            }
#pragma unroll
            for (int n = 0; n < 13; n++) {
                bf16x8 bh = *(const bf16x8*)&Bh[n * 16 + l15][ko];
                bf16x8 bl = *(const bf16x8*)&Bl[n * 16 + l15][ko];
#pragma unroll
                for (int m = 0; m < 2; m++) {
                    acc[m][n] = __builtin_amdgcn_mfma_f32_16x16x32_bf16(ah[m], bh, acc[m][n], 0, 0, 0);
                    acc[m][n] = __builtin_amdgcn_mfma_f32_16x16x32_bf16(ah[m], bl, acc[m][n], 0, 0, 0);
                    acc[m][n] = __builtin_amdgcn_mfma_f32_16x16x32_bf16(al[m], bh, acc[m][n], 0, 0, 0);
                }
            }
        }
    }
    // epilogue: part[ksl][row][j]; C layout row=(q*4+r), col=l15 per 16x16 frag
    long long pbase = (long long)ksl * (BB * DD);
#pragma unroll
    for (int n = 0; n < 13; n++) {
        int j = n * 16 + l15;
        if (j < DD) {
#pragma unroll
            for (int m = 0; m < 2; m++) {
                int rowb = b0 + wid * 32 + m * 16 + q * 4;
#pragma unroll
                for (int r = 0; r < 4; r++)
                    part[pbase + (long long)(rowb + r) * DD + j] = acc[m][n][r];
            }
        }
    }
}

// bn2 over batch, folding the split-K reduction; emits x2 bf16 hi/lo only
__global__ void k_bn2(const float* __restrict__ part, const float* __restrict__ fc_b,
                      const float* __restrict__ g2, const float* __restrict__ b2,
                      ushort* __restrict__ x2h, ushort* __restrict__ x2l) {
    int j = blockIdx.x;
    float vals[4];
    float s = 0.f, q = 0.f;
#pragma unroll
    for (int i = 0; i < 4; i++) {
        int b = threadIdx.x + i * 256;
        float v = fc_b[j];
#pragma unroll
        for (int ks = 0; ks < FC_KS; ks++)
            v += part[(long long)ks * (BB * DD) + (long long)b * DD + j];
        vals[i] = v;
        s += v; q += v * v;
    }
    __shared__ float r1[256], r2[256];
    __shared__ float bc[2];
    r1[threadIdx.x] = s; r2[threadIdx.x] = q;
    __syncthreads();
    for (int st = 128; st > 0; st >>= 1) {
        if (threadIdx.x < st) { r1[threadIdx.x] += r1[threadIdx.x + st]; r2[threadIdx.x] += r2[threadIdx.x + st]; }
        __syncthreads();
    }
    if (threadIdx.x == 0) {
        float m = r1[0] * (1.f / BB);
        float v = r2[0] * (1.f / BB) - m * m;
        float sc = rsqrtf(v + 1e-5f) * g2[j];
        bc[0] = sc; bc[1] = b2[j] - m * sc;
    }
    __syncthreads();
    float sc = bc[0], sh = bc[1];
#pragma unroll
    for (int i = 0; i < 4; i++) {
        int b = threadIdx.x + i * 256;
        float v = fmaxf(vals[i] * sc + sh, 0.f);
        ushort h, l;
        bf16split(v, h, l);
        x2h[b * DD + j] = h;
        x2l[b * DD + j] = l;
    }
}

// logits = sigmoid(x2 @ all_ent^T + bias) via bf16-split MFMA (hi*hi + hi*lo + lo*hi)
__global__ __launch_bounds__(512) void k_logits_mfma(
        const ushort* __restrict__ x2h, const ushort* __restrict__ x2l,
        const ushort* __restrict__ aeh, const ushort* __restrict__ ael,
        const float* __restrict__ bias, float* __restrict__ out) {
    __shared__ ushort Ah[64 * DD];   // 25.6 KB
    __shared__ ushort Al[64 * DD];   // 25.6 KB
    int m0 = blockIdx.y * 64;
    {
        const uint4* g0 = (const uint4*)(x2h + (long long)m0 * DD);
        const uint4* g1 = (const uint4*)(x2l + (long long)m0 * DD);
        uint4* s0 = (uint4*)Ah;
        uint4* s1 = (uint4*)Al;
        for (int i = threadIdx.x; i < 1600; i += 512) { s0[i] = g0[i]; s1[i] = g1[i]; }
    }
    __syncthreads();
    int wid = threadIdx.x >> 6;
    int lane = threadIdx.x & 63;
    int l15 = lane & 15, q = lane >> 4;
    int e0 = blockIdx.x * 512 + wid * 64;

    f32x4 zero4 = {0.f, 0.f, 0.f, 0.f};
    f32x4 acc[4][4];
#pragma unroll
    for (int m = 0; m < 4; m++)
#pragma unroll
        for (int n = 0; n < 4; n++) acc[m][n] = zero4;

    long long brow[4];
#pragma unroll
    for (int n = 0; n < 4; n++) {
        int e = e0 + n * 16 + l15;
        if (e > NENT - 1) e = NENT - 1;
        brow[n] = (long long)e * DD;
    }
    int aoff = q * 8;

#pragma unroll
    for (int kk = 0; kk < 6; kk++) {
        int k0 = kk * 32 + aoff;
        bf16x8 ah[4], al[4], bh[4], bl[4];
#pragma unroll
        for (int m = 0; m < 4; m++) {
            int off = (m * 16 + l15) * DD + k0;
            ah[m] = *(const bf16x8*)&Ah[off];
            al[m] = *(const bf16x8*)&Al[off];
        }
#pragma unroll
        for (int n = 0; n < 4; n++) {
            bh[n] = *(const bf16x8*)&aeh[brow[n] + k0];
            bl[n] = *(const bf16x8*)&ael[brow[n] + k0];
        }
#pragma unroll
        for (int m = 0; m < 4; m++)
#pragma unroll
            for (int n = 0; n < 4; n++) {
                acc[m][n] = __builtin_amdgcn_mfma_f32_16x16x32_bf16(ah[m], bh[n], acc[m][n], 0, 0, 0);
                acc[m][n] = __builtin_amdgcn_mfma_f32_16x16x32_bf16(ah[m], bl[n], acc[m][n], 0, 0, 0);
                acc[m][n] = __builtin_amdgcn_mfma_f32_16x16x32_bf16(al[m], bh[n], acc[m][n], 0, 0, 0);
            }
    }
    {   // partial k-step 192..199 (quarter 0 only)
        bf16x8 zf = {0, 0, 0, 0, 0, 0, 0, 0};
        bf16x8 ah[4], al[4], bh[4], bl[4];
#pragma unroll
        for (int m = 0; m < 4; m++) { ah[m] = zf; al[m] = zf; }
#pragma unroll
        for (int n = 0; n < 4; n++) { bh[n] = zf; bl[n] = zf; }
        if (q == 0) {
#pragma unroll
            for (int m = 0; m < 4; m++) {
                int off = (m * 16 + l15) * DD + 192;
                ah[m] = *(const bf16x8*)&Ah[off];
                al[m] = *(const bf16x8*)&Al[off];
            }
#pragma unroll
            for (int n = 0; n < 4; n++) {
                bh[n] = *(const bf16x8*)&aeh[brow[n] + 192];
                bl[n] = *(const bf16x8*)&ael[brow[n] + 192];
            }
        }
#pragma unroll
        for (int m = 0; m < 4; m++)
#pragma unroll
            for (int n = 0; n < 4; n++) {
                acc[m][n] = __builtin_amdgcn_mfma_f32_16x16x32_bf16(ah[m], bh[n], acc[m][n], 0, 0, 0);
                acc[m][n] = __builtin_amdgcn_mfma_f32_16x16x32_bf16(ah[m], bl[n], acc[m][n], 0, 0, 0);
                acc[m][n] = __builtin_amdgcn_mfma_f32_16x16x32_bf16(al[m], bh[n], acc[m][n], 0, 0, 0);
            }
    }
#pragma unroll
    for (int n = 0; n < 4; n++) {
        int e = e0 + n * 16 + l15;
        if (e < NENT) {
            float bv = bias[e];
#pragma unroll
            for (int m = 0; m < 4; m++) {
                int row = m0 + m * 16 + q * 4;
#pragma unroll
                for (int r = 0; r < 4; r++) {
                    float t = acc[m][n][r] + bv;
                    out[(long long)(row + r) * NENT + e] = 1.f / (1.f + __expf(-t));
                }
            }
        }
    }
}

// ================= host =================

extern "C" void kernel_launch(void* const* d_in, const int* in_sizes, int n_in,
                              void* d_out, int out_size, void* d_ws, size_t ws_size,
                              hipStream_t stream) {
    const int*   sub      = (const int*)d_in[0];
    const int*   rel      = (const int*)d_in[1];
    const int*   ei       = (const int*)d_in[3];
    const int*   et       = (const int*)d_in[4];
    const int*   perm     = (const int*)d_in[5];
    const float* emb      = (const float*)d_in[6];
    const float* init_rel = (const float*)d_in[7];
    const float* w_in     = (const float*)d_in[8];
    const float* w_out    = (const float*)d_in[9];
    const float* w_loop   = (const float*)d_in[10];
    const float* w_rel    = (const float*)d_in[11];
    const float* loop_rel = (const float*)d_in[12];
    const float* bn0_g    = (const float*)d_in[13];
    const float* bn0_b    = (const float*)d_in[14];
    const float* bn1_g    = (const float*)d_in[15];
    const float* bn1_b    = (const float*)d_in[16];
    const float* bn2_g    = (const float*)d_in[17];
    const float* bn2_b    = (const float*)d_in[18];
    const float* filt     = (const float*)d_in[19];
    const float* fc_w     = (const float*)d_in[20];
    const float* fc_b     = (const float*)d_in[21];
    const float* bias_ent = (const float*)d_in[22];

    float* ws  = (float*)d_ws;
    float* o   = (float*)d_out;

    float* agg     = ws + OFF_AGG;
    float* agg_in  = agg;
    float* agg_out = agg + (long long)NENT * DD;
    int*   cnt     = (int*)(ws + OFF_CNT);
    int*   cursor  = (int*)(ws + OFF_CURSOR);
    int*   bsum    = (int*)(ws + OFF_BSUM);
    int*   elist   = (int*)(ws + OFF_ELIST);
    float* acc0    = ws + OFF_ACC0;
    float* acc1    = ws + OFF_ACC1;
    float* dinv    = ws + OFF_DINV;
    float* rmat    = ws + OFF_RMAT;
    float* cheq    = ws + OFF_CHEQ;
    float* bn1s    = ws + OFF_BN1S;
    ushort* x2h    = (ushort*)(ws + OFF_X2H);
    ushort* x2l    = (ushort*)(ws + OFF_X2L);
    float* all_ent = agg_in;
    ushort* aeh    = (ushort*)agg_out;
    ushort* ael    = aeh + (long long)NENT * DD;

    // d_out scratch (fully overwritten by k_logits_mfma at the end)
    float*  conv_out = o + OD_CONV;
    ushort* fwh      = (ushort*)(o + OD_FWH);
    ushort* fwl      = (ushort*)(o + OD_FWL);
    float*  part     = o + OD_PART;

    hipMemsetAsync(ws + ZSTART, 0, (size_t)(ZEND - ZSTART) * 4, stream);

    // ---- CSR build + gather aggregation ----
    k_hist<<<(ETOT + 255) / 256, 256, 0, stream>>>(ei, cnt);
    k_dinv<<<(NENT + 255) / 256, 256, 0, stream>>>(cnt, dinv);
    k_scan1<<<98, 256, 0, stream>>>(cnt, bsum);
    k_scan2<<<1, 128, 0, stream>>>(bsum);
    k_scan3<<<98, 256, 0, stream>>>(cnt, bsum, cursor);
    k_fill<<<(ETOT + 255) / 256, 256, 0, stream>>>(ei, cursor, elist);
    k_agg<<<NSEG / 4, 256, 0, stream>>>(ei, et, cnt, elist, emb, init_rel, dinv, agg);

    // ---- encoder GEMMs + weight conversions ----
    k_allent<<<NENT / 16, 256, 0, stream>>>(agg_in, agg_out, emb, loop_rel,
                                            w_in, w_out, w_loop, all_ent);
    k_cvt<<<((NENT * DD / 4) + 255) / 256, 256, 0, stream>>>(all_ent, aeh, ael);
    k_cvtw<<<((DD * FLAT / 4) + 255) / 256, 256, 0, stream>>>(fc_w, fwh, fwl);
    k_rmat<<<400 / 16, 256, 0, stream>>>(init_rel, w_rel, rmat);

    // ---- decoder ----
    k_cheq<<<(BB * 400) / 256, 256, 0, stream>>>(sub, rel, perm, all_ent, rmat, cheq, acc0);
    k_conv<<<BB, 256, 0, stream>>>(cheq, acc0, bn0_g, bn0_b, filt, conv_out, acc1);
    k_bn1fin<<<1, 128, 0, stream>>>(acc1, bn1_g, bn1_b, bn1s);
    k_fc_mfma<<<dim3(BB / 64, FC_KS), 128, 0, stream>>>(conv_out, bn1s, fwh, fwl, part);
    k_bn2<<<DD, 256, 0, stream>>>(part, fc_b, bn2_g, bn2_b, x2h, x2l);
    k_logits_mfma<<<dim3((NENT + 511) / 512, BB / 64), 512, 0, stream>>>(
        x2h, x2l, aeh, ael, bias_ent, o);
}

// Round 5
// 1293.215 us; speedup vs baseline: 3.0676x; 1.0777x over previous
//
#include <hip/hip_runtime.h>

// ---------------- problem constants ----------------
#define ETOT  500000
#define EHALF 250000
#define NENT  50000
#define NSEG  (2 * NENT)   // segments: half*NENT + dst
#define DD    200
#define BB    1024
#define NF    96
#define FLAT  38400   // 96*400

// fc split-K config
#define FC_KS     20
#define FC_KSLICE 1920    // 38400/20
#define FC_CHUNKS 30      // 1920/64

// ---------------- workspace layout (float32 offsets) ----------------
#define OFF_AGG      0LL          // 20,000,000  ([0,10M)=agg_in->all_ent, [10M,20M)=agg_out->aeh/ael)
// zeroed region: [ZSTART, ZEND)
#define ZSTART       20000000LL
#define OFF_CNT      20000000LL   // 100,004 ints (NSEG+1 used; becomes row_start after scan)
#define OFF_ACC0     20100004LL   //          2  (bn0 sum, sumsq)
#define OFF_ACC1     20100006LL   //        192  (bn1 sum[96], sumsq[96])
#define ZEND         20100198LL
// non-zeroed:
#define OFF_CURSOR   20304998LL   //    100,000 ints
#define OFF_BSUM     20404998LL   //        128 ints
#define OFF_ELIST    20405126LL   //    500,000 ints (dead after k_agg; wt planes reuse it)
#define OFF_WT       20405128LL   //    120,000 f32 = 240,000 ushort (3 transposed w hi+lo), 16B-aligned
#define OFF_DINV     20905126LL   //     50,000
#define OFF_RMAT     20955126LL   //     80,000
#define OFF_CHEQ     21035126LL   //    409,600
#define OFF_BN1S     21444726LL   //        192  (scale[96], shift[96])
#define OFF_X2H      21649720LL   //    102,400 f32 (= 204,800 ushort), 16B-aligned
#define OFF_X2L      21752120LL   //    102,400 f32
// total ws need ~= 21,854,520 f32 = 87.4 MB

// ---------------- d_out scratch layout (f32 offsets; out_size = 51,200,000) ----
#define OD_CONV 0LL          // 39,321,600 (1024 x 38400 conv output, f32)
#define OD_FWH  39321600LL   //  3,840,000 f32 = 7,680,000 ushort (fc_w hi plane)
#define OD_FWL  43161600LL   //  3,840,000 f32 (fc_w lo plane)
#define OD_PART 47001600LL   //  4,096,000 f32 (FC_KS x 1024 x 200 partials) -> ends 51,097,600

typedef __attribute__((ext_vector_type(8))) short bf16x8;
typedef __attribute__((ext_vector_type(4))) float f32x4;

__device__ inline void bf16split(float v, ushort& h, ushort& l) {
    unsigned u = __float_as_uint(v);
    unsigned hu = u & 0xffff0000u;
    h = (ushort)(hu >> 16);
    float lf = v - __uint_as_float(hu);
    l = (ushort)(__float_as_uint(lf) >> 16);
}

// ================= CSR build =================

__global__ void k_hist(const int* __restrict__ ei, int* __restrict__ cnt) {
    int e = blockIdx.x * 256 + threadIdx.x;
    if (e < ETOT) {
        int seg = (e < EHALF ? 0 : NENT) + ei[ETOT + e];
        atomicAdd(&cnt[seg], 1);
    }
}

__global__ void k_dinv(const int* __restrict__ cnt, float* __restrict__ dinv) {
    int i = blockIdx.x * 256 + threadIdx.x;
    if (i < NENT) {
        int d = cnt[i] + cnt[NENT + i];
        dinv[i] = d > 0 ? rsqrtf((float)d) : 0.f;
    }
}

__global__ void k_scan1(int* __restrict__ cnt, int* __restrict__ bsum) {
    __shared__ int S[256];
    int base = blockIdx.x * 1024 + threadIdx.x * 4;
    int v[4], s = 0;
#pragma unroll
    for (int i = 0; i < 4; i++) { v[i] = (base + i <= NSEG) ? cnt[base + i] : 0; s += v[i]; }
    S[threadIdx.x] = s;
    __syncthreads();
    for (int off = 1; off < 256; off <<= 1) {
        int t = (threadIdx.x >= off) ? S[threadIdx.x - off] : 0;
        __syncthreads();
        S[threadIdx.x] += t;
        __syncthreads();
    }
    int run = S[threadIdx.x] - s;
#pragma unroll
    for (int i = 0; i < 4; i++) {
        if (base + i <= NSEG) cnt[base + i] = run;
        run += v[i];
    }
    if (threadIdx.x == 255) bsum[blockIdx.x] = S[255];
}

__global__ void k_scan2(int* __restrict__ bsum) {
    __shared__ int S[128];
    int v = (threadIdx.x < 98) ? bsum[threadIdx.x] : 0;
    S[threadIdx.x] = v;
    __syncthreads();
    for (int off = 1; off < 128; off <<= 1) {
        int t = (threadIdx.x >= off) ? S[threadIdx.x - off] : 0;
        __syncthreads();
        S[threadIdx.x] += t;
        __syncthreads();
    }
    if (threadIdx.x < 98) bsum[threadIdx.x] = S[threadIdx.x] - v;
}

__global__ void k_scan3(int* __restrict__ cnt, const int* __restrict__ bsum,
                        int* __restrict__ cursor) {
    int add = bsum[blockIdx.x];
    int base = blockIdx.x * 1024 + threadIdx.x * 4;
#pragma unroll
    for (int i = 0; i < 4; i++) {
        int idx = base + i;
        if (idx <= NSEG) {
            int v = cnt[idx] + add;
            cnt[idx] = v;
            if (idx < NSEG) cursor[idx] = v;
        }
    }
}

__global__ void k_fill(const int* __restrict__ ei, int* __restrict__ cursor,
                       int* __restrict__ elist) {
    int e = blockIdx.x * 256 + threadIdx.x;
    if (e < ETOT) {
        int seg = (e < EHALF ? 0 : NENT) + ei[ETOT + e];
        int pos = atomicAdd(&cursor[seg], 1);
        elist[pos] = e;
    }
}

// gather-aggregate: one wave per segment (4 waves/block), no float atomics
__global__ void k_agg(const int* __restrict__ ei, const int* __restrict__ et,
                      const int* __restrict__ row_start, const int* __restrict__ elist,
                      const float* __restrict__ emb, const float* __restrict__ rel,
                      const float* __restrict__ dinv, float* __restrict__ agg) {
    int seg = blockIdx.x * 4 + (threadIdx.x >> 6);
    int lane = threadIdx.x & 63;
    int dst = seg - (seg >= NENT ? NENT : 0);
    float dd = dinv[dst];
    int s = row_start[seg], e = row_start[seg + 1];
    bool act = lane < 50;
    float4 acc = {0.f, 0.f, 0.f, 0.f};
    for (int i = s; i < e; i++) {
        int ed = elist[i];
        int src = ei[ed];
        int t = et[ed];
        float nrm = dinv[src] * dd;
        if (act) {
            float4 a = *(const float4*)&emb[(long long)src * DD + lane * 4];
            float4 b = *(const float4*)&rel[t * DD + lane * 4];
            acc.x += (a.x - b.x) * nrm;
            acc.y += (a.y - b.y) * nrm;
            acc.z += (a.z - b.z) * nrm;
            acc.w += (a.w - b.w) * nrm;
        }
    }
    if (act) *(float4*)&agg[(long long)seg * DD + lane * 4] = acc;
}

// ================= encoder GEMMs =================

// transpose + hi/lo-split the three 200x200 weights: wt[s][j][k] = split(w_s[k][j])
__global__ void k_cvt3w(const float* __restrict__ w_in, const float* __restrict__ w_out,
                        const float* __restrict__ w_loop,
                        ushort* __restrict__ wth, ushort* __restrict__ wtl) {
    int idx = blockIdx.x * 256 + threadIdx.x;
    if (idx >= 3 * DD * DD) return;
    int s = idx / (DD * DD);
    int rem = idx - s * DD * DD;
    int j = rem / DD, k = rem - (rem / DD) * DD;
    const float* w = (s == 0) ? w_in : (s == 1) ? w_out : w_loop;
    ushort h, l;
    bf16split(w[k * DD + j], h, l);
    wth[idx] = h;
    wtl[idx] = l;
}

// all_ent = tanh((agg_in@w_in + agg_out@w_out + (emb-loop_rel)@w_loop)/3) via bf16-split MFMA
// 128 thr = 2 waves; block = 64 rows; wave tile 32x208 (2x13 frags of 16x16x32); in-place over agg_in
__global__ __launch_bounds__(128) void k_allent_mfma(
        const float* __restrict__ agg, const float* __restrict__ emb,
        const float* __restrict__ loop_rel,
        const ushort* __restrict__ wth, const ushort* __restrict__ wtl,
        float* __restrict__ all_ent) {
    __shared__ __align__(16) ushort Ah[64][DD];   // stride 400B -> bank stride 4 -> 2-way (free)
    __shared__ __align__(16) ushort Al[64][DD];
    __shared__ float lr[DD];
    int tid = threadIdx.x;
    for (int i = tid; i < DD; i += 128) lr[i] = loop_rel[i];
    int r0 = blockIdx.x * 64;
    int wid = tid >> 6, lane = tid & 63, l15 = lane & 15, q = lane >> 4;

    f32x4 zero4 = {0.f, 0.f, 0.f, 0.f};
    f32x4 acc[2][13];
#pragma unroll
    for (int m = 0; m < 2; m++)
#pragma unroll
        for (int n = 0; n < 13; n++) acc[m][n] = zero4;

    int jc[13];
#pragma unroll
    for (int n = 0; n < 13; n++) {
        int j = n * 16 + l15;
        jc[n] = j < DD ? j : DD - 1;
    }

    for (int s = 0; s < 3; s++) {
        __syncthreads();   // previous source's MFMA reads done before restage
        for (int i = tid; i < 3200; i += 128) {
            int row = i / 50, c4 = (i % 50) * 4;
            int rg = r0 + row;
            if (rg > NENT - 1) rg = NENT - 1;
            float4 v;
            if (s == 2) {
                v = *(const float4*)&emb[(long long)rg * DD + c4];
                v.x -= lr[c4]; v.y -= lr[c4 + 1]; v.z -= lr[c4 + 2]; v.w -= lr[c4 + 3];
            } else {
                v = *(const float4*)&agg[(long long)(s * NENT + rg) * DD + c4];
            }
            ushort4 h, l;
            bf16split(v.x, h.x, l.x);
            bf16split(v.y, h.y, l.y);
            bf16split(v.z, h.z, l.z);
            bf16split(v.w, h.w, l.w);
            *(ushort4*)&Ah[row][c4] = h;
            *(ushort4*)&Al[row][c4] = l;
        }
        __syncthreads();
        const ushort* bhb = wth + s * (DD * DD);
        const ushort* blb = wtl + s * (DD * DD);
#pragma unroll
        for (int kk = 0; kk < 6; kk++) {
            int k0 = kk * 32 + q * 8;
            bf16x8 ah[2], al[2];
#pragma unroll
            for (int m = 0; m < 2; m++) {
                ah[m] = *(const bf16x8*)&Ah[wid * 32 + m * 16 + l15][k0];
                al[m] = *(const bf16x8*)&Al[wid * 32 + m * 16 + l15][k0];
            }
#pragma unroll
            for (int n = 0; n < 13; n++) {
                bf16x8 bh = *(const bf16x8*)&bhb[jc[n] * DD + k0];
                bf16x8 bl = *(const bf16x8*)&blb[jc[n] * DD + k0];
#pragma unroll
                for (int m = 0; m < 2; m++) {
                    acc[m][n] = __builtin_amdgcn_mfma_f32_16x16x32_bf16(ah[m], bh, acc[m][n], 0, 0, 0);
                    acc[m][n] = __builtin_amdgcn_mfma_f32_16x16x32_bf16(ah[m], bl, acc[m][n], 0, 0, 0);
                    acc[m][n] = __builtin_amdgcn_mfma_f32_16x16x32_bf16(al[m], bh, acc[m][n], 0, 0, 0);
                }
            }
        }
        {   // partial k-step 192..199 (quarter 0 only)
            bf16x8 zf = {0, 0, 0, 0, 0, 0, 0, 0};
            bf16x8 ah[2], al[2];
#pragma unroll
            for (int m = 0; m < 2; m++) { ah[m] = zf; al[m] = zf; }
            if (q == 0) {
#pragma unroll
                for (int m = 0; m < 2; m++) {
                    ah[m] = *(const bf16x8*)&Ah[wid * 32 + m * 16 + l15][192];
                    al[m] = *(const bf16x8*)&Al[wid * 32 + m * 16 + l15][192];
                }
            }
#pragma unroll
            for (int n = 0; n < 13; n++) {
                bf16x8 bh = zf, bl = zf;
                if (q == 0) {
                    bh = *(const bf16x8*)&bhb[jc[n] * DD + 192];
                    bl = *(const bf16x8*)&blb[jc[n] * DD + 192];
                }
#pragma unroll
                for (int m = 0; m < 2; m++) {
                    acc[m][n] = __builtin_amdgcn_mfma_f32_16x16x32_bf16(ah[m], bh, acc[m][n], 0, 0, 0);
                    acc[m][n] = __builtin_amdgcn_mfma_f32_16x16x32_bf16(ah[m], bl, acc[m][n], 0, 0, 0);
                    acc[m][n] = __builtin_amdgcn_mfma_f32_16x16x32_bf16(al[m], bh, acc[m][n], 0, 0, 0);
                }
            }
        }
    }
    // epilogue: tanh(acc/3); C layout row=(q*4+r), col=l15 per 16x16 frag
#pragma unroll
    for (int n = 0; n < 13; n++) {
        int j = n * 16 + l15;
        if (j < DD) {
#pragma unroll
            for (int m = 0; m < 2; m++) {
                int row = r0 + wid * 32 + m * 16 + q * 4;
#pragma unroll
                for (int r = 0; r < 4; r++) {
                    if (row + r < NENT)
                        all_ent[(long long)(row + r) * DD + j] = tanhf(acc[m][n][r] * (1.f / 3.f));
                }
            }
        }
    }
}

// convert all_ent f32 -> bf16 hi/lo (over agg_out region), 4 elems/thread
__global__ void k_cvt(const float* __restrict__ src, ushort* __restrict__ hi,
                      ushort* __restrict__ lo) {
    long long i = (long long)(blockIdx.x * 256 + threadIdx.x) * 4;
    if (i >= (long long)NENT * DD) return;
    float4 v = *(const float4*)&src[i];
    ushort4 h, l;
    bf16split(v.x, h.x, l.x);
    bf16split(v.y, h.y, l.y);
    bf16split(v.z, h.z, l.z);
    bf16split(v.w, h.w, l.w);
    *(ushort4*)&hi[i] = h;
    *(ushort4*)&lo[i] = l;
}

// convert fc_w f32 -> bf16 hi/lo planes (into d_out tail)
__global__ void k_cvtw(const float* __restrict__ src, ushort* __restrict__ hi,
                       ushort* __restrict__ lo) {
    long long i = (long long)(blockIdx.x * 256 + threadIdx.x) * 4;
    if (i >= (long long)DD * FLAT) return;
    float4 v = *(const float4*)&src[i];
    ushort4 h, l;
    bf16split(v.x, h.x, l.x);
    bf16split(v.y, h.y, l.y);
    bf16split(v.z, h.z, l.z);
    bf16split(v.w, h.w, l.w);
    *(ushort4*)&hi[i] = h;
    *(ushort4*)&lo[i] = l;
}

__global__ void k_rmat(const float* __restrict__ init_rel, const float* __restrict__ w_rel,
                       float* __restrict__ rmat) {
    __shared__ float S[16][DD];
    int r0 = blockIdx.x * 16;
    for (int i = threadIdx.x; i < 16 * DD; i += 256)
        S[i / DD][i % DD] = init_rel[(r0 + i / DD) * DD + i % DD];
    __syncthreads();
    int j = threadIdx.x;
    if (j < DD) {
        float acc[16];
#pragma unroll
        for (int rr = 0; rr < 16; rr++) acc[rr] = 0.f;
        for (int k = 0; k < DD; k += 4) {
            float wx = w_rel[(k + 0) * DD + j], wy = w_rel[(k + 1) * DD + j],
                  wz = w_rel[(k + 2) * DD + j], ww = w_rel[(k + 3) * DD + j];
#pragma unroll
            for (int rr = 0; rr < 16; rr++) {
                float4 a = *(const float4*)&S[rr][k];
                acc[rr] += a.x * wx + a.y * wy + a.z * wz + a.w * ww;
            }
        }
#pragma unroll
        for (int rr = 0; rr < 16; rr++) rmat[(r0 + rr) * DD + j] = acc[rr];
    }
}

// ================= decoder =================

__global__ void k_cheq(const int* __restrict__ sub, const int* __restrict__ rel,
                       const int* __restrict__ perm, const float* __restrict__ all_ent,
                       const float* __restrict__ rmat, float* __restrict__ cheq,
                       float* __restrict__ acc0) {
    int i = blockIdx.x * 256 + threadIdx.x;
    int b = i / 400, p = i % 400;
    int c = perm[p];
    float v = (c < DD) ? all_ent[(long long)sub[b] * DD + c]
                       : rmat[rel[b] * DD + (c - DD)];
    cheq[i] = v;
    __shared__ float s1[256], s2[256];
    s1[threadIdx.x] = v;
    s2[threadIdx.x] = v * v;
    __syncthreads();
    for (int st = 128; st > 0; st >>= 1) {
        if (threadIdx.x < st) { s1[threadIdx.x] += s1[threadIdx.x + st]; s2[threadIdx.x] += s2[threadIdx.x + st]; }
        __syncthreads();
    }
    if (threadIdx.x == 0) { atomicAdd(&acc0[0], s1[0]); atomicAdd(&acc0[1], s2[0]); }
}

__global__ void k_conv(const float* __restrict__ cheq, const float* __restrict__ acc0,
                       const float* __restrict__ bn0_g, const float* __restrict__ bn0_b,
                       const float* __restrict__ filt, float* __restrict__ conv_out,
                       float* __restrict__ acc1) {
    __shared__ float xp[28 * 28];
    __shared__ float fl[NF * 81];
    __shared__ float csum[NF], csq[NF];
    int b = blockIdx.x;
    const float invN = 1.f / (BB * 400.f);
    float mean = acc0[0] * invN;
    float var = acc0[1] * invN - mean * mean;
    float sc = rsqrtf(var + 1e-5f) * bn0_g[0];
    float sh = bn0_b[0] - mean * sc;
    for (int i = threadIdx.x; i < 28 * 28; i += 256) {
        int r = i / 28, c = i % 28;
        int rr = (r + 16) % 20, cc = (c + 16) % 20;
        xp[i] = cheq[b * 400 + rr * 20 + cc] * sc + sh;
    }
    for (int i = threadIdx.x; i < NF * 81; i += 256) fl[i] = filt[i];
    if (threadIdx.x < NF) { csum[threadIdx.x] = 0.f; csq[threadIdx.x] = 0.f; }
    __syncthreads();
    for (int t = threadIdx.x; t < NF * 20; t += 256) {
        int ch = t / 20, row = t % 20;
        float acc[20];
#pragma unroll
        for (int c2 = 0; c2 < 20; c2++) acc[c2] = 0.f;
        for (int di = 0; di < 9; di++) {
            const float* xrow = &xp[(row + di) * 28];
#pragma unroll
            for (int dj = 0; dj < 9; dj++) {
                float f = fl[ch * 81 + di * 9 + dj];
#pragma unroll
                for (int c2 = 0; c2 < 20; c2++) acc[c2] = fmaf(xrow[c2 + dj], f, acc[c2]);
            }
        }
        float s = 0.f, q = 0.f;
        long long base = (long long)b * FLAT + ch * 400 + row * 20;
#pragma unroll
        for (int c2 = 0; c2 < 20; c2++) {
            float v = acc[c2];
            s += v; q += v * v;
            conv_out[base + c2] = v;
        }
        atomicAdd(&csum[ch], s);
        atomicAdd(&csq[ch], q);
    }
    __syncthreads();
    if (threadIdx.x < NF) {
        atomicAdd(&acc1[threadIdx.x], csum[threadIdx.x]);
        atomicAdd(&acc1[NF + threadIdx.x], csq[threadIdx.x]);
    }
}

__global__ void k_bn1fin(const float* __restrict__ acc1, const float* __restrict__ g1,
                         const float* __restrict__ b1, float* __restrict__ bn1s) {
    int c = threadIdx.x;
    if (c >= NF) return;
    const float invN = 1.f / (BB * 400.f);
    float m = acc1[c] * invN;
    float v = acc1[NF + c] * invN - m * m;
    float sc = rsqrtf(v + 1e-5f) * g1[c];
    bn1s[c] = sc;
    bn1s[NF + c] = b1[c] - m * sc;
}

// fc GEMM via bf16-split MFMA (split-K into partials)
__global__ __launch_bounds__(128) void k_fc_mfma(
        const float* __restrict__ conv_out, const float* __restrict__ bn1s,
        const ushort* __restrict__ fwh, const ushort* __restrict__ fwl,
        float* __restrict__ part) {
    __shared__ __align__(16) ushort Ah[64][72];
    __shared__ __align__(16) ushort Al[64][72];
    __shared__ __align__(16) ushort Bh[208][72];
    __shared__ __align__(16) ushort Bl[208][72];
    __shared__ float bns[192];
    int tid = threadIdx.x;
    for (int i = tid; i < 192; i += 128) bns[i] = bn1s[i];
    int b0 = blockIdx.x * 64;
    int ksl = blockIdx.y;
    int kbase = ksl * FC_KSLICE;
    int wid = tid >> 6, lane = tid & 63, l15 = lane & 15, q = lane >> 4;

    f32x4 zero4 = {0.f, 0.f, 0.f, 0.f};
    f32x4 acc[2][13];
#pragma unroll
    for (int m = 0; m < 2; m++)
#pragma unroll
        for (int n = 0; n < 13; n++) acc[m][n] = zero4;

    for (int c = 0; c < FC_CHUNKS; c++) {
        int k0 = kbase + c * 64;
        __syncthreads();
        for (int i = tid; i < 256; i += 128) {
            int row = i >> 2, seg = i & 3;
            const float* src = &conv_out[(long long)(b0 + row) * FLAT + k0 + seg * 16];
#pragma unroll
            for (int s = 0; s < 4; s++) {
                float4 v = *(const float4*)&src[s * 4];
                int kk = k0 + seg * 16 + s * 4;
                int ch = kk / 400;
                float sc = bns[ch], sh = bns[96 + ch];
                ushort4 h, l;
                float e0 = fmaxf(v.x * sc + sh, 0.f);
                float e1 = fmaxf(v.y * sc + sh, 0.f);
                float e2 = fmaxf(v.z * sc + sh, 0.f);
                float e3 = fmaxf(v.w * sc + sh, 0.f);
                bf16split(e0, h.x, l.x);
                bf16split(e1, h.y, l.y);
                bf16split(e2, h.z, l.z);
                bf16split(e3, h.w, l.w);
                *(ushort4*)&Ah[row][seg * 16 + s * 4] = h;
                *(ushort4*)&Al[row][seg * 16 + s * 4] = l;
            }
        }
        for (int i = tid; i < 1664; i += 128) {
            int row = i >> 3, koff = (i & 7) * 8;
            uint4 h = {0u, 0u, 0u, 0u}, l = {0u, 0u, 0u, 0u};
            if (row < DD) {
                h = *(const uint4*)&fwh[(long long)row * FLAT + k0 + koff];
                l = *(const uint4*)&fwl[(long long)row * FLAT + k0 + koff];
            }
            *(uint4*)&Bh[row][koff] = h;
            *(uint4*)&Bl[row][koff] = l;
        }
        __syncthreads();
#pragma unroll
        for (int ks2 = 0; ks2 < 2; ks2++) {
            int ko = ks2 * 32 + q * 8;
            bf16x8 ah[2], al[2];
#pragma unroll
            for (int m = 0; m < 2; m++) {
                ah[m] = *(const bf16x8*)&Ah[wid * 32 + m * 16 + l15][ko];
                al[m] = *(const bf16x8*)&Al[wid * 32 + m * 16 + l15][ko];
            }
#pragma unroll
            for (int n = 0; n < 13; n++) {
                bf16x8 bh = *(const bf16x8*)&Bh[n * 16 + l15][ko];
                bf16x8 bl = *(const bf16x8*)&Bl[n * 16 + l15][ko];
#pragma unroll
                for (int m = 0; m < 2; m++) {
                    acc[m][n] = __builtin_amdgcn_mfma_f32_16x16x32_bf16(ah[m], bh, acc[m][n], 0, 0, 0);
                    acc[m][n] = __builtin_amdgcn_mfma_f32_16x16x32_bf16(ah[m], bl, acc[m][n], 0, 0, 0);
                    acc[m][n] = __builtin_amdgcn_mfma_f32_16x16x32_bf16(al[m], bh, acc[m][n], 0, 0, 0);
                }
            }
        }
    }
    long long pbase = (long long)ksl * (BB * DD);
#pragma unroll
    for (int n = 0; n < 13; n++) {
        int j = n * 16 + l15;
        if (j < DD) {
#pragma unroll
            for (int m = 0; m < 2; m++) {
                int rowb = b0 + wid * 32 + m * 16 + q * 4;
#pragma unroll
                for (int r = 0; r < 4; r++)
                    part[pbase + (long long)(rowb + r) * DD + j] = acc[m][n][r];
            }
        }
    }
}

// bn2 over batch, folding the split-K reduction; emits x2 bf16 hi/lo only
__global__ void k_bn2(const float* __restrict__ part, const float* __restrict__ fc_b,
                      const float* __restrict__ g2, const float* __restrict__ b2,
                      ushort* __restrict__ x2h, ushort* __restrict__ x2l) {
    int j = blockIdx.x;
    float vals[4];
    float s = 0.f, q = 0.f;
#pragma unroll
    for (int i = 0; i < 4; i++) {
        int b = threadIdx.x + i * 256;
        float v = fc_b[j];
#pragma unroll
        for (int ks = 0; ks < FC_KS; ks++)
            v += part[(long long)ks * (BB * DD) + (long long)b * DD + j];
        vals[i] = v;
        s += v; q += v * v;
    }
    __shared__ float r1[256], r2[256];
    __shared__ float bc[2];
    r1[threadIdx.x] = s; r2[threadIdx.x] = q;
    __syncthreads();
    for (int st = 128; st > 0; st >>= 1) {
        if (threadIdx.x < st) { r1[threadIdx.x] += r1[threadIdx.x + st]; r2[threadIdx.x] += r2[threadIdx.x + st]; }
        __syncthreads();
    }
    if (threadIdx.x == 0) {
        float m = r1[0] * (1.f / BB);
        float v = r2[0] * (1.f / BB) - m * m;
        float sc = rsqrtf(v + 1e-5f) * g2[j];
        bc[0] = sc; bc[1] = b2[j] - m * sc;
    }
    __syncthreads();
    float sc = bc[0], sh = bc[1];
#pragma unroll
    for (int i = 0; i < 4; i++) {
        int b = threadIdx.x + i * 256;
        float v = fmaxf(vals[i] * sc + sh, 0.f);
        ushort h, l;
        bf16split(v, h, l);
        x2h[b * DD + j] = h;
        x2l[b * DD + j] = l;
    }
}

// logits = sigmoid(x2 @ all_ent^T + bias) via bf16-split MFMA (hi*hi + hi*lo + lo*hi)
__global__ __launch_bounds__(512) void k_logits_mfma(
        const ushort* __restrict__ x2h, const ushort* __restrict__ x2l,
        const ushort* __restrict__ aeh, const ushort* __restrict__ ael,
        const float* __restrict__ bias, float* __restrict__ out) {
    __shared__ ushort Ah[64 * DD];
    __shared__ ushort Al[64 * DD];
    int m0 = blockIdx.y * 64;
    {
        const uint4* g0 = (const uint4*)(x2h + (long long)m0 * DD);
        const uint4* g1 = (const uint4*)(x2l + (long long)m0 * DD);
        uint4* s0 = (uint4*)Ah;
        uint4* s1 = (uint4*)Al;
        for (int i = threadIdx.x; i < 1600; i += 512) { s0[i] = g0[i]; s1[i] = g1[i]; }
    }
    __syncthreads();
    int wid = threadIdx.x >> 6;
    int lane = threadIdx.x & 63;
    int l15 = lane & 15, q = lane >> 4;
    int e0 = blockIdx.x * 512 + wid * 64;

    f32x4 zero4 = {0.f, 0.f, 0.f, 0.f};
    f32x4 acc[4][4];
#pragma unroll
    for (int m = 0; m < 4; m++)
#pragma unroll
        for (int n = 0; n < 4; n++) acc[m][n] = zero4;

    long long brow[4];
#pragma unroll
    for (int n = 0; n < 4; n++) {
        int e = e0 + n * 16 + l15;
        if (e > NENT - 1) e = NENT - 1;
        brow[n] = (long long)e * DD;
    }
    int aoff = q * 8;

#pragma unroll
    for (int kk = 0; kk < 6; kk++) {
        int k0 = kk * 32 + aoff;
        bf16x8 ah[4], al[4], bh[4], bl[4];
#pragma unroll
        for (int m = 0; m < 4; m++) {
            int off = (m * 16 + l15) * DD + k0;
            ah[m] = *(const bf16x8*)&Ah[off];
            al[m] = *(const bf16x8*)&Al[off];
        }
#pragma unroll
        for (int n = 0; n < 4; n++) {
            bh[n] = *(const bf16x8*)&aeh[brow[n] + k0];
            bl[n] = *(const bf16x8*)&ael[brow[n] + k0];
        }
#pragma unroll
        for (int m = 0; m < 4; m++)
#pragma unroll
            for (int n = 0; n < 4; n++) {
                acc[m][n] = __builtin_amdgcn_mfma_f32_16x16x32_bf16(ah[m], bh[n], acc[m][n], 0, 0, 0);
                acc[m][n] = __builtin_amdgcn_mfma_f32_16x16x32_bf16(ah[m], bl[n], acc[m][n], 0, 0, 0);
                acc[m][n] = __builtin_amdgcn_mfma_f32_16x16x32_bf16(al[m], bh[n], acc[m][n], 0, 0, 0);
            }
    }
    {
        bf16x8 zf = {0, 0, 0, 0, 0, 0, 0, 0};
        bf16x8 ah[4], al[4], bh[4], bl[4];
#pragma unroll
        for (int m = 0; m < 4; m++) { ah[m] = zf; al[m] = zf; }
#pragma unroll
        for (int n = 0; n < 4; n++) { bh[n] = zf; bl[n] = zf; }
        if (q == 0) {
#pragma unroll
            for (int m = 0; m < 4; m++) {
                int off = (m * 16 + l15) * DD + 192;
                ah[m] = *(const bf16x8*)&Ah[off];
                al[m] = *(const bf16x8*)&Al[off];
            }
#pragma unroll
            for (int n = 0; n < 4; n++) {
                bh[n] = *(const bf16x8*)&aeh[brow[n] + 192];
                bl[n] = *(const bf16x8*)&ael[brow[n] + 192];
            }
        }
#pragma unroll
        for (int m = 0; m < 4; m++)
#pragma unroll
            for (int n = 0; n < 4; n++) {
                acc[m][n] = __builtin_amdgcn_mfma_f32_16x16x32_bf16(ah[m], bh[n], acc[m][n], 0, 0, 0);
                acc[m][n] = __builtin_amdgcn_mfma_f32_16x16x32_bf16(ah[m], bl[n], acc[m][n], 0, 0, 0);
                acc[m][n] = __builtin_amdgcn_mfma_f32_16x16x32_bf16(al[m], bh[n], acc[m][n], 0, 0, 0);
            }
    }
#pragma unroll
    for (int n = 0; n < 4; n++) {
        int e = e0 + n * 16 + l15;
        if (e < NENT) {
            float bv = bias[e];
#pragma unroll
            for (int m = 0; m < 4; m++) {
                int row = m0 + m * 16 + q * 4;
#pragma unroll
                for (int r = 0; r < 4; r++) {
                    float t = acc[m][n][r] + bv;
                    out[(long long)(row + r) * NENT + e] = 1.f / (1.f + __expf(-t));
                }
            }
        }
    }
}

// ================= host =================

extern "C" void kernel_launch(void* const* d_in, const int* in_sizes, int n_in,
                              void* d_out, int out_size, void* d_ws, size_t ws_size,
                              hipStream_t stream) {
    const int*   sub      = (const int*)d_in[0];
    const int*   rel      = (const int*)d_in[1];
    const int*   ei       = (const int*)d_in[3];
    const int*   et       = (const int*)d_in[4];
    const int*   perm     = (const int*)d_in[5];
    const float* emb      = (const float*)d_in[6];
    const float* init_rel = (const float*)d_in[7];
    const float* w_in     = (const float*)d_in[8];
    const float* w_out    = (const float*)d_in[9];
    const float* w_loop   = (const float*)d_in[10];
    const float* w_rel    = (const float*)d_in[11];
    const float* loop_rel = (const float*)d_in[12];
    const float* bn0_g    = (const float*)d_in[13];
    const float* bn0_b    = (const float*)d_in[14];
    const float* bn1_g    = (const float*)d_in[15];
    const float* bn1_b    = (const float*)d_in[16];
    const float* bn2_g    = (const float*)d_in[17];
    const float* bn2_b    = (const float*)d_in[18];
    const float* filt     = (const float*)d_in[19];
    const float* fc_w     = (const float*)d_in[20];
    const float* fc_b     = (const float*)d_in[21];
    const float* bias_ent = (const float*)d_in[22];

    float* ws  = (float*)d_ws;
    float* o   = (float*)d_out;

    float* agg     = ws + OFF_AGG;
    float* agg_in  = agg;
    float* agg_out = agg + (long long)NENT * DD;
    int*   cnt     = (int*)(ws + OFF_CNT);
    int*   cursor  = (int*)(ws + OFF_CURSOR);
    int*   bsum    = (int*)(ws + OFF_BSUM);
    int*   elist   = (int*)(ws + OFF_ELIST);
    ushort* wth    = (ushort*)(ws + OFF_WT);            // 3x200x200 hi (reuses dead elist)
    ushort* wtl    = wth + 3 * DD * DD;                 // 3x200x200 lo
    float* acc0    = ws + OFF_ACC0;
    float* acc1    = ws + OFF_ACC1;
    float* dinv    = ws + OFF_DINV;
    float* rmat    = ws + OFF_RMAT;
    float* cheq    = ws + OFF_CHEQ;
    float* bn1s    = ws + OFF_BN1S;
    ushort* x2h    = (ushort*)(ws + OFF_X2H);
    ushort* x2l    = (ushort*)(ws + OFF_X2L);
    float* all_ent = agg_in;
    ushort* aeh    = (ushort*)agg_out;
    ushort* ael    = aeh + (long long)NENT * DD;

    // d_out scratch (fully overwritten by k_logits_mfma at the end)
    float*  conv_out = o + OD_CONV;
    ushort* fwh      = (ushort*)(o + OD_FWH);
    ushort* fwl      = (ushort*)(o + OD_FWL);
    float*  part     = o + OD_PART;

    hipMemsetAsync(ws + ZSTART, 0, (size_t)(ZEND - ZSTART) * 4, stream);

    // ---- CSR build + gather aggregation ----
    k_hist<<<(ETOT + 255) / 256, 256, 0, stream>>>(ei, cnt);
    k_dinv<<<(NENT + 255) / 256, 256, 0, stream>>>(cnt, dinv);
    k_scan1<<<98, 256, 0, stream>>>(cnt, bsum);
    k_scan2<<<1, 128, 0, stream>>>(bsum);
    k_scan3<<<98, 256, 0, stream>>>(cnt, bsum, cursor);
    k_fill<<<(ETOT + 255) / 256, 256, 0, stream>>>(ei, cursor, elist);
    k_agg<<<NSEG / 4, 256, 0, stream>>>(ei, et, cnt, elist, emb, init_rel, dinv, agg);

    // ---- encoder GEMMs + weight conversions ----
    k_cvt3w<<<(3 * DD * DD + 255) / 256, 256, 0, stream>>>(w_in, w_out, w_loop, wth, wtl);
    k_allent_mfma<<<(NENT + 63) / 64, 128, 0, stream>>>(agg, emb, loop_rel, wth, wtl, all_ent);
    k_cvt<<<((NENT * DD / 4) + 255) / 256, 256, 0, stream>>>(all_ent, aeh, ael);
    k_cvtw<<<((DD * FLAT / 4) + 255) / 256, 256, 0, stream>>>(fc_w, fwh, fwl);
    k_rmat<<<400 / 16, 256, 0, stream>>>(init_rel, w_rel, rmat);

    // ---- decoder ----
    k_cheq<<<(BB * 400) / 256, 256, 0, stream>>>(sub, rel, perm, all_ent, rmat, cheq, acc0);
    k_conv<<<BB, 256, 0, stream>>>(cheq, acc0, bn0_g, bn0_b, filt, conv_out, acc1);
    k_bn1fin<<<1, 128, 0, stream>>>(acc1, bn1_g, bn1_b, bn1s);
    k_fc_mfma<<<dim3(BB / 64, FC_KS), 128, 0, stream>>>(conv_out, bn1s, fwh, fwl, part);
    k_bn2<<<DD, 256, 0, stream>>>(part, fc_b, bn2_g, bn2_b, x2h, x2l);
    k_logits_mfma<<<dim3((NENT + 511) / 512, BB / 64), 512, 0, stream>>>(
        x2h, x2l, aeh, ael, bias_ent, o);
}

// Round 6
// 1223.341 us; speedup vs baseline: 3.2428x; 1.0571x over previous
//
#include <hip/hip_runtime.h>

// ---------------- problem constants ----------------
#define ETOT  500000
#define EHALF 250000
#define NENT  50000
#define NSEG  (2 * NENT)   // segments: half*NENT + dst
#define DD    200
#define BB    1024
#define NF    96
#define FLAT  38400   // 96*400

// fc split-K config
#define FC_KS     20
#define FC_KSLICE 1920    // 38400/20
#define FC_NCHUNK 60      // 1920/32 (32-k chunks, double-buffered)

// ---------------- workspace layout (float32 offsets) ----------------
#define OFF_AGG      0LL          // 20,000,000  ([0,10M)=agg_in->all_ent, [10M,20M)=agg_out->aeh/ael)
// zeroed region: [ZSTART, ZEND)
#define ZSTART       20000000LL
#define OFF_CNT      20000000LL   // 100,004 ints (NSEG+1 used; becomes row_start after scan)
#define OFF_ACC0     20100004LL   //          2  (bn0 sum, sumsq)
#define OFF_ACC1     20100006LL   //        192  (bn1 sum[96], sumsq[96])
#define ZEND         20100198LL
// non-zeroed:
#define OFF_CURSOR   20304998LL   //    100,000 ints
#define OFF_BSUM     20404998LL   //        128 ints
#define OFF_ELIST    20405126LL   //    500,000 ints (dead after k_agg; wt planes reuse it)
#define OFF_WT       20405128LL   //    120,000 f32 = 240,000 ushort (3 transposed w hi+lo), 16B-aligned
#define OFF_DINV     20905126LL   //     50,000
#define OFF_RMAT     20955126LL   //     80,000
#define OFF_CHEQ     21035126LL   //    409,600
#define OFF_BN1S     21444726LL   //        192  (scale[96], shift[96])
#define OFF_X2H      21649720LL   //    102,400 f32 (= 204,800 ushort), 16B-aligned
#define OFF_X2L      21752120LL   //    102,400 f32
// total ws need ~= 21,854,520 f32 = 87.4 MB

// ---------------- d_out scratch layout (f32 offsets; out_size = 51,200,000) ----
#define OD_CONV 0LL          // 39,321,600 (1024 x 38400 conv output, f32)
#define OD_FWH  39321600LL   //  3,840,000 f32 = 7,680,000 ushort (fc_w hi plane)
#define OD_FWL  43161600LL   //  3,840,000 f32 (fc_w lo plane)
#define OD_PART 47001600LL   //  4,096,000 f32 (FC_KS x 1024 x 200 partials) -> ends 51,097,600

typedef __attribute__((ext_vector_type(8))) short bf16x8;
typedef __attribute__((ext_vector_type(4))) float f32x4;

__device__ inline void bf16split(float v, ushort& h, ushort& l) {
    unsigned u = __float_as_uint(v);
    unsigned hu = u & 0xffff0000u;
    h = (ushort)(hu >> 16);
    float lf = v - __uint_as_float(hu);
    l = (ushort)(__float_as_uint(lf) >> 16);
}

// ================= CSR build =================

__global__ void k_hist(const int* __restrict__ ei, int* __restrict__ cnt) {
    int e = blockIdx.x * 256 + threadIdx.x;
    if (e < ETOT) {
        int seg = (e < EHALF ? 0 : NENT) + ei[ETOT + e];
        atomicAdd(&cnt[seg], 1);
    }
}

__global__ void k_dinv(const int* __restrict__ cnt, float* __restrict__ dinv) {
    int i = blockIdx.x * 256 + threadIdx.x;
    if (i < NENT) {
        int d = cnt[i] + cnt[NENT + i];
        dinv[i] = d > 0 ? rsqrtf((float)d) : 0.f;
    }
}

__global__ void k_scan1(int* __restrict__ cnt, int* __restrict__ bsum) {
    __shared__ int S[256];
    int base = blockIdx.x * 1024 + threadIdx.x * 4;
    int v[4], s = 0;
#pragma unroll
    for (int i = 0; i < 4; i++) { v[i] = (base + i <= NSEG) ? cnt[base + i] : 0; s += v[i]; }
    S[threadIdx.x] = s;
    __syncthreads();
    for (int off = 1; off < 256; off <<= 1) {
        int t = (threadIdx.x >= off) ? S[threadIdx.x - off] : 0;
        __syncthreads();
        S[threadIdx.x] += t;
        __syncthreads();
    }
    int run = S[threadIdx.x] - s;
#pragma unroll
    for (int i = 0; i < 4; i++) {
        if (base + i <= NSEG) cnt[base + i] = run;
        run += v[i];
    }
    if (threadIdx.x == 255) bsum[blockIdx.x] = S[255];
}

__global__ void k_scan2(int* __restrict__ bsum) {
    __shared__ int S[128];
    int v = (threadIdx.x < 98) ? bsum[threadIdx.x] : 0;
    S[threadIdx.x] = v;
    __syncthreads();
    for (int off = 1; off < 128; off <<= 1) {
        int t = (threadIdx.x >= off) ? S[threadIdx.x - off] : 0;
        __syncthreads();
        S[threadIdx.x] += t;
        __syncthreads();
    }
    if (threadIdx.x < 98) bsum[threadIdx.x] = S[threadIdx.x] - v;
}

__global__ void k_scan3(int* __restrict__ cnt, const int* __restrict__ bsum,
                        int* __restrict__ cursor) {
    int add = bsum[blockIdx.x];
    int base = blockIdx.x * 1024 + threadIdx.x * 4;
#pragma unroll
    for (int i = 0; i < 4; i++) {
        int idx = base + i;
        if (idx <= NSEG) {
            int v = cnt[idx] + add;
            cnt[idx] = v;
            if (idx < NSEG) cursor[idx] = v;
        }
    }
}

__global__ void k_fill(const int* __restrict__ ei, int* __restrict__ cursor,
                       int* __restrict__ elist) {
    int e = blockIdx.x * 256 + threadIdx.x;
    if (e < ETOT) {
        int seg = (e < EHALF ? 0 : NENT) + ei[ETOT + e];
        int pos = atomicAdd(&cursor[seg], 1);
        elist[pos] = e;
    }
}

// gather-aggregate: one wave per segment (4 waves/block), no float atomics
__global__ void k_agg(const int* __restrict__ ei, const int* __restrict__ et,
                      const int* __restrict__ row_start, const int* __restrict__ elist,
                      const float* __restrict__ emb, const float* __restrict__ rel,
                      const float* __restrict__ dinv, float* __restrict__ agg) {
    int seg = blockIdx.x * 4 + (threadIdx.x >> 6);
    int lane = threadIdx.x & 63;
    int dst = seg - (seg >= NENT ? NENT : 0);
    float dd = dinv[dst];
    int s = row_start[seg], e = row_start[seg + 1];
    bool act = lane < 50;
    float4 acc = {0.f, 0.f, 0.f, 0.f};
    for (int i = s; i < e; i++) {
        int ed = elist[i];
        int src = ei[ed];
        int t = et[ed];
        float nrm = dinv[src] * dd;
        if (act) {
            float4 a = *(const float4*)&emb[(long long)src * DD + lane * 4];
            float4 b = *(const float4*)&rel[t * DD + lane * 4];
            acc.x += (a.x - b.x) * nrm;
            acc.y += (a.y - b.y) * nrm;
            acc.z += (a.z - b.z) * nrm;
            acc.w += (a.w - b.w) * nrm;
        }
    }
    if (act) *(float4*)&agg[(long long)seg * DD + lane * 4] = acc;
}

// ================= encoder GEMMs =================

// transpose + hi/lo-split the three 200x200 weights: wt[s][j][k] = split(w_s[k][j])
__global__ void k_cvt3w(const float* __restrict__ w_in, const float* __restrict__ w_out,
                        const float* __restrict__ w_loop,
                        ushort* __restrict__ wth, ushort* __restrict__ wtl) {
    int idx = blockIdx.x * 256 + threadIdx.x;
    if (idx >= 3 * DD * DD) return;
    int s = idx / (DD * DD);
    int rem = idx - s * DD * DD;
    int j = rem / DD, k = rem - (rem / DD) * DD;
    const float* w = (s == 0) ? w_in : (s == 1) ? w_out : w_loop;
    ushort h, l;
    bf16split(w[k * DD + j], h, l);
    wth[idx] = h;
    wtl[idx] = l;
}

// all_ent = tanh((agg_in@w_in + agg_out@w_out + (emb-loop_rel)@w_loop)/3) via bf16-split MFMA
__global__ __launch_bounds__(128) void k_allent_mfma(
        const float* __restrict__ agg, const float* __restrict__ emb,
        const float* __restrict__ loop_rel,
        const ushort* __restrict__ wth, const ushort* __restrict__ wtl,
        float* __restrict__ all_ent) {
    __shared__ __align__(16) ushort Ah[64][DD];
    __shared__ __align__(16) ushort Al[64][DD];
    __shared__ float lr[DD];
    int tid = threadIdx.x;
    for (int i = tid; i < DD; i += 128) lr[i] = loop_rel[i];
    int r0 = blockIdx.x * 64;
    int wid = tid >> 6, lane = tid & 63, l15 = lane & 15, q = lane >> 4;

    f32x4 zero4 = {0.f, 0.f, 0.f, 0.f};
    f32x4 acc[2][13];
#pragma unroll
    for (int m = 0; m < 2; m++)
#pragma unroll
        for (int n = 0; n < 13; n++) acc[m][n] = zero4;

    int jc[13];
#pragma unroll
    for (int n = 0; n < 13; n++) {
        int j = n * 16 + l15;
        jc[n] = j < DD ? j : DD - 1;
    }

    for (int s = 0; s < 3; s++) {
        __syncthreads();
        for (int i = tid; i < 3200; i += 128) {
            int row = i / 50, c4 = (i % 50) * 4;
            int rg = r0 + row;
            if (rg > NENT - 1) rg = NENT - 1;
            float4 v;
            if (s == 2) {
                v = *(const float4*)&emb[(long long)rg * DD + c4];
                v.x -= lr[c4]; v.y -= lr[c4 + 1]; v.z -= lr[c4 + 2]; v.w -= lr[c4 + 3];
            } else {
                v = *(const float4*)&agg[(long long)(s * NENT + rg) * DD + c4];
            }
            ushort4 h, l;
            bf16split(v.x, h.x, l.x);
            bf16split(v.y, h.y, l.y);
            bf16split(v.z, h.z, l.z);
            bf16split(v.w, h.w, l.w);
            *(ushort4*)&Ah[row][c4] = h;
            *(ushort4*)&Al[row][c4] = l;
        }
        __syncthreads();
        const ushort* bhb = wth + s * (DD * DD);
        const ushort* blb = wtl + s * (DD * DD);
#pragma unroll
        for (int kk = 0; kk < 6; kk++) {
            int k0 = kk * 32 + q * 8;
            bf16x8 ah[2], al[2];
#pragma unroll
            for (int m = 0; m < 2; m++) {
                ah[m] = *(const bf16x8*)&Ah[wid * 32 + m * 16 + l15][k0];
                al[m] = *(const bf16x8*)&Al[wid * 32 + m * 16 + l15][k0];
            }
#pragma unroll
            for (int n = 0; n < 13; n++) {
                bf16x8 bh = *(const bf16x8*)&bhb[jc[n] * DD + k0];
                bf16x8 bl = *(const bf16x8*)&blb[jc[n] * DD + k0];
#pragma unroll
                for (int m = 0; m < 2; m++) {
                    acc[m][n] = __builtin_amdgcn_mfma_f32_16x16x32_bf16(ah[m], bh, acc[m][n], 0, 0, 0);
                    acc[m][n] = __builtin_amdgcn_mfma_f32_16x16x32_bf16(ah[m], bl, acc[m][n], 0, 0, 0);
                    acc[m][n] = __builtin_amdgcn_mfma_f32_16x16x32_bf16(al[m], bh, acc[m][n], 0, 0, 0);
                }
            }
        }
        {   // partial k-step 192..199 (quarter 0 only)
            bf16x8 zf = {0, 0, 0, 0, 0, 0, 0, 0};
            bf16x8 ah[2], al[2];
#pragma unroll
            for (int m = 0; m < 2; m++) { ah[m] = zf; al[m] = zf; }
            if (q == 0) {
#pragma unroll
                for (int m = 0; m < 2; m++) {
                    ah[m] = *(const bf16x8*)&Ah[wid * 32 + m * 16 + l15][192];
                    al[m] = *(const bf16x8*)&Al[wid * 32 + m * 16 + l15][192];
                }
            }
#pragma unroll
            for (int n = 0; n < 13; n++) {
                bf16x8 bh = zf, bl = zf;
                if (q == 0) {
                    bh = *(const bf16x8*)&bhb[jc[n] * DD + 192];
                    bl = *(const bf16x8*)&blb[jc[n] * DD + 192];
                }
#pragma unroll
                for (int m = 0; m < 2; m++) {
                    acc[m][n] = __builtin_amdgcn_mfma_f32_16x16x32_bf16(ah[m], bh, acc[m][n], 0, 0, 0);
                    acc[m][n] = __builtin_amdgcn_mfma_f32_16x16x32_bf16(ah[m], bl, acc[m][n], 0, 0, 0);
                    acc[m][n] = __builtin_amdgcn_mfma_f32_16x16x32_bf16(al[m], bh, acc[m][n], 0, 0, 0);
                }
            }
        }
    }
#pragma unroll
    for (int n = 0; n < 13; n++) {
        int j = n * 16 + l15;
        if (j < DD) {
#pragma unroll
            for (int m = 0; m < 2; m++) {
                int row = r0 + wid * 32 + m * 16 + q * 4;
#pragma unroll
                for (int r = 0; r < 4; r++) {
                    if (row + r < NENT)
                        all_ent[(long long)(row + r) * DD + j] = tanhf(acc[m][n][r] * (1.f / 3.f));
                }
            }
        }
    }
}

// convert all_ent f32 -> bf16 hi/lo (over agg_out region), 4 elems/thread
__global__ void k_cvt(const float* __restrict__ src, ushort* __restrict__ hi,
                      ushort* __restrict__ lo) {
    long long i = (long long)(blockIdx.x * 256 + threadIdx.x) * 4;
    if (i >= (long long)NENT * DD) return;
    float4 v = *(const float4*)&src[i];
    ushort4 h, l;
    bf16split(v.x, h.x, l.x);
    bf16split(v.y, h.y, l.y);
    bf16split(v.z, h.z, l.z);
    bf16split(v.w, h.w, l.w);
    *(ushort4*)&hi[i] = h;
    *(ushort4*)&lo[i] = l;
}

// convert fc_w f32 -> bf16 hi/lo planes (into d_out tail)
__global__ void k_cvtw(const float* __restrict__ src, ushort* __restrict__ hi,
                       ushort* __restrict__ lo) {
    long long i = (long long)(blockIdx.x * 256 + threadIdx.x) * 4;
    if (i >= (long long)DD * FLAT) return;
    float4 v = *(const float4*)&src[i];
    ushort4 h, l;
    bf16split(v.x, h.x, l.x);
    bf16split(v.y, h.y, l.y);
    bf16split(v.z, h.z, l.z);
    bf16split(v.w, h.w, l.w);
    *(ushort4*)&hi[i] = h;
    *(ushort4*)&lo[i] = l;
}

__global__ void k_rmat(const float* __restrict__ init_rel, const float* __restrict__ w_rel,
                       float* __restrict__ rmat) {
    __shared__ float S[16][DD];
    int r0 = blockIdx.x * 16;
    for (int i = threadIdx.x; i < 16 * DD; i += 256)
        S[i / DD][i % DD] = init_rel[(r0 + i / DD) * DD + i % DD];
    __syncthreads();
    int j = threadIdx.x;
    if (j < DD) {
        float acc[16];
#pragma unroll
        for (int rr = 0; rr < 16; rr++) acc[rr] = 0.f;
        for (int k = 0; k < DD; k += 4) {
            float wx = w_rel[(k + 0) * DD + j], wy = w_rel[(k + 1) * DD + j],
                  wz = w_rel[(k + 2) * DD + j], ww = w_rel[(k + 3) * DD + j];
#pragma unroll
            for (int rr = 0; rr < 16; rr++) {
                float4 a = *(const float4*)&S[rr][k];
                acc[rr] += a.x * wx + a.y * wy + a.z * wz + a.w * ww;
            }
        }
#pragma unroll
        for (int rr = 0; rr < 16; rr++) rmat[(r0 + rr) * DD + j] = acc[rr];
    }
}

// ================= decoder =================

__global__ void k_cheq(const int* __restrict__ sub, const int* __restrict__ rel,
                       const int* __restrict__ perm, const float* __restrict__ all_ent,
                       const float* __restrict__ rmat, float* __restrict__ cheq,
                       float* __restrict__ acc0) {
    int i = blockIdx.x * 256 + threadIdx.x;
    int b = i / 400, p = i % 400;
    int c = perm[p];
    float v = (c < DD) ? all_ent[(long long)sub[b] * DD + c]
                       : rmat[rel[b] * DD + (c - DD)];
    cheq[i] = v;
    __shared__ float s1[256], s2[256];
    s1[threadIdx.x] = v;
    s2[threadIdx.x] = v * v;
    __syncthreads();
    for (int st = 128; st > 0; st >>= 1) {
        if (threadIdx.x < st) { s1[threadIdx.x] += s1[threadIdx.x + st]; s2[threadIdx.x] += s2[threadIdx.x + st]; }
        __syncthreads();
    }
    if (threadIdx.x == 0) { atomicAdd(&acc0[0], s1[0]); atomicAdd(&acc0[1], s2[0]); }
}

__global__ void k_conv(const float* __restrict__ cheq, const float* __restrict__ acc0,
                       const float* __restrict__ bn0_g, const float* __restrict__ bn0_b,
                       const float* __restrict__ filt, float* __restrict__ conv_out,
                       float* __restrict__ acc1) {
    __shared__ float xp[28 * 28];
    __shared__ float fl[NF * 81];
    __shared__ float csum[NF], csq[NF];
    int b = blockIdx.x;
    const float invN = 1.f / (BB * 400.f);
    float mean = acc0[0] * invN;
    float var = acc0[1] * invN - mean * mean;
    float sc = rsqrtf(var + 1e-5f) * bn0_g[0];
    float sh = bn0_b[0] - mean * sc;
    for (int i = threadIdx.x; i < 28 * 28; i += 256) {
        int r = i / 28, c = i % 28;
        int rr = (r + 16) % 20, cc = (c + 16) % 20;
        xp[i] = cheq[b * 400 + rr * 20 + cc] * sc + sh;
    }
    for (int i = threadIdx.x; i < NF * 81; i += 256) fl[i] = filt[i];
    if (threadIdx.x < NF) { csum[threadIdx.x] = 0.f; csq[threadIdx.x] = 0.f; }
    __syncthreads();
    for (int t = threadIdx.x; t < NF * 20; t += 256) {
        int ch = t / 20, row = t % 20;
        float acc[20];
#pragma unroll
        for (int c2 = 0; c2 < 20; c2++) acc[c2] = 0.f;
        for (int di = 0; di < 9; di++) {
            const float* xrow = &xp[(row + di) * 28];
#pragma unroll
            for (int dj = 0; dj < 9; dj++) {
                float f = fl[ch * 81 + di * 9 + dj];
#pragma unroll
                for (int c2 = 0; c2 < 20; c2++) acc[c2] = fmaf(xrow[c2 + dj], f, acc[c2]);
            }
        }
        float s = 0.f, q = 0.f;
        long long base = (long long)b * FLAT + ch * 400 + row * 20;
#pragma unroll
        for (int c2 = 0; c2 < 20; c2++) {
            float v = acc[c2];
            s += v; q += v * v;
            conv_out[base + c2] = v;
        }
        atomicAdd(&csum[ch], s);
        atomicAdd(&csq[ch], q);
    }
    __syncthreads();
    if (threadIdx.x < NF) {
        atomicAdd(&acc1[threadIdx.x], csum[threadIdx.x]);
        atomicAdd(&acc1[NF + threadIdx.x], csq[threadIdx.x]);
    }
}

__global__ void k_bn1fin(const float* __restrict__ acc1, const float* __restrict__ g1,
                         const float* __restrict__ b1, float* __restrict__ bn1s) {
    int c = threadIdx.x;
    if (c >= NF) return;
    const float invN = 1.f / (BB * 400.f);
    float m = acc1[c] * invN;
    float v = acc1[NF + c] * invN - m * m;
    float sc = rsqrtf(v + 1e-5f) * g1[c];
    bn1s[c] = sc;
    bn1s[NF + c] = b1[c] - m * sc;
}

// ---- fc GEMM via bf16-split MFMA, restructured ----
// grid (16 M-tiles, 2 N-halves, FC_KS K-slices); 128 thr = 2 waves.
// wave tile 32x112 (2 m x 7 n frags). A direct from global (bn1+relu+split in regs);
// B double-buffered in LDS, 32-k chunks, one barrier per chunk.
__device__ __forceinline__ void fc_stageB(int tid, int nh, int k0,
        const ushort* __restrict__ fwh, const ushort* __restrict__ fwl,
        ushort (*Bh)[40], ushort (*Bl)[40]) {
    for (int i = tid; i < 896; i += 128) {     // 2 planes x 112 rows x 4 segs of 16B
        int pl = (i >= 448);
        int ii = pl ? i - 448 : i;
        int row = ii >> 2;
        int koff = (ii & 3) * 8;
        int j = nh * 112 + row;
        int jr = j < DD ? j : DD - 1;
        const ushort* src = (pl ? fwl : fwh) + (long long)jr * FLAT + k0 + koff;
        uint4 v = *(const uint4*)src;
        if (pl) *(uint4*)&Bl[row][koff] = v;
        else    *(uint4*)&Bh[row][koff] = v;
    }
}

__global__ __launch_bounds__(128) void k_fc_mfma(
        const float* __restrict__ conv_out, const float* __restrict__ bn1s,
        const ushort* __restrict__ fwh, const ushort* __restrict__ fwl,
        float* __restrict__ part) {
    __shared__ __align__(16) ushort Bh[2][112][40];   // +8 pad -> 2-way banks (free)
    __shared__ __align__(16) ushort Bl[2][112][40];
    __shared__ float bns[192];
    int tid = threadIdx.x;
    for (int i = tid; i < 192; i += 128) bns[i] = bn1s[i];
    int b0 = blockIdx.x * 64;
    int nh = blockIdx.y;
    int ksl = blockIdx.z;
    int kbase = ksl * FC_KSLICE;
    int wid = tid >> 6, lane = tid & 63, l15 = lane & 15, q = lane >> 4;

    const float* aptr0 = conv_out + (long long)(b0 + wid * 32 + l15) * FLAT;
    const float* aptr1 = aptr0 + 16LL * FLAT;

    f32x4 zero4 = {0.f, 0.f, 0.f, 0.f};
    f32x4 acc[2][7];
#pragma unroll
    for (int m = 0; m < 2; m++)
#pragma unroll
        for (int n = 0; n < 7; n++) acc[m][n] = zero4;

    fc_stageB(tid, nh, kbase, fwh, fwl, Bh[0], Bl[0]);
    __syncthreads();

    for (int c = 0; c < FC_NCHUNK; c++) {
        int buf = c & 1;
        int k0 = kbase + c * 32 + q * 8;
        // A loads for this chunk (issue early)
        float4 a0 = *(const float4*)&aptr0[k0];
        float4 a0b = *(const float4*)&aptr0[k0 + 4];
        float4 a1 = *(const float4*)&aptr1[k0];
        float4 a1b = *(const float4*)&aptr1[k0 + 4];
        // prefetch next B chunk into the other buffer (flies under MFMA)
        if (c + 1 < FC_NCHUNK)
            fc_stageB(tid, nh, kbase + (c + 1) * 32, fwh, fwl, Bh[buf ^ 1], Bl[buf ^ 1]);
        // bn1 + relu + hi/lo split in regs (8 consecutive k share one channel: 400%8==0)
        int ch = k0 / 400;
        float sc = bns[ch], sh = bns[96 + ch];
        bf16x8 ah0, al0, ah1, al1;
        {
            float e[8];
            e[0]=fmaxf(a0.x*sc+sh,0.f); e[1]=fmaxf(a0.y*sc+sh,0.f);
            e[2]=fmaxf(a0.z*sc+sh,0.f); e[3]=fmaxf(a0.w*sc+sh,0.f);
            e[4]=fmaxf(a0b.x*sc+sh,0.f); e[5]=fmaxf(a0b.y*sc+sh,0.f);
            e[6]=fmaxf(a0b.z*sc+sh,0.f); e[7]=fmaxf(a0b.w*sc+sh,0.f);
#pragma unroll
            for (int t = 0; t < 8; t++) { ushort h, l; bf16split(e[t], h, l); ah0[t]=(short)h; al0[t]=(short)l; }
            e[0]=fmaxf(a1.x*sc+sh,0.f); e[1]=fmaxf(a1.y*sc+sh,0.f);
            e[2]=fmaxf(a1.z*sc+sh,0.f); e[3]=fmaxf(a1.w*sc+sh,0.f);
            e[4]=fmaxf(a1b.x*sc+sh,0.f); e[5]=fmaxf(a1b.y*sc+sh,0.f);
            e[6]=fmaxf(a1b.z*sc+sh,0.f); e[7]=fmaxf(a1b.w*sc+sh,0.f);
#pragma unroll
            for (int t = 0; t < 8; t++) { ushort h, l; bf16split(e[t], h, l); ah1[t]=(short)h; al1[t]=(short)l; }
        }
#pragma unroll
        for (int n = 0; n < 7; n++) {
            bf16x8 bh = *(const bf16x8*)&Bh[buf][n * 16 + l15][q * 8];
            bf16x8 bl = *(const bf16x8*)&Bl[buf][n * 16 + l15][q * 8];
            acc[0][n] = __builtin_amdgcn_mfma_f32_16x16x32_bf16(ah0, bh, acc[0][n], 0, 0, 0);
            acc[0][n] = __builtin_amdgcn_mfma_f32_16x16x32_bf16(ah0, bl, acc[0][n], 0, 0, 0);
            acc[0][n] = __builtin_amdgcn_mfma_f32_16x16x32_bf16(al0, bh, acc[0][n], 0, 0, 0);
            acc[1][n] = __builtin_amdgcn_mfma_f32_16x16x32_bf16(ah1, bh, acc[1][n], 0, 0, 0);
            acc[1][n] = __builtin_amdgcn_mfma_f32_16x16x32_bf16(ah1, bl, acc[1][n], 0, 0, 0);
            acc[1][n] = __builtin_amdgcn_mfma_f32_16x16x32_bf16(al1, bh, acc[1][n], 0, 0, 0);
        }
        __syncthreads();
    }
    // epilogue: part[ksl][row][j]; C layout row=(q*4+r), col=l15 per 16x16 frag
    long long pbase = (long long)ksl * (BB * DD);
#pragma unroll
    for (int n = 0; n < 7; n++) {
        int j = nh * 112 + n * 16 + l15;
        if (j < DD) {
#pragma unroll
            for (int m = 0; m < 2; m++) {
                int rowb = b0 + wid * 32 + m * 16 + q * 4;
#pragma unroll
                for (int r = 0; r < 4; r++)
                    part[pbase + (long long)(rowb + r) * DD + j] = acc[m][n][r];
            }
        }
    }
}

// bn2 over batch, folding the split-K reduction; emits x2 bf16 hi/lo only
__global__ void k_bn2(const float* __restrict__ part, const float* __restrict__ fc_b,
                      const float* __restrict__ g2, const float* __restrict__ b2,
                      ushort* __restrict__ x2h, ushort* __restrict__ x2l) {
    int j = blockIdx.x;
    float vals[4];
    float s = 0.f, q = 0.f;
#pragma unroll
    for (int i = 0; i < 4; i++) {
        int b = threadIdx.x + i * 256;
        float v = fc_b[j];
#pragma unroll
        for (int ks = 0; ks < FC_KS; ks++)
            v += part[(long long)ks * (BB * DD) + (long long)b * DD + j];
        vals[i] = v;
        s += v; q += v * v;
    }
    __shared__ float r1[256], r2[256];
    __shared__ float bc[2];
    r1[threadIdx.x] = s; r2[threadIdx.x] = q;
    __syncthreads();
    for (int st = 128; st > 0; st >>= 1) {
        if (threadIdx.x < st) { r1[threadIdx.x] += r1[threadIdx.x + st]; r2[threadIdx.x] += r2[threadIdx.x + st]; }
        __syncthreads();
    }
    if (threadIdx.x == 0) {
        float m = r1[0] * (1.f / BB);
        float v = r2[0] * (1.f / BB) - m * m;
        float sc = rsqrtf(v + 1e-5f) * g2[j];
        bc[0] = sc; bc[1] = b2[j] - m * sc;
    }
    __syncthreads();
    float sc = bc[0], sh = bc[1];
#pragma unroll
    for (int i = 0; i < 4; i++) {
        int b = threadIdx.x + i * 256;
        float v = fmaxf(vals[i] * sc + sh, 0.f);
        ushort h, l;
        bf16split(v, h, l);
        x2h[b * DD + j] = h;
        x2l[b * DD + j] = l;
    }
}

// logits = sigmoid(x2 @ all_ent^T + bias) via bf16-split MFMA (hi*hi + hi*lo + lo*hi)
__global__ __launch_bounds__(512) void k_logits_mfma(
        const ushort* __restrict__ x2h, const ushort* __restrict__ x2l,
        const ushort* __restrict__ aeh, const ushort* __restrict__ ael,
        const float* __restrict__ bias, float* __restrict__ out) {
    __shared__ ushort Ah[64 * DD];
    __shared__ ushort Al[64 * DD];
    int m0 = blockIdx.y * 64;
    {
        const uint4* g0 = (const uint4*)(x2h + (long long)m0 * DD);
        const uint4* g1 = (const uint4*)(x2l + (long long)m0 * DD);
        uint4* s0 = (uint4*)Ah;
        uint4* s1 = (uint4*)Al;
        for (int i = threadIdx.x; i < 1600; i += 512) { s0[i] = g0[i]; s1[i] = g1[i]; }
    }
    __syncthreads();
    int wid = threadIdx.x >> 6;
    int lane = threadIdx.x & 63;
    int l15 = lane & 15, q = lane >> 4;
    int e0 = blockIdx.x * 512 + wid * 64;

    f32x4 zero4 = {0.f, 0.f, 0.f, 0.f};
    f32x4 acc[4][4];
#pragma unroll
    for (int m = 0; m < 4; m++)
#pragma unroll
        for (int n = 0; n < 4; n++) acc[m][n] = zero4;

    long long brow[4];
#pragma unroll
    for (int n = 0; n < 4; n++) {
        int e = e0 + n * 16 + l15;
        if (e > NENT - 1) e = NENT - 1;
        brow[n] = (long long)e * DD;
    }
    int aoff = q * 8;

#pragma unroll
    for (int kk = 0; kk < 6; kk++) {
        int k0 = kk * 32 + aoff;
        bf16x8 ah[4], al[4], bh[4], bl[4];
#pragma unroll
        for (int m = 0; m < 4; m++) {
            int off = (m * 16 + l15) * DD + k0;
            ah[m] = *(const bf16x8*)&Ah[off];
            al[m] = *(const bf16x8*)&Al[off];
        }
#pragma unroll
        for (int n = 0; n < 4; n++) {
            bh[n] = *(const bf16x8*)&aeh[brow[n] + k0];
            bl[n] = *(const bf16x8*)&ael[brow[n] + k0];
        }
#pragma unroll
        for (int m = 0; m < 4; m++)
#pragma unroll
            for (int n = 0; n < 4; n++) {
                acc[m][n] = __builtin_amdgcn_mfma_f32_16x16x32_bf16(ah[m], bh[n], acc[m][n], 0, 0, 0);
                acc[m][n] = __builtin_amdgcn_mfma_f32_16x16x32_bf16(ah[m], bl[n], acc[m][n], 0, 0, 0);
                acc[m][n] = __builtin_amdgcn_mfma_f32_16x16x32_bf16(al[m], bh[n], acc[m][n], 0, 0, 0);
            }
    }
    {
        bf16x8 zf = {0, 0, 0, 0, 0, 0, 0, 0};
        bf16x8 ah[4], al[4], bh[4], bl[4];
#pragma unroll
        for (int m = 0; m < 4; m++) { ah[m] = zf; al[m] = zf; }
#pragma unroll
        for (int n = 0; n < 4; n++) { bh[n] = zf; bl[n] = zf; }
        if (q == 0) {
#pragma unroll
            for (int m = 0; m < 4; m++) {
                int off = (m * 16 + l15) * DD + 192;
                ah[m] = *(const bf16x8*)&Ah[off];
                al[m] = *(const bf16x8*)&Al[off];
            }
#pragma unroll
            for (int n = 0; n < 4; n++) {
                bh[n] = *(const bf16x8*)&aeh[brow[n] + 192];
                bl[n] = *(const bf16x8*)&ael[brow[n] + 192];
            }
        }
#pragma unroll
        for (int m = 0; m < 4; m++)
#pragma unroll
            for (int n = 0; n < 4; n++) {
                acc[m][n] = __builtin_amdgcn_mfma_f32_16x16x32_bf16(ah[m], bh[n], acc[m][n], 0, 0, 0);
                acc[m][n] = __builtin_amdgcn_mfma_f32_16x16x32_bf16(ah[m], bl[n], acc[m][n], 0, 0, 0);
                acc[m][n] = __builtin_amdgcn_mfma_f32_16x16x32_bf16(al[m], bh[n], acc[m][n], 0, 0, 0);
            }
    }
#pragma unroll
    for (int n = 0; n < 4; n++) {
        int e = e0 + n * 16 + l15;
        if (e < NENT) {
            float bv = bias[e];
#pragma unroll
            for (int m = 0; m < 4; m++) {
                int row = m0 + m * 16 + q * 4;
#pragma unroll
                for (int r = 0; r < 4; r++) {
                    float t = acc[m][n][r] + bv;
                    out[(long long)(row + r) * NENT + e] = 1.f / (1.f + __expf(-t));
                }
            }
        }
    }
}

// ================= host =================

extern "C" void kernel_launch(void* const* d_in, const int* in_sizes, int n_in,
                              void* d_out, int out_size, void* d_ws, size_t ws_size,
                              hipStream_t stream) {
    const int*   sub      = (const int*)d_in[0];
    const int*   rel      = (const int*)d_in[1];
    const int*   ei       = (const int*)d_in[3];
    const int*   et       = (const int*)d_in[4];
    const int*   perm     = (const int*)d_in[5];
    const float* emb      = (const float*)d_in[6];
    const float* init_rel = (const float*)d_in[7];
    const float* w_in     = (const float*)d_in[8];
    const float* w_out    = (const float*)d_in[9];
    const float* w_loop   = (const float*)d_in[10];
    const float* w_rel    = (const float*)d_in[11];
    const float* loop_rel = (const float*)d_in[12];
    const float* bn0_g    = (const float*)d_in[13];
    const float* bn0_b    = (const float*)d_in[14];
    const float* bn1_g    = (const float*)d_in[15];
    const float* bn1_b    = (const float*)d_in[16];
    const float* bn2_g    = (const float*)d_in[17];
    const float* bn2_b    = (const float*)d_in[18];
    const float* filt     = (const float*)d_in[19];
    const float* fc_w     = (const float*)d_in[20];
    const float* fc_b     = (const float*)d_in[21];
    const float* bias_ent = (const float*)d_in[22];

    float* ws  = (float*)d_ws;
    float* o   = (float*)d_out;

    float* agg     = ws + OFF_AGG;
    float* agg_in  = agg;
    float* agg_out = agg + (long long)NENT * DD;
    int*   cnt     = (int*)(ws + OFF_CNT);
    int*   cursor  = (int*)(ws + OFF_CURSOR);
    int*   bsum    = (int*)(ws + OFF_BSUM);
    int*   elist   = (int*)(ws + OFF_ELIST);
    ushort* wth    = (ushort*)(ws + OFF_WT);
    ushort* wtl    = wth + 3 * DD * DD;
    float* acc0    = ws + OFF_ACC0;
    float* acc1    = ws + OFF_ACC1;
    float* dinv    = ws + OFF_DINV;
    float* rmat    = ws + OFF_RMAT;
    float* cheq    = ws + OFF_CHEQ;
    float* bn1s    = ws + OFF_BN1S;
    ushort* x2h    = (ushort*)(ws + OFF_X2H);
    ushort* x2l    = (ushort*)(ws + OFF_X2L);
    float* all_ent = agg_in;
    ushort* aeh    = (ushort*)agg_out;
    ushort* ael    = aeh + (long long)NENT * DD;

    // d_out scratch (fully overwritten by k_logits_mfma at the end)
    float*  conv_out = o + OD_CONV;
    ushort* fwh      = (ushort*)(o + OD_FWH);
    ushort* fwl      = (ushort*)(o + OD_FWL);
    float*  part     = o + OD_PART;

    hipMemsetAsync(ws + ZSTART, 0, (size_t)(ZEND - ZSTART) * 4, stream);

    // ---- CSR build + gather aggregation ----
    k_hist<<<(ETOT + 255) / 256, 256, 0, stream>>>(ei, cnt);
    k_dinv<<<(NENT + 255) / 256, 256, 0, stream>>>(cnt, dinv);
    k_scan1<<<98, 256, 0, stream>>>(cnt, bsum);
    k_scan2<<<1, 128, 0, stream>>>(bsum);
    k_scan3<<<98, 256, 0, stream>>>(cnt, bsum, cursor);
    k_fill<<<(ETOT + 255) / 256, 256, 0, stream>>>(ei, cursor, elist);
    k_agg<<<NSEG / 4, 256, 0, stream>>>(ei, et, cnt, elist, emb, init_rel, dinv, agg);

    // ---- encoder GEMMs + weight conversions ----
    k_cvt3w<<<(3 * DD * DD + 255) / 256, 256, 0, stream>>>(w_in, w_out, w_loop, wth, wtl);
    k_allent_mfma<<<(NENT + 63) / 64, 128, 0, stream>>>(agg, emb, loop_rel, wth, wtl, all_ent);
    k_cvt<<<((NENT * DD / 4) + 255) / 256, 256, 0, stream>>>(all_ent, aeh, ael);
    k_cvtw<<<((DD * FLAT / 4) + 255) / 256, 256, 0, stream>>>(fc_w, fwh, fwl);
    k_rmat<<<400 / 16, 256, 0, stream>>>(init_rel, w_rel, rmat);

    // ---- decoder ----
    k_cheq<<<(BB * 400) / 256, 256, 0, stream>>>(sub, rel, perm, all_ent, rmat, cheq, acc0);
    k_conv<<<BB, 256, 0, stream>>>(cheq, acc0, bn0_g, bn0_b, filt, conv_out, acc1);
    k_bn1fin<<<1, 128, 0, stream>>>(acc1, bn1_g, bn1_b, bn1s);
    k_fc_mfma<<<dim3(BB / 64, 2, FC_KS), 128, 0, stream>>>(conv_out, bn1s, fwh, fwl, part);
    k_bn2<<<DD, 256, 0, stream>>>(part, fc_b, bn2_g, bn2_b, x2h, x2l);
    k_logits_mfma<<<dim3((NENT + 511) / 512, BB / 64), 512, 0, stream>>>(
        x2h, x2l, aeh, ael, bias_ent, o);
}

// Round 7
// 1123.443 us; speedup vs baseline: 3.5312x; 1.0889x over previous
//
#include <hip/hip_runtime.h>

// ---------------- problem constants ----------------
#define ETOT  500000
#define EHALF 250000
#define NENT  50000
#define NSEG  (2 * NENT)   // segments: half*NENT + dst
#define DD    200
#define BB    1024
#define NF    96
#define FLAT  38400   // 96*400

// fc split-K config
#define FC_KS     20
#define FC_KSLICE 1920    // 38400/20
#define FC_NCHUNK 60      // 1920/32 (32-k chunks, double-buffered)

// logits config
#define LE 64             // entities per block (LDS strip)

// ---------------- workspace layout (float32 offsets) ----------------
#define OFF_AGG      0LL          // 20,000,000  ([0,10M)=agg_in->all_ent, [10M,20M)=agg_out->aeh/ael)
// zeroed region: [ZSTART, ZEND)
#define ZSTART       20000000LL
#define OFF_CNT      20000000LL   // 100,004 ints (NSEG+1 used; becomes row_start after scan)
#define OFF_ACC0     20100004LL   //          2  (bn0 sum, sumsq)
#define OFF_ACC1     20100006LL   //        192  (bn1 sum[96], sumsq[96])
#define ZEND         20100198LL
// non-zeroed:
#define OFF_CURSOR   20304998LL   //    100,000 ints
#define OFF_BSUM     20404998LL   //        128 ints
#define OFF_ELIST    20405126LL   //    500,000 ints (dead after k_agg; wt planes reuse it)
#define OFF_WT       20405128LL   //    120,000 f32 = 240,000 ushort (3 transposed w hi+lo), 16B-aligned
#define OFF_DINV     20905126LL   //     50,000
#define OFF_RMAT     20955126LL   //     80,000
#define OFF_CHEQ     21035126LL   //    409,600
#define OFF_BN1S     21444726LL   //        192  (scale[96], shift[96])
#define OFF_X2H      21649720LL   //    102,400 f32 (= 204,800 ushort), 16B-aligned
#define OFF_X2L      21752120LL   //    102,400 f32
// total ws need ~= 21,854,520 f32 = 87.4 MB

// ---------------- d_out scratch layout (f32 offsets; out_size = 51,200,000) ----
#define OD_CONV 0LL          // 39,321,600 (1024 x 38400 conv output, f32)
#define OD_FWH  39321600LL   //  3,840,000 f32 = 7,680,000 ushort (fc_w hi plane)
#define OD_FWL  43161600LL   //  3,840,000 f32 (fc_w lo plane)
#define OD_PART 47001600LL   //  4,096,000 f32 (FC_KS x 1024 x 200 partials) -> ends 51,097,600

typedef __attribute__((ext_vector_type(8))) short bf16x8;
typedef __attribute__((ext_vector_type(4))) float f32x4;

__device__ inline void bf16split(float v, ushort& h, ushort& l) {
    unsigned u = __float_as_uint(v);
    unsigned hu = u & 0xffff0000u;
    h = (ushort)(hu >> 16);
    float lf = v - __uint_as_float(hu);
    l = (ushort)(__float_as_uint(lf) >> 16);
}

// ================= CSR build =================

__global__ void k_hist(const int* __restrict__ ei, int* __restrict__ cnt) {
    int e = blockIdx.x * 256 + threadIdx.x;
    if (e < ETOT) {
        int seg = (e < EHALF ? 0 : NENT) + ei[ETOT + e];
        atomicAdd(&cnt[seg], 1);
    }
}

__global__ void k_dinv(const int* __restrict__ cnt, float* __restrict__ dinv) {
    int i = blockIdx.x * 256 + threadIdx.x;
    if (i < NENT) {
        int d = cnt[i] + cnt[NENT + i];
        dinv[i] = d > 0 ? rsqrtf((float)d) : 0.f;
    }
}

__global__ void k_scan1(int* __restrict__ cnt, int* __restrict__ bsum) {
    __shared__ int S[256];
    int base = blockIdx.x * 1024 + threadIdx.x * 4;
    int v[4], s = 0;
#pragma unroll
    for (int i = 0; i < 4; i++) { v[i] = (base + i <= NSEG) ? cnt[base + i] : 0; s += v[i]; }
    S[threadIdx.x] = s;
    __syncthreads();
    for (int off = 1; off < 256; off <<= 1) {
        int t = (threadIdx.x >= off) ? S[threadIdx.x - off] : 0;
        __syncthreads();
        S[threadIdx.x] += t;
        __syncthreads();
    }
    int run = S[threadIdx.x] - s;
#pragma unroll
    for (int i = 0; i < 4; i++) {
        if (base + i <= NSEG) cnt[base + i] = run;
        run += v[i];
    }
    if (threadIdx.x == 255) bsum[blockIdx.x] = S[255];
}

__global__ void k_scan2(int* __restrict__ bsum) {
    __shared__ int S[128];
    int v = (threadIdx.x < 98) ? bsum[threadIdx.x] : 0;
    S[threadIdx.x] = v;
    __syncthreads();
    for (int off = 1; off < 128; off <<= 1) {
        int t = (threadIdx.x >= off) ? S[threadIdx.x - off] : 0;
        __syncthreads();
        S[threadIdx.x] += t;
        __syncthreads();
    }
    if (threadIdx.x < 98) bsum[threadIdx.x] = S[threadIdx.x] - v;
}

__global__ void k_scan3(int* __restrict__ cnt, const int* __restrict__ bsum,
                        int* __restrict__ cursor) {
    int add = bsum[blockIdx.x];
    int base = blockIdx.x * 1024 + threadIdx.x * 4;
#pragma unroll
    for (int i = 0; i < 4; i++) {
        int idx = base + i;
        if (idx <= NSEG) {
            int v = cnt[idx] + add;
            cnt[idx] = v;
            if (idx < NSEG) cursor[idx] = v;
        }
    }
}

__global__ void k_fill(const int* __restrict__ ei, int* __restrict__ cursor,
                       int* __restrict__ elist) {
    int e = blockIdx.x * 256 + threadIdx.x;
    if (e < ETOT) {
        int seg = (e < EHALF ? 0 : NENT) + ei[ETOT + e];
        int pos = atomicAdd(&cursor[seg], 1);
        elist[pos] = e;
    }
}

// gather-aggregate: one wave per segment (4 waves/block), no float atomics
__global__ void k_agg(const int* __restrict__ ei, const int* __restrict__ et,
                      const int* __restrict__ row_start, const int* __restrict__ elist,
                      const float* __restrict__ emb, const float* __restrict__ rel,
                      const float* __restrict__ dinv, float* __restrict__ agg) {
    int seg = blockIdx.x * 4 + (threadIdx.x >> 6);
    int lane = threadIdx.x & 63;
    int dst = seg - (seg >= NENT ? NENT : 0);
    float dd = dinv[dst];
    int s = row_start[seg], e = row_start[seg + 1];
    bool act = lane < 50;
    float4 acc = {0.f, 0.f, 0.f, 0.f};
    for (int i = s; i < e; i++) {
        int ed = elist[i];
        int src = ei[ed];
        int t = et[ed];
        float nrm = dinv[src] * dd;
        if (act) {
            float4 a = *(const float4*)&emb[(long long)src * DD + lane * 4];
            float4 b = *(const float4*)&rel[t * DD + lane * 4];
            acc.x += (a.x - b.x) * nrm;
            acc.y += (a.y - b.y) * nrm;
            acc.z += (a.z - b.z) * nrm;
            acc.w += (a.w - b.w) * nrm;
        }
    }
    if (act) *(float4*)&agg[(long long)seg * DD + lane * 4] = acc;
}

// ================= encoder GEMMs =================

// transpose + hi/lo-split the three 200x200 weights: wt[s][j][k] = split(w_s[k][j])
__global__ void k_cvt3w(const float* __restrict__ w_in, const float* __restrict__ w_out,
                        const float* __restrict__ w_loop,
                        ushort* __restrict__ wth, ushort* __restrict__ wtl) {
    int idx = blockIdx.x * 256 + threadIdx.x;
    if (idx >= 3 * DD * DD) return;
    int s = idx / (DD * DD);
    int rem = idx - s * DD * DD;
    int j = rem / DD, k = rem - (rem / DD) * DD;
    const float* w = (s == 0) ? w_in : (s == 1) ? w_out : w_loop;
    ushort h, l;
    bf16split(w[k * DD + j], h, l);
    wth[idx] = h;
    wtl[idx] = l;
}

// all_ent = tanh((agg_in@w_in + agg_out@w_out + (emb-loop_rel)@w_loop)/3) via bf16-split MFMA
__global__ __launch_bounds__(128) void k_allent_mfma(
        const float* __restrict__ agg, const float* __restrict__ emb,
        const float* __restrict__ loop_rel,
        const ushort* __restrict__ wth, const ushort* __restrict__ wtl,
        float* __restrict__ all_ent) {
    __shared__ __align__(16) ushort Ah[64][DD];
    __shared__ __align__(16) ushort Al[64][DD];
    __shared__ float lr[DD];
    int tid = threadIdx.x;
    for (int i = tid; i < DD; i += 128) lr[i] = loop_rel[i];
    int r0 = blockIdx.x * 64;
    int wid = tid >> 6, lane = tid & 63, l15 = lane & 15, q = lane >> 4;

    f32x4 zero4 = {0.f, 0.f, 0.f, 0.f};
    f32x4 acc[2][13];
#pragma unroll
    for (int m = 0; m < 2; m++)
#pragma unroll
        for (int n = 0; n < 13; n++) acc[m][n] = zero4;

    int jc[13];
#pragma unroll
    for (int n = 0; n < 13; n++) {
        int j = n * 16 + l15;
        jc[n] = j < DD ? j : DD - 1;
    }

    for (int s = 0; s < 3; s++) {
        __syncthreads();
        for (int i = tid; i < 3200; i += 128) {
            int row = i / 50, c4 = (i % 50) * 4;
            int rg = r0 + row;
            if (rg > NENT - 1) rg = NENT - 1;
            float4 v;
            if (s == 2) {
                v = *(const float4*)&emb[(long long)rg * DD + c4];
                v.x -= lr[c4]; v.y -= lr[c4 + 1]; v.z -= lr[c4 + 2]; v.w -= lr[c4 + 3];
            } else {
                v = *(const float4*)&agg[(long long)(s * NENT + rg) * DD + c4];
            }
            ushort4 h, l;
            bf16split(v.x, h.x, l.x);
            bf16split(v.y, h.y, l.y);
            bf16split(v.z, h.z, l.z);
            bf16split(v.w, h.w, l.w);
            *(ushort4*)&Ah[row][c4] = h;
            *(ushort4*)&Al[row][c4] = l;
        }
        __syncthreads();
        const ushort* bhb = wth + s * (DD * DD);
        const ushort* blb = wtl + s * (DD * DD);
#pragma unroll
        for (int kk = 0; kk < 6; kk++) {
            int k0 = kk * 32 + q * 8;
            bf16x8 ah[2], al[2];
#pragma unroll
            for (int m = 0; m < 2; m++) {
                ah[m] = *(const bf16x8*)&Ah[wid * 32 + m * 16 + l15][k0];
                al[m] = *(const bf16x8*)&Al[wid * 32 + m * 16 + l15][k0];
            }
#pragma unroll
            for (int n = 0; n < 13; n++) {
                bf16x8 bh = *(const bf16x8*)&bhb[jc[n] * DD + k0];
                bf16x8 bl = *(const bf16x8*)&blb[jc[n] * DD + k0];
#pragma unroll
                for (int m = 0; m < 2; m++) {
                    acc[m][n] = __builtin_amdgcn_mfma_f32_16x16x32_bf16(ah[m], bh, acc[m][n], 0, 0, 0);
                    acc[m][n] = __builtin_amdgcn_mfma_f32_16x16x32_bf16(ah[m], bl, acc[m][n], 0, 0, 0);
                    acc[m][n] = __builtin_amdgcn_mfma_f32_16x16x32_bf16(al[m], bh, acc[m][n], 0, 0, 0);
                }
            }
        }
        {   // partial k-step 192..199 (quarter 0 only)
            bf16x8 zf = {0, 0, 0, 0, 0, 0, 0, 0};
            bf16x8 ah[2], al[2];
#pragma unroll
            for (int m = 0; m < 2; m++) { ah[m] = zf; al[m] = zf; }
            if (q == 0) {
#pragma unroll
                for (int m = 0; m < 2; m++) {
                    ah[m] = *(const bf16x8*)&Ah[wid * 32 + m * 16 + l15][192];
                    al[m] = *(const bf16x8*)&Al[wid * 32 + m * 16 + l15][192];
                }
            }
#pragma unroll
            for (int n = 0; n < 13; n++) {
                bf16x8 bh = zf, bl = zf;
                if (q == 0) {
                    bh = *(const bf16x8*)&bhb[jc[n] * DD + 192];
                    bl = *(const bf16x8*)&blb[jc[n] * DD + 192];
                }
#pragma unroll
                for (int m = 0; m < 2; m++) {
                    acc[m][n] = __builtin_amdgcn_mfma_f32_16x16x32_bf16(ah[m], bh, acc[m][n], 0, 0, 0);
                    acc[m][n] = __builtin_amdgcn_mfma_f32_16x16x32_bf16(ah[m], bl, acc[m][n], 0, 0, 0);
                    acc[m][n] = __builtin_amdgcn_mfma_f32_16x16x32_bf16(al[m], bh, acc[m][n], 0, 0, 0);
                }
            }
        }
    }
#pragma unroll
    for (int n = 0; n < 13; n++) {
        int j = n * 16 + l15;
        if (j < DD) {
#pragma unroll
            for (int m = 0; m < 2; m++) {
                int row = r0 + wid * 32 + m * 16 + q * 4;
#pragma unroll
                for (int r = 0; r < 4; r++) {
                    if (row + r < NENT)
                        all_ent[(long long)(row + r) * DD + j] = tanhf(acc[m][n][r] * (1.f / 3.f));
                }
            }
        }
    }
}

// convert all_ent f32 -> bf16 hi/lo (over agg_out region), 4 elems/thread
__global__ void k_cvt(const float* __restrict__ src, ushort* __restrict__ hi,
                      ushort* __restrict__ lo) {
    long long i = (long long)(blockIdx.x * 256 + threadIdx.x) * 4;
    if (i >= (long long)NENT * DD) return;
    float4 v = *(const float4*)&src[i];
    ushort4 h, l;
    bf16split(v.x, h.x, l.x);
    bf16split(v.y, h.y, l.y);
    bf16split(v.z, h.z, l.z);
    bf16split(v.w, h.w, l.w);
    *(ushort4*)&hi[i] = h;
    *(ushort4*)&lo[i] = l;
}

// convert fc_w f32 -> bf16 hi/lo planes (into d_out tail)
__global__ void k_cvtw(const float* __restrict__ src, ushort* __restrict__ hi,
                       ushort* __restrict__ lo) {
    long long i = (long long)(blockIdx.x * 256 + threadIdx.x) * 4;
    if (i >= (long long)DD * FLAT) return;
    float4 v = *(const float4*)&src[i];
    ushort4 h, l;
    bf16split(v.x, h.x, l.x);
    bf16split(v.y, h.y, l.y);
    bf16split(v.z, h.z, l.z);
    bf16split(v.w, h.w, l.w);
    *(ushort4*)&hi[i] = h;
    *(ushort4*)&lo[i] = l;
}

__global__ void k_rmat(const float* __restrict__ init_rel, const float* __restrict__ w_rel,
                       float* __restrict__ rmat) {
    __shared__ float S[16][DD];
    int r0 = blockIdx.x * 16;
    for (int i = threadIdx.x; i < 16 * DD; i += 256)
        S[i / DD][i % DD] = init_rel[(r0 + i / DD) * DD + i % DD];
    __syncthreads();
    int j = threadIdx.x;
    if (j < DD) {
        float acc[16];
#pragma unroll
        for (int rr = 0; rr < 16; rr++) acc[rr] = 0.f;
        for (int k = 0; k < DD; k += 4) {
            float wx = w_rel[(k + 0) * DD + j], wy = w_rel[(k + 1) * DD + j],
                  wz = w_rel[(k + 2) * DD + j], ww = w_rel[(k + 3) * DD + j];
#pragma unroll
            for (int rr = 0; rr < 16; rr++) {
                float4 a = *(const float4*)&S[rr][k];
                acc[rr] += a.x * wx + a.y * wy + a.z * wz + a.w * ww;
            }
        }
#pragma unroll
        for (int rr = 0; rr < 16; rr++) rmat[(r0 + rr) * DD + j] = acc[rr];
    }
}

// ================= decoder =================

__global__ void k_cheq(const int* __restrict__ sub, const int* __restrict__ rel,
                       const int* __restrict__ perm, const float* __restrict__ all_ent,
                       const float* __restrict__ rmat, float* __restrict__ cheq,
                       float* __restrict__ acc0) {
    int i = blockIdx.x * 256 + threadIdx.x;
    int b = i / 400, p = i % 400;
    int c = perm[p];
    float v = (c < DD) ? all_ent[(long long)sub[b] * DD + c]
                       : rmat[rel[b] * DD + (c - DD)];
    cheq[i] = v;
    __shared__ float s1[256], s2[256];
    s1[threadIdx.x] = v;
    s2[threadIdx.x] = v * v;
    __syncthreads();
    for (int st = 128; st > 0; st >>= 1) {
        if (threadIdx.x < st) { s1[threadIdx.x] += s1[threadIdx.x + st]; s2[threadIdx.x] += s2[threadIdx.x + st]; }
        __syncthreads();
    }
    if (threadIdx.x == 0) { atomicAdd(&acc0[0], s1[0]); atomicAdd(&acc0[1], s2[0]); }
}

__global__ void k_conv(const float* __restrict__ cheq, const float* __restrict__ acc0,
                       const float* __restrict__ bn0_g, const float* __restrict__ bn0_b,
                       const float* __restrict__ filt, float* __restrict__ conv_out,
                       float* __restrict__ acc1) {
    __shared__ float xp[28 * 28];
    __shared__ float fl[NF * 81];
    __shared__ float csum[NF], csq[NF];
    int b = blockIdx.x;
    const float invN = 1.f / (BB * 400.f);
    float mean = acc0[0] * invN;
    float var = acc0[1] * invN - mean * mean;
    float sc = rsqrtf(var + 1e-5f) * bn0_g[0];
    float sh = bn0_b[0] - mean * sc;
    for (int i = threadIdx.x; i < 28 * 28; i += 256) {
        int r = i / 28, c = i % 28;
        int rr = (r + 16) % 20, cc = (c + 16) % 20;
        xp[i] = cheq[b * 400 + rr * 20 + cc] * sc + sh;
    }
    for (int i = threadIdx.x; i < NF * 81; i += 256) fl[i] = filt[i];
    if (threadIdx.x < NF) { csum[threadIdx.x] = 0.f; csq[threadIdx.x] = 0.f; }
    __syncthreads();
    for (int t = threadIdx.x; t < NF * 20; t += 256) {
        int ch = t / 20, row = t % 20;
        float acc[20];
#pragma unroll
        for (int c2 = 0; c2 < 20; c2++) acc[c2] = 0.f;
        for (int di = 0; di < 9; di++) {
            const float* xrow = &xp[(row + di) * 28];
#pragma unroll
            for (int dj = 0; dj < 9; dj++) {
                float f = fl[ch * 81 + di * 9 + dj];
#pragma unroll
                for (int c2 = 0; c2 < 20; c2++) acc[c2] = fmaf(xrow[c2 + dj], f, acc[c2]);
            }
        }
        float s = 0.f, q = 0.f;
        long long base = (long long)b * FLAT + ch * 400 + row * 20;
#pragma unroll
        for (int c2 = 0; c2 < 20; c2++) {
            float v = acc[c2];
            s += v; q += v * v;
            conv_out[base + c2] = v;
        }
        atomicAdd(&csum[ch], s);
        atomicAdd(&csq[ch], q);
    }
    __syncthreads();
    if (threadIdx.x < NF) {
        atomicAdd(&acc1[threadIdx.x], csum[threadIdx.x]);
        atomicAdd(&acc1[NF + threadIdx.x], csq[threadIdx.x]);
    }
}

__global__ void k_bn1fin(const float* __restrict__ acc1, const float* __restrict__ g1,
                         const float* __restrict__ b1, float* __restrict__ bn1s) {
    int c = threadIdx.x;
    if (c >= NF) return;
    const float invN = 1.f / (BB * 400.f);
    float m = acc1[c] * invN;
    float v = acc1[NF + c] * invN - m * m;
    float sc = rsqrtf(v + 1e-5f) * g1[c];
    bn1s[c] = sc;
    bn1s[NF + c] = b1[c] - m * sc;
}

// ---- fc GEMM via bf16-split MFMA ----
__device__ __forceinline__ void fc_stageB(int tid, int nh, int k0,
        const ushort* __restrict__ fwh, const ushort* __restrict__ fwl,
        ushort (*Bh)[40], ushort (*Bl)[40]) {
    for (int i = tid; i < 896; i += 128) {
        int pl = (i >= 448);
        int ii = pl ? i - 448 : i;
        int row = ii >> 2;
        int koff = (ii & 3) * 8;
        int j = nh * 112 + row;
        int jr = j < DD ? j : DD - 1;
        const ushort* src = (pl ? fwl : fwh) + (long long)jr * FLAT + k0 + koff;
        uint4 v = *(const uint4*)src;
        if (pl) *(uint4*)&Bl[row][koff] = v;
        else    *(uint4*)&Bh[row][koff] = v;
    }
}

__global__ __launch_bounds__(128) void k_fc_mfma(
        const float* __restrict__ conv_out, const float* __restrict__ bn1s,
        const ushort* __restrict__ fwh, const ushort* __restrict__ fwl,
        float* __restrict__ part) {
    __shared__ __align__(16) ushort Bh[2][112][40];
    __shared__ __align__(16) ushort Bl[2][112][40];
    __shared__ float bns[192];
    int tid = threadIdx.x;
    for (int i = tid; i < 192; i += 128) bns[i] = bn1s[i];
    int b0 = blockIdx.x * 64;
    int nh = blockIdx.y;
    int ksl = blockIdx.z;
    int kbase = ksl * FC_KSLICE;
    int wid = tid >> 6, lane = tid & 63, l15 = lane & 15, q = lane >> 4;

    const float* aptr0 = conv_out + (long long)(b0 + wid * 32 + l15) * FLAT;
    const float* aptr1 = aptr0 + 16LL * FLAT;

    f32x4 zero4 = {0.f, 0.f, 0.f, 0.f};
    f32x4 acc[2][7];
#pragma unroll
    for (int m = 0; m < 2; m++)
#pragma unroll
        for (int n = 0; n < 7; n++) acc[m][n] = zero4;

    fc_stageB(tid, nh, kbase, fwh, fwl, Bh[0], Bl[0]);
    __syncthreads();

    for (int c = 0; c < FC_NCHUNK; c++) {
        int buf = c & 1;
        int k0 = kbase + c * 32 + q * 8;
        float4 a0 = *(const float4*)&aptr0[k0];
        float4 a0b = *(const float4*)&aptr0[k0 + 4];
        float4 a1 = *(const float4*)&aptr1[k0];
        float4 a1b = *(const float4*)&aptr1[k0 + 4];
        if (c + 1 < FC_NCHUNK)
            fc_stageB(tid, nh, kbase + (c + 1) * 32, fwh, fwl, Bh[buf ^ 1], Bl[buf ^ 1]);
        int ch = k0 / 400;
        float sc = bns[ch], sh = bns[96 + ch];
        bf16x8 ah0, al0, ah1, al1;
        {
            float e[8];
            e[0]=fmaxf(a0.x*sc+sh,0.f); e[1]=fmaxf(a0.y*sc+sh,0.f);
            e[2]=fmaxf(a0.z*sc+sh,0.f); e[3]=fmaxf(a0.w*sc+sh,0.f);
            e[4]=fmaxf(a0b.x*sc+sh,0.f); e[5]=fmaxf(a0b.y*sc+sh,0.f);
            e[6]=fmaxf(a0b.z*sc+sh,0.f); e[7]=fmaxf(a0b.w*sc+sh,0.f);
#pragma unroll
            for (int t = 0; t < 8; t++) { ushort h, l; bf16split(e[t], h, l); ah0[t]=(short)h; al0[t]=(short)l; }
            e[0]=fmaxf(a1.x*sc+sh,0.f); e[1]=fmaxf(a1.y*sc+sh,0.f);
            e[2]=fmaxf(a1.z*sc+sh,0.f); e[3]=fmaxf(a1.w*sc+sh,0.f);
            e[4]=fmaxf(a1b.x*sc+sh,0.f); e[5]=fmaxf(a1b.y*sc+sh,0.f);
            e[6]=fmaxf(a1b.z*sc+sh,0.f); e[7]=fmaxf(a1b.w*sc+sh,0.f);
#pragma unroll
            for (int t = 0; t < 8; t++) { ushort h, l; bf16split(e[t], h, l); ah1[t]=(short)h; al1[t]=(short)l; }
        }
#pragma unroll
        for (int n = 0; n < 7; n++) {
            bf16x8 bh = *(const bf16x8*)&Bh[buf][n * 16 + l15][q * 8];
            bf16x8 bl = *(const bf16x8*)&Bl[buf][n * 16 + l15][q * 8];
            acc[0][n] = __builtin_amdgcn_mfma_f32_16x16x32_bf16(ah0, bh, acc[0][n], 0, 0, 0);
            acc[0][n] = __builtin_amdgcn_mfma_f32_16x16x32_bf16(ah0, bl, acc[0][n], 0, 0, 0);
            acc[0][n] = __builtin_amdgcn_mfma_f32_16x16x32_bf16(al0, bh, acc[0][n], 0, 0, 0);
            acc[1][n] = __builtin_amdgcn_mfma_f32_16x16x32_bf16(ah1, bh, acc[1][n], 0, 0, 0);
            acc[1][n] = __builtin_amdgcn_mfma_f32_16x16x32_bf16(ah1, bl, acc[1][n], 0, 0, 0);
            acc[1][n] = __builtin_amdgcn_mfma_f32_16x16x32_bf16(al1, bh, acc[1][n], 0, 0, 0);
        }
        __syncthreads();
    }
    long long pbase = (long long)ksl * (BB * DD);
#pragma unroll
    for (int n = 0; n < 7; n++) {
        int j = nh * 112 + n * 16 + l15;
        if (j < DD) {
#pragma unroll
            for (int m = 0; m < 2; m++) {
                int rowb = b0 + wid * 32 + m * 16 + q * 4;
#pragma unroll
                for (int r = 0; r < 4; r++)
                    part[pbase + (long long)(rowb + r) * DD + j] = acc[m][n][r];
            }
        }
    }
}

// bn2 over batch, folding the split-K reduction; emits x2 bf16 hi/lo only
__global__ void k_bn2(const float* __restrict__ part, const float* __restrict__ fc_b,
                      const float* __restrict__ g2, const float* __restrict__ b2,
                      ushort* __restrict__ x2h, ushort* __restrict__ x2l) {
    int j = blockIdx.x;
    float vals[4];
    float s = 0.f, q = 0.f;
#pragma unroll
    for (int i = 0; i < 4; i++) {
        int b = threadIdx.x + i * 256;
        float v = fc_b[j];
#pragma unroll
        for (int ks = 0; ks < FC_KS; ks++)
            v += part[(long long)ks * (BB * DD) + (long long)b * DD + j];
        vals[i] = v;
        s += v; q += v * v;
    }
    __shared__ float r1[256], r2[256];
    __shared__ float bc[2];
    r1[threadIdx.x] = s; r2[threadIdx.x] = q;
    __syncthreads();
    for (int st = 128; st > 0; st >>= 1) {
        if (threadIdx.x < st) { r1[threadIdx.x] += r1[threadIdx.x + st]; r2[threadIdx.x] += r2[threadIdx.x + st]; }
        __syncthreads();
    }
    if (threadIdx.x == 0) {
        float m = r1[0] * (1.f / BB);
        float v = r2[0] * (1.f / BB) - m * m;
        float sc = rsqrtf(v + 1e-5f) * g2[j];
        bc[0] = sc; bc[1] = b2[j] - m * sc;
    }
    __syncthreads();
    float sc = bc[0], sh = bc[1];
#pragma unroll
    for (int i = 0; i < 4; i++) {
        int b = threadIdx.x + i * 256;
        float v = fmaxf(vals[i] * sc + sh, 0.f);
        ushort h, l;
        bf16split(v, h, l);
        x2h[b * DD + j] = h;
        x2l[b * DD + j] = l;
    }
}

// logits = sigmoid(x2 @ all_ent^T + bias) via bf16-split MFMA, B-strip-resident.
// One block per 64-entity strip; B hi/lo staged once in LDS (51.2 KB, 3 blk/CU);
// loop over all 16 M-tiles; A frags straight from L2 (x2 = 800 KB). No inner barriers.
// 8 waves as 4M x 2N; wave tile 16 rows x 32 entities (1 m-frag x 2 n-frags).
__global__ __launch_bounds__(512) void k_logits_mfma(
        const ushort* __restrict__ x2h, const ushort* __restrict__ x2l,
        const ushort* __restrict__ aeh, const ushort* __restrict__ ael,
        const float* __restrict__ bias, float* __restrict__ out) {
    __shared__ ushort Bhs[LE * DD];   // 25.6 KB
    __shared__ ushort Bls[LE * DD];   // 25.6 KB
    int e0 = blockIdx.x * LE;
    for (int i = threadIdx.x; i < 2 * LE * 25; i += 512) {   // 3200 uint4
        int pl = i >= LE * 25;
        int ii = pl ? i - LE * 25 : i;
        int row = ii / 25, seg = ii % 25;
        int e = e0 + row;
        if (e > NENT - 1) e = NENT - 1;
        const ushort* src = (pl ? ael : aeh) + (long long)e * DD + seg * 8;
        uint4 v = *(const uint4*)src;
        if (pl) *(uint4*)&Bls[row * DD + seg * 8] = v;
        else    *(uint4*)&Bhs[row * DD + seg * 8] = v;
    }
    __syncthreads();

    int wid = threadIdx.x >> 6;
    int lane = threadIdx.x & 63;
    int l15 = lane & 15, q = lane >> 4;
    int wm = wid >> 1;          // 0..3  (M sub-tile within 64-row tile)
    int wn = wid & 1;           // 0..1  (entity half of the 64-strip)

    // per-block constants: bias + entity validity for the 2 n-frags
    float bv[2];
    bool ev[2];
#pragma unroll
    for (int n = 0; n < 2; n++) {
        int e = e0 + wn * 32 + n * 16 + l15;
        ev[n] = e < NENT;
        bv[n] = bias[ev[n] ? e : NENT - 1];
    }
    int nbase0 = (wn * 32 + l15) * DD;        // n-frag 0 LDS row base
    int nbase1 = (wn * 32 + 16 + l15) * DD;   // n-frag 1

    f32x4 zero4 = {0.f, 0.f, 0.f, 0.f};
    bf16x8 zf = {0, 0, 0, 0, 0, 0, 0, 0};

    for (int mt = 0; mt < 16; mt++) {
        int arow = mt * 64 + wm * 16 + l15;   // batch row this lane's A frag covers
        const ushort* ah_p = x2h + (long long)arow * DD;
        const ushort* al_p = x2l + (long long)arow * DD;

        f32x4 acc[2];
        acc[0] = zero4; acc[1] = zero4;

#pragma unroll
        for (int kk = 0; kk < 6; kk++) {
            int k0 = kk * 32 + q * 8;
            bf16x8 ah = *(const bf16x8*)&ah_p[k0];
            bf16x8 al = *(const bf16x8*)&al_p[k0];
            bf16x8 bh0 = *(const bf16x8*)&Bhs[nbase0 + k0];
            bf16x8 bl0 = *(const bf16x8*)&Bls[nbase0 + k0];
            bf16x8 bh1 = *(const bf16x8*)&Bhs[nbase1 + k0];
            bf16x8 bl1 = *(const bf16x8*)&Bls[nbase1 + k0];
            acc[0] = __builtin_amdgcn_mfma_f32_16x16x32_bf16(ah, bh0, acc[0], 0, 0, 0);
            acc[0] = __builtin_amdgcn_mfma_f32_16x16x32_bf16(ah, bl0, acc[0], 0, 0, 0);
            acc[0] = __builtin_amdgcn_mfma_f32_16x16x32_bf16(al, bh0, acc[0], 0, 0, 0);
            acc[1] = __builtin_amdgcn_mfma_f32_16x16x32_bf16(ah, bh1, acc[1], 0, 0, 0);
            acc[1] = __builtin_amdgcn_mfma_f32_16x16x32_bf16(ah, bl1, acc[1], 0, 0, 0);
            acc[1] = __builtin_amdgcn_mfma_f32_16x16x32_bf16(al, bh1, acc[1], 0, 0, 0);
        }
        {   // partial k-step 192..199 (quarter 0 only)
            bf16x8 ah = zf, al = zf, bh0 = zf, bl0 = zf, bh1 = zf, bl1 = zf;
            if (q == 0) {
                ah = *(const bf16x8*)&ah_p[192];
                al = *(const bf16x8*)&al_p[192];
                bh0 = *(const bf16x8*)&Bhs[nbase0 + 192];
                bl0 = *(const bf16x8*)&Bls[nbase0 + 192];
                bh1 = *(const bf16x8*)&Bhs[nbase1 + 192];
                bl1 = *(const bf16x8*)&Bls[nbase1 + 192];
            }
            acc[0] = __builtin_amdgcn_mfma_f32_16x16x32_bf16(ah, bh0, acc[0], 0, 0, 0);
            acc[0] = __builtin_amdgcn_mfma_f32_16x16x32_bf16(ah, bl0, acc[0], 0, 0, 0);
            acc[0] = __builtin_amdgcn_mfma_f32_16x16x32_bf16(al, bh0, acc[0], 0, 0, 0);
            acc[1] = __builtin_amdgcn_mfma_f32_16x16x32_bf16(ah, bh1, acc[1], 0, 0, 0);
            acc[1] = __builtin_amdgcn_mfma_f32_16x16x32_bf16(ah, bl1, acc[1], 0, 0, 0);
            acc[1] = __builtin_amdgcn_mfma_f32_16x16x32_bf16(al, bh1, acc[1], 0, 0, 0);
        }
        // epilogue: C row = q*4+r (within 16-row frag), col = l15
        int rowb = mt * 64 + wm * 16 + q * 4;
#pragma unroll
        for (int n = 0; n < 2; n++) {
            if (ev[n]) {
                int e = e0 + wn * 32 + n * 16 + l15;
#pragma unroll
                for (int r = 0; r < 4; r++) {
                    float t = acc[n][r] + bv[n];
                    out[(long long)(rowb + r) * NENT + e] = 1.f / (1.f + __expf(-t));
                }
            }
        }
    }
}

// ================= host =================

extern "C" void kernel_launch(void* const* d_in, const int* in_sizes, int n_in,
                              void* d_out, int out_size, void* d_ws, size_t ws_size,
                              hipStream_t stream) {
    const int*   sub      = (const int*)d_in[0];
    const int*   rel      = (const int*)d_in[1];
    const int*   ei       = (const int*)d_in[3];
    const int*   et       = (const int*)d_in[4];
    const int*   perm     = (const int*)d_in[5];
    const float* emb      = (const float*)d_in[6];
    const float* init_rel = (const float*)d_in[7];
    const float* w_in     = (const float*)d_in[8];
    const float* w_out    = (const float*)d_in[9];
    const float* w_loop   = (const float*)d_in[10];
    const float* w_rel    = (const float*)d_in[11];
    const float* loop_rel = (const float*)d_in[12];
    const float* bn0_g    = (const float*)d_in[13];
    const float* bn0_b    = (const float*)d_in[14];
    const float* bn1_g    = (const float*)d_in[15];
    const float* bn1_b    = (const float*)d_in[16];
    const float* bn2_g    = (const float*)d_in[17];
    const float* bn2_b    = (const float*)d_in[18];
    const float* filt     = (const float*)d_in[19];
    const float* fc_w     = (const float*)d_in[20];
    const float* fc_b     = (const float*)d_in[21];
    const float* bias_ent = (const float*)d_in[22];

    float* ws  = (float*)d_ws;
    float* o   = (float*)d_out;

    float* agg     = ws + OFF_AGG;
    float* agg_in  = agg;
    float* agg_out = agg + (long long)NENT * DD;
    int*   cnt     = (int*)(ws + OFF_CNT);
    int*   cursor  = (int*)(ws + OFF_CURSOR);
    int*   bsum    = (int*)(ws + OFF_BSUM);
    int*   elist   = (int*)(ws + OFF_ELIST);
    ushort* wth    = (ushort*)(ws + OFF_WT);
    ushort* wtl    = wth + 3 * DD * DD;
    float* acc0    = ws + OFF_ACC0;
    float* acc1    = ws + OFF_ACC1;
    float* dinv    = ws + OFF_DINV;
    float* rmat    = ws + OFF_RMAT;
    float* cheq    = ws + OFF_CHEQ;
    float* bn1s    = ws + OFF_BN1S;
    ushort* x2h    = (ushort*)(ws + OFF_X2H);
    ushort* x2l    = (ushort*)(ws + OFF_X2L);
    float* all_ent = agg_in;
    ushort* aeh    = (ushort*)agg_out;
    ushort* ael    = aeh + (long long)NENT * DD;

    // d_out scratch (fully overwritten by k_logits_mfma at the end)
    float*  conv_out = o + OD_CONV;
    ushort* fwh      = (ushort*)(o + OD_FWH);
    ushort* fwl      = (ushort*)(o + OD_FWL);
    float*  part     = o + OD_PART;

    hipMemsetAsync(ws + ZSTART, 0, (size_t)(ZEND - ZSTART) * 4, stream);

    // ---- CSR build + gather aggregation ----
    k_hist<<<(ETOT + 255) / 256, 256, 0, stream>>>(ei, cnt);
    k_dinv<<<(NENT + 255) / 256, 256, 0, stream>>>(cnt, dinv);
    k_scan1<<<98, 256, 0, stream>>>(cnt, bsum);
    k_scan2<<<1, 128, 0, stream>>>(bsum);
    k_scan3<<<98, 256, 0, stream>>>(cnt, bsum, cursor);
    k_fill<<<(ETOT + 255) / 256, 256, 0, stream>>>(ei, cursor, elist);
    k_agg<<<NSEG / 4, 256, 0, stream>>>(ei, et, cnt, elist, emb, init_rel, dinv, agg);

    // ---- encoder GEMMs + weight conversions ----
    k_cvt3w<<<(3 * DD * DD + 255) / 256, 256, 0, stream>>>(w_in, w_out, w_loop, wth, wtl);
    k_allent_mfma<<<(NENT + 63) / 64, 128, 0, stream>>>(agg, emb, loop_rel, wth, wtl, all_ent);
    k_cvt<<<((NENT * DD / 4) + 255) / 256, 256, 0, stream>>>(all_ent, aeh, ael);
    k_cvtw<<<((DD * FLAT / 4) + 255) / 256, 256, 0, stream>>>(fc_w, fwh, fwl);
    k_rmat<<<400 / 16, 256, 0, stream>>>(init_rel, w_rel, rmat);

    // ---- decoder ----
    k_cheq<<<(BB * 400) / 256, 256, 0, stream>>>(sub, rel, perm, all_ent, rmat, cheq, acc0);
    k_conv<<<BB, 256, 0, stream>>>(cheq, acc0, bn0_g, bn0_b, filt, conv_out, acc1);
    k_bn1fin<<<1, 128, 0, stream>>>(acc1, bn1_g, bn1_b, bn1s);
    k_fc_mfma<<<dim3(BB / 64, 2, FC_KS), 128, 0, stream>>>(conv_out, bn1s, fwh, fwl, part);
    k_bn2<<<DD, 256, 0, stream>>>(part, fc_b, bn2_g, bn2_b, x2h, x2l);
    k_logits_mfma<<<(NENT + LE - 1) / LE, 512, 0, stream>>>(
        x2h, x2l, aeh, ael, bias_ent, o);
}